// Round 3
// baseline (1461.254 us; speedup 1.0000x reference)
//
#include <hip/hip_runtime.h>
#include <hip/hip_bf16.h>
#include <math.h>

// Problem constants
#define BN   4
#define CIN  128
#define COUT 256
#define HWP  4096      // 64*64

typedef __hip_bfloat16 bf16;

__device__ __forceinline__ float b2f(bf16 v) { return __bfloat162float(v); }
__device__ __forceinline__ float bflo(unsigned u) { return __uint_as_float(u << 16); }
__device__ __forceinline__ float bfhi(unsigned u) { return __uint_as_float(u & 0xffff0000u); }

__device__ __forceinline__ float ldv(const float* p, size_t i) { return p[i]; }
__device__ __forceinline__ float ldv(const bf16* p, size_t i) { return b2f(p[i]); }
__device__ __forceinline__ void stv(float* p, size_t i, float v) { p[i] = v; }
__device__ __forceinline__ void stv(bf16* p, size_t i, float v) { p[i] = __float2bfloat16(v); }

// ------------------------------------------------- dc_w (co, ci*9+k) f32 -> wT (idx, co) bf16
__global__ __launch_bounds__(256) void prep_wT_kernel(const float* __restrict__ w,
                                                      bf16* __restrict__ wT) {
    int j = blockIdx.x * 256 + threadIdx.x;   // j = idx*256 + co
    if (j < 1152 * 256) {
        int idx = j >> 8, co = j & 255;
        wT[j] = __float2bfloat16(w[co * 1152 + idx]);
    }
}

// ---------------------------------------------------------------- generic 3x3 conv
// grid (CO, 16, B), block 256 = 64x * 4y. ACT: 0=none 1=relu 2=sigmoid
template<int ACT, int USE_BN, typename IT, typename OT>
__global__ __launch_bounds__(256) void conv3x3_kernel(
    const IT* __restrict__ in, const float* __restrict__ w, const float* __restrict__ bias,
    const float* __restrict__ bn_g, const float* __restrict__ bn_b,
    const float* __restrict__ bn_m, const float* __restrict__ bn_v,
    OT* __restrict__ out, int CI, int CO)
{
    extern __shared__ float wl[];          // CI*9 floats
    const int co = blockIdx.x, strip = blockIdx.y, b = blockIdx.z;
    const int nt = CI * 9;
    for (int i = threadIdx.x; i < nt; i += 256) wl[i] = w[co * nt + i];
    __syncthreads();

    const int tx = threadIdx.x & 63, ty = threadIdx.x >> 6;
    const int y = strip * 4 + ty, x = tx;
    float acc = bias[co];
    const IT* ip = in + (size_t)(b * CI) * HWP;
    for (int ci = 0; ci < CI; ci++) {
        const IT* p = ip + ci * HWP;
        const float* wp = wl + ci * 9;
        #pragma unroll
        for (int ky = 0; ky < 3; ky++) {
            int yy = y + ky - 1;
            if (yy < 0 || yy > 63) continue;
            #pragma unroll
            for (int kx = 0; kx < 3; kx++) {
                int xx = x + kx - 1;
                if (xx < 0 || xx > 63) continue;
                acc += ldv(p, yy * 64 + xx) * wp[ky * 3 + kx];
            }
        }
    }
    if (USE_BN) {
        float sc = bn_g[co] / sqrtf(bn_v[co] + 1e-5f);
        acc = (acc - bn_m[co]) * sc + bn_b[co];
    }
    if (ACT == 1) acc = fmaxf(acc, 0.f);
    else if (ACT == 2) acc = 1.f / (1.f + expf(-acc));
    stv(out, (size_t)(b * CO + co) * HWP + y * 64 + x, acc);
}

// ---------------------------------------------------------------- depthwise 3x3 + BN + ReLU
__global__ __launch_bounds__(256) void dwconv_kernel(
    const float* __restrict__ in, const float* __restrict__ w, const float* __restrict__ bias,
    const float* __restrict__ bn_g, const float* __restrict__ bn_b,
    const float* __restrict__ bn_m, const float* __restrict__ bn_v,
    bf16* __restrict__ out)
{
    int i = blockIdx.x * 256 + threadIdx.x;
    if (i >= BN * CIN * HWP) return;
    int x = i & 63, y = (i >> 6) & 63, c = (i >> 12) & 127;
    int b = i >> 19;
    float acc = bias[c];
    const float* p = in + (size_t)(b * CIN + c) * HWP;
    #pragma unroll
    for (int ky = 0; ky < 3; ky++) {
        int yy = y + ky - 1;
        if (yy < 0 || yy > 63) continue;
        #pragma unroll
        for (int kx = 0; kx < 3; kx++) {
            int xx = x + kx - 1;
            if (xx < 0 || xx > 63) continue;
            acc += p[yy * 64 + xx] * w[c * 9 + ky * 3 + kx];
        }
    }
    float sc = bn_g[c] / sqrtf(bn_v[c] + 1e-5f);
    acc = (acc - bn_m[c]) * sc + bn_b[c];
    acc = fmaxf(acc, 0.f);
    out[i] = __float2bfloat16(acc);
}

// ---------------------------------------------------------------- pointwise 1x1 (contour pw)
// grid (CO/8, 16, B), block 256. 8 output channels per thread.
__global__ __launch_bounds__(256) void pw_kernel(
    const bf16* __restrict__ in, const float* __restrict__ w, const float* __restrict__ bias,
    bf16* __restrict__ out, int CI, int CO)
{
    __shared__ float wl[8 * 128];
    const int cog = blockIdx.x, strip = blockIdx.y, b = blockIdx.z;
    const int co0 = cog * 8;
    for (int i = threadIdx.x; i < 8 * CI; i += 256) wl[i] = w[co0 * CI + i];
    __syncthreads();
    const int tx = threadIdx.x & 63, ty = threadIdx.x >> 6;
    const int pos = (strip * 4 + ty) * 64 + tx;
    float acc[8];
    #pragma unroll
    for (int cs = 0; cs < 8; cs++) acc[cs] = bias[co0 + cs];
    const bf16* ip = in + (size_t)b * CI * HWP + pos;
    for (int ci = 0; ci < CI; ci++) {
        float v = b2f(ip[ci * HWP]);
        #pragma unroll
        for (int cs = 0; cs < 8; cs++) acc[cs] += v * wl[cs * CI + ci];
    }
    #pragma unroll
    for (int cs = 0; cs < 8; cs++)
        out[(size_t)(b * CO + co0 + cs) * HWP + pos] = __float2bfloat16(acc[cs]);
}

// ---------------------------------------------------------------- modulated deformable conv
// grid 2048 (= B * 512 tiles of 8 pixels), block 256. LDS ~20.7 KB.
__global__ __launch_bounds__(256) void deform_kernel(
    const float* __restrict__ x, const float* __restrict__ offs, const float* __restrict__ msk,
    const bf16* __restrict__ wT, const float* __restrict__ bias, bf16* __restrict__ out)
{
    __shared__ __align__(16) bf16 val[1152 * 8];   // [ci*9+k][pix], 18432 B
    __shared__ int   ci4[72][4];
    __shared__ float cw4[72][4];

    const int bid = blockIdx.x;
    const int b = bid >> 9;
    const int tile = bid & 511;
    const int pos0 = tile * 8;
    const int tid = threadIdx.x;

    if (tid < 72) {                       // pair = k*8 + pix
        int k = tid >> 3, pix = tid & 7;
        int pos = pos0 + pix;
        int y = pos >> 6, xc = pos & 63;
        float offy = offs[(size_t)(b * 18 + 2 * k) * HWP + pos];
        float offx = offs[(size_t)(b * 18 + 2 * k + 1) * HWP + pos];
        float m = msk[(size_t)(b * 9 + k) * HWP + pos];
        float py = (float)(y - 1 + k / 3) + offy;
        float px = (float)(xc - 1 + k % 3) + offx;
        float fy = floorf(py), fx = floorf(px);
        float wy1 = py - fy, wx1 = px - fx;
        int y0 = (int)fy, x0 = (int)fx;
        int y1 = y0 + 1, x1 = x0 + 1;
        bool vy0 = (y0 >= 0 && y0 <= 63), vy1 = (y1 >= 0 && y1 <= 63);
        bool vx0 = (x0 >= 0 && x0 <= 63), vx1 = (x1 >= 0 && x1 <= 63);
        int cy0 = min(max(y0, 0), 63), cy1 = min(max(y1, 0), 63);
        int cx0 = min(max(x0, 0), 63), cx1 = min(max(x1, 0), 63);
        ci4[tid][0] = cy0 * 64 + cx0;  cw4[tid][0] = (vy0 && vx0) ? (1.f - wy1) * (1.f - wx1) * m : 0.f;
        ci4[tid][1] = cy0 * 64 + cx1;  cw4[tid][1] = (vy0 && vx1) ? (1.f - wy1) * wx1 * m : 0.f;
        ci4[tid][2] = cy1 * 64 + cx0;  cw4[tid][2] = (vy1 && vx0) ? wy1 * (1.f - wx1) * m : 0.f;
        ci4[tid][3] = cy1 * 64 + cx1;  cw4[tid][3] = (vy1 && vx1) ? wy1 * wx1 * m : 0.f;
    }
    __syncthreads();

    const float* xb = x + (size_t)b * CIN * HWP;
    for (int i = 0; i < 36; i++) {        // 9216 gathers / 256 threads
        int jj = tid + 256 * i;
        int ci = jj / 72, pr = jj - ci * 72;
        const float* p = xb + ci * HWP;
        float g = cw4[pr][0] * p[ci4[pr][0]] + cw4[pr][1] * p[ci4[pr][1]]
                + cw4[pr][2] * p[ci4[pr][2]] + cw4[pr][3] * p[ci4[pr][3]];
        int k = pr >> 3, pix = pr & 7;
        val[(ci * 9 + k) * 8 + pix] = __float2bfloat16(g);
    }
    __syncthreads();

    const int co = tid;
    float acc[8];
    float bv = bias[co];
    #pragma unroll
    for (int p = 0; p < 8; p++) acc[p] = bv;

    const uint4* vp = (const uint4*)val;
    #pragma unroll 2
    for (int idx = 0; idx < 1152; idx++) {
        float wv = b2f(wT[idx * 256 + co]);
        uint4 pv = vp[idx];               // 8 bf16, broadcast ds_read_b128
        acc[0] += wv * bflo(pv.x); acc[1] += wv * bfhi(pv.x);
        acc[2] += wv * bflo(pv.y); acc[3] += wv * bfhi(pv.y);
        acc[4] += wv * bflo(pv.z); acc[5] += wv * bfhi(pv.z);
        acc[6] += wv * bflo(pv.w); acc[7] += wv * bfhi(pv.w);
    }
    bf16* op = out + (size_t)(b * COUT + co) * HWP + pos0;
    #pragma unroll
    for (int p = 0; p < 8; p++) op[p] = __float2bfloat16(acc[p]);
}

// ---------------------------------------------------------------- spatial attention 7x7, channel-split
// grid (16 strips, 4 b, 4 csplit), block 256
__global__ __launch_bounds__(256) void sa_kernel(
    const bf16* __restrict__ mainf, const bf16* __restrict__ contf,
    const float* __restrict__ w, float* __restrict__ part)
{
    __shared__ float wl[96 * 49];
    const int strip = blockIdx.x, b = blockIdx.y, cs = blockIdx.z;
    const int c0 = cs * 96;
    for (int i = threadIdx.x; i < 96 * 49; i += 256) wl[i] = w[c0 * 49 + i];
    __syncthreads();
    const int tx = threadIdx.x & 63, ty = threadIdx.x >> 6;
    const int y = strip * 4 + ty, x = tx;
    float acc = 0.f;
    for (int c = 0; c < 96; c++) {
        int cc = c0 + c;
        const bf16* p = (cc < 256) ? (mainf + (size_t)(b * COUT + cc) * HWP)
                                   : (contf + (size_t)(b * 128 + (cc - 256)) * HWP);
        const float* wp = wl + c * 49;
        #pragma unroll
        for (int ky = 0; ky < 7; ky++) {
            int yy = y + ky - 3;
            if (yy < 0 || yy > 63) continue;
            #pragma unroll
            for (int kx = 0; kx < 7; kx++) {
                int xx = x + kx - 3;
                if (xx < 0 || xx > 63) continue;
                acc += b2f(p[yy * 64 + xx]) * wp[ky * 7 + kx];
            }
        }
    }
    part[(size_t)(cs * 4 + b) * HWP + y * 64 + x] = acc;
}

// ---------------------------------------------------------------- attn finalize
__global__ __launch_bounds__(256) void attn_fin_kernel(
    const float* __restrict__ part, const float* __restrict__ sa_b, float* __restrict__ attn)
{
    int i = blockIdx.x * 256 + threadIdx.x;
    if (i >= BN * HWP) return;
    int b = i >> 12, pos = i & 4095;
    float s = part[(size_t)(0 * 4 + b) * HWP + pos] + part[(size_t)(1 * 4 + b) * HWP + pos]
            + part[(size_t)(2 * 4 + b) * HWP + pos] + part[(size_t)(3 * 4 + b) * HWP + pos]
            + sa_b[0];
    attn[i] = 1.f / (1.f + expf(-s));
}

// ---------------------------------------------------------------- fusion 1x1 (384->256) + BN + ReLU -> fp32
// conv(attn*combined) == attn * conv(combined) since attn is per-pixel scalar
__global__ __launch_bounds__(256) void fuse_kernel(
    const bf16* __restrict__ mainf, const bf16* __restrict__ contf, const float* __restrict__ attn,
    const float* __restrict__ w, const float* __restrict__ bias,
    const float* __restrict__ bn_g, const float* __restrict__ bn_b,
    const float* __restrict__ bn_m, const float* __restrict__ bn_v,
    float* __restrict__ out)
{
    __shared__ float wl[8 * 384];
    const int cog = blockIdx.x, strip = blockIdx.y, b = blockIdx.z;
    const int co0 = cog * 8;
    for (int i = threadIdx.x; i < 8 * 384; i += 256) wl[i] = w[co0 * 384 + i];
    __syncthreads();
    const int tx = threadIdx.x & 63, ty = threadIdx.x >> 6;
    const int pos = (strip * 4 + ty) * 64 + tx;
    float a = attn[b * HWP + pos];
    float acc[8];
    #pragma unroll
    for (int cs = 0; cs < 8; cs++) acc[cs] = 0.f;
    const bf16* mp = mainf + (size_t)b * COUT * HWP + pos;
    for (int ci = 0; ci < 256; ci++) {
        float v = b2f(mp[ci * HWP]);
        #pragma unroll
        for (int cs = 0; cs < 8; cs++) acc[cs] += v * wl[cs * 384 + ci];
    }
    const bf16* cp = contf + (size_t)b * 128 * HWP + pos;
    for (int ci = 0; ci < 128; ci++) {
        float v = b2f(cp[ci * HWP]);
        #pragma unroll
        for (int cs = 0; cs < 8; cs++) acc[cs] += v * wl[cs * 384 + 256 + ci];
    }
    #pragma unroll
    for (int cs = 0; cs < 8; cs++) {
        int co = co0 + cs;
        float o = acc[cs] * a + bias[co];
        float sc = bn_g[co] / sqrtf(bn_v[co] + 1e-5f);
        o = (o - bn_m[co]) * sc + bn_b[co];
        o = fmaxf(o, 0.f);
        out[(size_t)(b * COUT + co) * HWP + pos] = o;
    }
}

// ================================================================ launch
extern "C" void kernel_launch(void* const* d_in, const int* in_sizes, int n_in,
                              void* d_out, int out_size, void* d_ws, size_t ws_size,
                              hipStream_t stream)
{
    const float* x      = (const float*)d_in[0];
    const float* oc1_w  = (const float*)d_in[1];
    const float* oc1_b  = (const float*)d_in[2];
    const float* obn_g  = (const float*)d_in[3];
    const float* obn_b  = (const float*)d_in[4];
    const float* obn_m  = (const float*)d_in[5];
    const float* obn_v  = (const float*)d_in[6];
    const float* oc2_w  = (const float*)d_in[7];
    const float* oc2_b  = (const float*)d_in[8];
    const float* mc1_w  = (const float*)d_in[9];
    const float* mc1_b  = (const float*)d_in[10];
    const float* mbn_g  = (const float*)d_in[11];
    const float* mbn_b  = (const float*)d_in[12];
    const float* mbn_m  = (const float*)d_in[13];
    const float* mbn_v  = (const float*)d_in[14];
    const float* mc2_w  = (const float*)d_in[15];
    const float* mc2_b  = (const float*)d_in[16];
    const float* dc_w   = (const float*)d_in[17];
    const float* dc_b   = (const float*)d_in[18];
    const float* cb_dw_w= (const float*)d_in[19];
    const float* cb_dw_b= (const float*)d_in[20];
    const float* cbn_g  = (const float*)d_in[21];
    const float* cbn_b  = (const float*)d_in[22];
    const float* cbn_m  = (const float*)d_in[23];
    const float* cbn_v  = (const float*)d_in[24];
    const float* cb_pw_w= (const float*)d_in[25];
    const float* cb_pw_b= (const float*)d_in[26];
    const float* sa_w   = (const float*)d_in[27];
    const float* sa_b   = (const float*)d_in[28];
    const float* fu_w   = (const float*)d_in[29];
    const float* fu_b   = (const float*)d_in[30];
    const float* fbn_g  = (const float*)d_in[31];
    const float* fbn_b  = (const float*)d_in[32];
    const float* fbn_m  = (const float*)d_in[33];
    const float* fbn_v  = (const float*)d_in[34];

    // workspace layout (~20.7 MB)
    bf16*  h     = (bf16*)d_ws;                //   524,288 bf16
    bf16*  hm    = h + 524288;                 //   524,288 bf16
    float* offsb = (float*)(hm + 524288);      //   294,912 f32
    float* mskb  = offsb + 294912;             //   147,456 f32
    bf16*  hc    = (bf16*)(mskb + 147456);     // 2,097,152 bf16
    bf16*  cont  = hc + 2097152;               // 2,097,152 bf16
    bf16*  mainf = cont + 2097152;             // 4,194,304 bf16
    float* part  = (float*)(mainf + 4194304);  //    65,536 f32
    float* attn  = part + 65536;               //    16,384 f32
    bf16*  wT    = (bf16*)(attn + 16384);      //   294,912 bf16

    float* out = (float*)d_out;

    // 1. transpose + cast main deform weight
    prep_wT_kernel<<<1152, 256, 0, stream>>>(dc_w, wT);
    // 2. offset branch conv1 (+BN+ReLU)
    conv3x3_kernel<1, 1><<<dim3(32, 16, 4), 256, 128 * 9 * 4, stream>>>(
        x, oc1_w, oc1_b, obn_g, obn_b, obn_m, obn_v, h, 128, 32);
    // 3. offset conv2 (raw, fp32 out)
    conv3x3_kernel<0, 0><<<dim3(18, 16, 4), 256, 32 * 9 * 4, stream>>>(
        h, oc2_w, oc2_b, (const float*)nullptr, (const float*)nullptr,
        (const float*)nullptr, (const float*)nullptr, offsb, 32, 18);
    // 4. mask branch conv1 (+BN+ReLU)
    conv3x3_kernel<1, 1><<<dim3(32, 16, 4), 256, 128 * 9 * 4, stream>>>(
        x, mc1_w, mc1_b, mbn_g, mbn_b, mbn_m, mbn_v, hm, 128, 32);
    // 5. mask conv2 (+sigmoid, fp32 out)
    conv3x3_kernel<2, 0><<<dim3(9, 16, 4), 256, 32 * 9 * 4, stream>>>(
        hm, mc2_w, mc2_b, (const float*)nullptr, (const float*)nullptr,
        (const float*)nullptr, (const float*)nullptr, mskb, 32, 9);
    // 6. contour depthwise (+BN+ReLU)
    dwconv_kernel<<<8192, 256, 0, stream>>>(x, cb_dw_w, cb_dw_b, cbn_g, cbn_b, cbn_m, cbn_v, hc);
    // 7. contour pointwise
    pw_kernel<<<dim3(16, 16, 4), 256, 0, stream>>>(hc, cb_pw_w, cb_pw_b, cont, 128, 128);
    // 8. modulated deformable conv
    deform_kernel<<<2048, 256, 0, stream>>>(x, offsb, mskb, wT, dc_b, mainf);
    // 9. spatial attention partials (7x7)
    sa_kernel<<<dim3(16, 4, 4), 256, 0, stream>>>(mainf, cont, sa_w, part);
    // 10. attn finalize
    attn_fin_kernel<<<64, 256, 0, stream>>>(part, sa_b, attn);
    // 11. fusion 1x1 + BN + ReLU -> fp32 out
    fuse_kernel<<<dim3(32, 16, 4), 256, 0, stream>>>(
        mainf, cont, attn, fu_w, fu_b, fbn_g, fbn_b, fbn_m, fbn_v, out);
}

// Round 4
// 1103.698 us; speedup vs baseline: 1.3240x; 1.3240x over previous
//
#include <hip/hip_runtime.h>
#include <hip/hip_bf16.h>
#include <math.h>

// Problem constants
#define BN   4
#define CIN  128
#define COUT 256
#define HWP  4096      // 64*64

typedef __hip_bfloat16 bf16;

__device__ __forceinline__ float b2f(bf16 v) { return __bfloat162float(v); }
__device__ __forceinline__ float bflo(unsigned u) { return __uint_as_float(u << 16); }
__device__ __forceinline__ float bfhi(unsigned u) { return __uint_as_float(u & 0xffff0000u); }

__device__ __forceinline__ float ldv(const float* p, size_t i) { return p[i]; }
__device__ __forceinline__ float ldv(const bf16* p, size_t i) { return b2f(p[i]); }
__device__ __forceinline__ void stv(float* p, size_t i, float v) { p[i] = v; }
__device__ __forceinline__ void stv(bf16* p, size_t i, float v) { p[i] = __float2bfloat16(v); }

// ------------------------------------------------- dc_w (co, ci*9+k) f32 -> wT (idx, co) bf16
__global__ __launch_bounds__(256) void prep_wT_kernel(const float* __restrict__ w,
                                                      bf16* __restrict__ wT) {
    int j = blockIdx.x * 256 + threadIdx.x;   // j = idx*256 + co
    if (j < 1152 * 256) {
        int idx = j >> 8, co = j & 255;
        wT[j] = __float2bfloat16(w[co * 1152 + idx]);
    }
}

// ---------------------------------------------------------------- generic 3x3 conv
// grid (CO, 16, B), block 256 = 64x * 4y. ACT: 0=none 1=relu 2=sigmoid
template<int ACT, int USE_BN, typename IT, typename OT>
__global__ __launch_bounds__(256) void conv3x3_kernel(
    const IT* __restrict__ in, const float* __restrict__ w, const float* __restrict__ bias,
    const float* __restrict__ bn_g, const float* __restrict__ bn_b,
    const float* __restrict__ bn_m, const float* __restrict__ bn_v,
    OT* __restrict__ out, int CI, int CO)
{
    extern __shared__ float wl[];          // CI*9 floats
    const int co = blockIdx.x, strip = blockIdx.y, b = blockIdx.z;
    const int nt = CI * 9;
    for (int i = threadIdx.x; i < nt; i += 256) wl[i] = w[co * nt + i];
    __syncthreads();

    const int tx = threadIdx.x & 63, ty = threadIdx.x >> 6;
    const int y = strip * 4 + ty, x = tx;
    float acc = bias[co];
    const IT* ip = in + (size_t)(b * CI) * HWP;
    for (int ci = 0; ci < CI; ci++) {
        const IT* p = ip + ci * HWP;
        const float* wp = wl + ci * 9;
        #pragma unroll
        for (int ky = 0; ky < 3; ky++) {
            int yy = y + ky - 1;
            if (yy < 0 || yy > 63) continue;
            #pragma unroll
            for (int kx = 0; kx < 3; kx++) {
                int xx = x + kx - 1;
                if (xx < 0 || xx > 63) continue;
                acc += ldv(p, yy * 64 + xx) * wp[ky * 3 + kx];
            }
        }
    }
    if (USE_BN) {
        float sc = bn_g[co] / sqrtf(bn_v[co] + 1e-5f);
        acc = (acc - bn_m[co]) * sc + bn_b[co];
    }
    if (ACT == 1) acc = fmaxf(acc, 0.f);
    else if (ACT == 2) acc = 1.f / (1.f + expf(-acc));
    stv(out, (size_t)(b * CO + co) * HWP + y * 64 + x, acc);
}

// ---------------------------------------------------------------- depthwise 3x3 + BN + ReLU
__global__ __launch_bounds__(256) void dwconv_kernel(
    const float* __restrict__ in, const float* __restrict__ w, const float* __restrict__ bias,
    const float* __restrict__ bn_g, const float* __restrict__ bn_b,
    const float* __restrict__ bn_m, const float* __restrict__ bn_v,
    bf16* __restrict__ out)
{
    int i = blockIdx.x * 256 + threadIdx.x;
    if (i >= BN * CIN * HWP) return;
    int x = i & 63, y = (i >> 6) & 63, c = (i >> 12) & 127;
    int b = i >> 19;
    float acc = bias[c];
    const float* p = in + (size_t)(b * CIN + c) * HWP;
    #pragma unroll
    for (int ky = 0; ky < 3; ky++) {
        int yy = y + ky - 1;
        if (yy < 0 || yy > 63) continue;
        #pragma unroll
        for (int kx = 0; kx < 3; kx++) {
            int xx = x + kx - 1;
            if (xx < 0 || xx > 63) continue;
            acc += p[yy * 64 + xx] * w[c * 9 + ky * 3 + kx];
        }
    }
    float sc = bn_g[c] / sqrtf(bn_v[c] + 1e-5f);
    acc = (acc - bn_m[c]) * sc + bn_b[c];
    acc = fmaxf(acc, 0.f);
    out[i] = __float2bfloat16(acc);
}

// ---------------------------------------------------------------- pointwise 1x1 (contour pw)
__global__ __launch_bounds__(256) void pw_kernel(
    const bf16* __restrict__ in, const float* __restrict__ w, const float* __restrict__ bias,
    bf16* __restrict__ out, int CI, int CO)
{
    __shared__ float wl[8 * 128];
    const int cog = blockIdx.x, strip = blockIdx.y, b = blockIdx.z;
    const int co0 = cog * 8;
    for (int i = threadIdx.x; i < 8 * CI; i += 256) wl[i] = w[co0 * CI + i];
    __syncthreads();
    const int tx = threadIdx.x & 63, ty = threadIdx.x >> 6;
    const int pos = (strip * 4 + ty) * 64 + tx;
    float acc[8];
    #pragma unroll
    for (int cs = 0; cs < 8; cs++) acc[cs] = bias[co0 + cs];
    const bf16* ip = in + (size_t)b * CI * HWP + pos;
    for (int ci = 0; ci < CI; ci++) {
        float v = b2f(ip[ci * HWP]);
        #pragma unroll
        for (int cs = 0; cs < 8; cs++) acc[cs] += v * wl[cs * CI + ci];
    }
    #pragma unroll
    for (int cs = 0; cs < 8; cs++)
        out[(size_t)(b * CO + co0 + cs) * HWP + pos] = __float2bfloat16(acc[cs]);
}

// ---------------------------------------------------------------- modulated deformable conv
// grid 2048 (= B * 512 tiles of 8 pixels), block 256. LDS ~20.7 KB.
__global__ __launch_bounds__(256) void deform_kernel(
    const float* __restrict__ x, const float* __restrict__ offs, const float* __restrict__ msk,
    const bf16* __restrict__ wT, const float* __restrict__ bias, bf16* __restrict__ out)
{
    __shared__ __align__(16) bf16 val[1152 * 8];   // [ci*9+k][pix], 18432 B
    __shared__ int   ci4[72][4];
    __shared__ float cw4[72][4];

    const int bid = blockIdx.x;
    const int b = bid >> 9;
    const int tile = bid & 511;
    const int pos0 = tile * 8;
    const int tid = threadIdx.x;

    if (tid < 72) {                       // pair = k*8 + pix
        int k = tid >> 3, pix = tid & 7;
        int pos = pos0 + pix;
        int y = pos >> 6, xc = pos & 63;
        float offy = offs[(size_t)(b * 18 + 2 * k) * HWP + pos];
        float offx = offs[(size_t)(b * 18 + 2 * k + 1) * HWP + pos];
        float m = msk[(size_t)(b * 9 + k) * HWP + pos];
        float py = (float)(y - 1 + k / 3) + offy;
        float px = (float)(xc - 1 + k % 3) + offx;
        float fy = floorf(py), fx = floorf(px);
        float wy1 = py - fy, wx1 = px - fx;
        int y0 = (int)fy, x0 = (int)fx;
        int y1 = y0 + 1, x1 = x0 + 1;
        bool vy0 = (y0 >= 0 && y0 <= 63), vy1 = (y1 >= 0 && y1 <= 63);
        bool vx0 = (x0 >= 0 && x0 <= 63), vx1 = (x1 >= 0 && x1 <= 63);
        int cy0 = min(max(y0, 0), 63), cy1 = min(max(y1, 0), 63);
        int cx0 = min(max(x0, 0), 63), cx1 = min(max(x1, 0), 63);
        ci4[tid][0] = cy0 * 64 + cx0;  cw4[tid][0] = (vy0 && vx0) ? (1.f - wy1) * (1.f - wx1) * m : 0.f;
        ci4[tid][1] = cy0 * 64 + cx1;  cw4[tid][1] = (vy0 && vx1) ? (1.f - wy1) * wx1 * m : 0.f;
        ci4[tid][2] = cy1 * 64 + cx0;  cw4[tid][2] = (vy1 && vx0) ? wy1 * (1.f - wx1) * m : 0.f;
        ci4[tid][3] = cy1 * 64 + cx1;  cw4[tid][3] = (vy1 && vx1) ? wy1 * wx1 * m : 0.f;
    }
    __syncthreads();

    const float* xb = x + (size_t)b * CIN * HWP;
    for (int i = 0; i < 36; i++) {        // 9216 gathers / 256 threads
        int jj = tid + 256 * i;
        int ci = jj / 72, pr = jj - ci * 72;
        const float* p = xb + ci * HWP;
        float g = cw4[pr][0] * p[ci4[pr][0]] + cw4[pr][1] * p[ci4[pr][1]]
                + cw4[pr][2] * p[ci4[pr][2]] + cw4[pr][3] * p[ci4[pr][3]];
        int k = pr >> 3, pix = pr & 7;
        val[(ci * 9 + k) * 8 + pix] = __float2bfloat16(g);
    }
    __syncthreads();

    const int co = tid;
    float acc[8];
    float bv = bias[co];
    #pragma unroll
    for (int p = 0; p < 8; p++) acc[p] = bv;

    const uint4* vp = (const uint4*)val;
    #pragma unroll 2
    for (int idx = 0; idx < 1152; idx++) {
        float wv = b2f(wT[idx * 256 + co]);
        uint4 pv = vp[idx];               // 8 bf16, broadcast ds_read_b128
        acc[0] += wv * bflo(pv.x); acc[1] += wv * bfhi(pv.x);
        acc[2] += wv * bflo(pv.y); acc[3] += wv * bfhi(pv.y);
        acc[4] += wv * bflo(pv.z); acc[5] += wv * bfhi(pv.z);
        acc[6] += wv * bflo(pv.w); acc[7] += wv * bfhi(pv.w);
    }
    bf16* op = out + (size_t)(b * COUT + co) * HWP + pos0;
    #pragma unroll
    for (int p = 0; p < 8; p++) op[p] = __float2bfloat16(acc[p]);
}

// ---------------------------------------------------------------- spatial attention: GEMM phase
// D[cs][j][b][pos] = sum_{c in cs-split} w[c*49+j] * feat[c][b][pos]
// grid (16 pos-chunks, 4 b, 4 cs), block 256. Weights read wave-uniform (s_load path).
__global__ __launch_bounds__(256) void sa_gemm_kernel(
    const bf16* __restrict__ mainf, const bf16* __restrict__ contf,
    const float* __restrict__ w, float* __restrict__ part)
{
    const int chunk = blockIdx.x, b = blockIdx.y, cs = blockIdx.z;
    const int pos = chunk * 256 + threadIdx.x;
    const int c0 = cs * 96;
    float acc[49];
    #pragma unroll
    for (int j = 0; j < 49; j++) acc[j] = 0.f;

    for (int ci = 0; ci < 96; ci += 8) {
        float v[8];
        #pragma unroll
        for (int u = 0; u < 8; u++) {
            int cc = c0 + ci + u;
            const bf16* p = (cc < 256) ? (mainf + (size_t)(b * COUT + cc) * HWP)
                                       : (contf + (size_t)(b * 128 + (cc - 256)) * HWP);
            v[u] = b2f(p[pos]);
        }
        #pragma unroll
        for (int j = 0; j < 49; j++) {
            #pragma unroll
            for (int u = 0; u < 8; u++)
                acc[j] += v[u] * w[(c0 + ci + u) * 49 + j];   // uniform -> scalar load
        }
    }
    #pragma unroll
    for (int j = 0; j < 49; j++)
        part[(size_t)((cs * 49 + j) * BN + b) * HWP + pos] = acc[j];
}

// ---------------------------------------------------------------- attn finalize: 49-tap shifted sum of D
__global__ __launch_bounds__(256) void attn_fin_kernel(
    const float* __restrict__ part, const float* __restrict__ sa_b, float* __restrict__ attn)
{
    int i = blockIdx.x * 256 + threadIdx.x;
    if (i >= BN * HWP) return;
    int b = i >> 12, pos = i & 4095;
    int y = pos >> 6, x = pos & 63;
    float s = sa_b[0];
    #pragma unroll
    for (int j = 0; j < 49; j++) {
        int yy = y + j / 7 - 3, xx = x + j % 7 - 3;
        if (yy < 0 || yy > 63 || xx < 0 || xx > 63) continue;
        int p2 = yy * 64 + xx;
        s += part[(size_t)((0 * 49 + j) * BN + b) * HWP + p2]
           + part[(size_t)((1 * 49 + j) * BN + b) * HWP + p2]
           + part[(size_t)((2 * 49 + j) * BN + b) * HWP + p2]
           + part[(size_t)((3 * 49 + j) * BN + b) * HWP + p2];
    }
    attn[i] = 1.f / (1.f + expf(-s));
}

// ---------------------------------------------------------------- fusion 1x1 (384->256) + BN + ReLU -> fp32
// conv(attn*combined) == attn * conv(combined) since attn is per-pixel scalar
__global__ __launch_bounds__(256) void fuse_kernel(
    const bf16* __restrict__ mainf, const bf16* __restrict__ contf, const float* __restrict__ attn,
    const float* __restrict__ w, const float* __restrict__ bias,
    const float* __restrict__ bn_g, const float* __restrict__ bn_b,
    const float* __restrict__ bn_m, const float* __restrict__ bn_v,
    float* __restrict__ out)
{
    __shared__ float wl[8 * 384];
    const int cog = blockIdx.x, strip = blockIdx.y, b = blockIdx.z;
    const int co0 = cog * 8;
    for (int i = threadIdx.x; i < 8 * 384; i += 256) wl[i] = w[co0 * 384 + i];
    __syncthreads();
    const int tx = threadIdx.x & 63, ty = threadIdx.x >> 6;
    const int pos = (strip * 4 + ty) * 64 + tx;
    float a = attn[b * HWP + pos];
    float acc[8];
    #pragma unroll
    for (int cs = 0; cs < 8; cs++) acc[cs] = 0.f;
    const bf16* mp = mainf + (size_t)b * COUT * HWP + pos;
    for (int ci = 0; ci < 256; ci++) {
        float v = b2f(mp[ci * HWP]);
        #pragma unroll
        for (int cs = 0; cs < 8; cs++) acc[cs] += v * wl[cs * 384 + ci];
    }
    const bf16* cp = contf + (size_t)b * 128 * HWP + pos;
    for (int ci = 0; ci < 128; ci++) {
        float v = b2f(cp[ci * HWP]);
        #pragma unroll
        for (int cs = 0; cs < 8; cs++) acc[cs] += v * wl[cs * 384 + 256 + ci];
    }
    #pragma unroll
    for (int cs = 0; cs < 8; cs++) {
        int co = co0 + cs;
        float o = acc[cs] * a + bias[co];
        float sc = bn_g[co] / sqrtf(bn_v[co] + 1e-5f);
        o = (o - bn_m[co]) * sc + bn_b[co];
        o = fmaxf(o, 0.f);
        out[(size_t)(b * COUT + co) * HWP + pos] = o;
    }
}

// ================================================================ launch
extern "C" void kernel_launch(void* const* d_in, const int* in_sizes, int n_in,
                              void* d_out, int out_size, void* d_ws, size_t ws_size,
                              hipStream_t stream)
{
    const float* x      = (const float*)d_in[0];
    const float* oc1_w  = (const float*)d_in[1];
    const float* oc1_b  = (const float*)d_in[2];
    const float* obn_g  = (const float*)d_in[3];
    const float* obn_b  = (const float*)d_in[4];
    const float* obn_m  = (const float*)d_in[5];
    const float* obn_v  = (const float*)d_in[6];
    const float* oc2_w  = (const float*)d_in[7];
    const float* oc2_b  = (const float*)d_in[8];
    const float* mc1_w  = (const float*)d_in[9];
    const float* mc1_b  = (const float*)d_in[10];
    const float* mbn_g  = (const float*)d_in[11];
    const float* mbn_b  = (const float*)d_in[12];
    const float* mbn_m  = (const float*)d_in[13];
    const float* mbn_v  = (const float*)d_in[14];
    const float* mc2_w  = (const float*)d_in[15];
    const float* mc2_b  = (const float*)d_in[16];
    const float* dc_w   = (const float*)d_in[17];
    const float* dc_b   = (const float*)d_in[18];
    const float* cb_dw_w= (const float*)d_in[19];
    const float* cb_dw_b= (const float*)d_in[20];
    const float* cbn_g  = (const float*)d_in[21];
    const float* cbn_b  = (const float*)d_in[22];
    const float* cbn_m  = (const float*)d_in[23];
    const float* cbn_v  = (const float*)d_in[24];
    const float* cb_pw_w= (const float*)d_in[25];
    const float* cb_pw_b= (const float*)d_in[26];
    const float* sa_w   = (const float*)d_in[27];
    const float* sa_b   = (const float*)d_in[28];
    const float* fu_w   = (const float*)d_in[29];
    const float* fu_b   = (const float*)d_in[30];
    const float* fbn_g  = (const float*)d_in[31];
    const float* fbn_b  = (const float*)d_in[32];
    const float* fbn_m  = (const float*)d_in[33];
    const float* fbn_v  = (const float*)d_in[34];

    // workspace layout (~34.1 MB)
    bf16*  h     = (bf16*)d_ws;                //   524,288 bf16
    bf16*  hm    = h + 524288;                 //   524,288 bf16
    float* offsb = (float*)(hm + 524288);      //   294,912 f32
    float* mskb  = offsb + 294912;             //   147,456 f32
    bf16*  hc    = (bf16*)(mskb + 147456);     // 2,097,152 bf16
    bf16*  cont  = hc + 2097152;               // 2,097,152 bf16
    bf16*  mainf = cont + 2097152;             // 4,194,304 bf16
    float* part  = (float*)(mainf + 4194304);  // 3,211,264 f32 (4cs x 49 x B x HWP)
    float* attn  = part + 3211264;             //    16,384 f32
    bf16*  wT    = (bf16*)(attn + 16384);      //   294,912 bf16

    float* out = (float*)d_out;

    // 1. transpose + cast main deform weight
    prep_wT_kernel<<<1152, 256, 0, stream>>>(dc_w, wT);
    // 2. offset branch conv1 (+BN+ReLU)
    conv3x3_kernel<1, 1><<<dim3(32, 16, 4), 256, 128 * 9 * 4, stream>>>(
        x, oc1_w, oc1_b, obn_g, obn_b, obn_m, obn_v, h, 128, 32);
    // 3. offset conv2 (raw, fp32 out)
    conv3x3_kernel<0, 0><<<dim3(18, 16, 4), 256, 32 * 9 * 4, stream>>>(
        h, oc2_w, oc2_b, (const float*)nullptr, (const float*)nullptr,
        (const float*)nullptr, (const float*)nullptr, offsb, 32, 18);
    // 4. mask branch conv1 (+BN+ReLU)
    conv3x3_kernel<1, 1><<<dim3(32, 16, 4), 256, 128 * 9 * 4, stream>>>(
        x, mc1_w, mc1_b, mbn_g, mbn_b, mbn_m, mbn_v, hm, 128, 32);
    // 5. mask conv2 (+sigmoid, fp32 out)
    conv3x3_kernel<2, 0><<<dim3(9, 16, 4), 256, 32 * 9 * 4, stream>>>(
        hm, mc2_w, mc2_b, (const float*)nullptr, (const float*)nullptr,
        (const float*)nullptr, (const float*)nullptr, mskb, 32, 9);
    // 6. contour depthwise (+BN+ReLU)
    dwconv_kernel<<<8192, 256, 0, stream>>>(x, cb_dw_w, cb_dw_b, cbn_g, cbn_b, cbn_m, cbn_v, hc);
    // 7. contour pointwise
    pw_kernel<<<dim3(16, 16, 4), 256, 0, stream>>>(hc, cb_pw_w, cb_pw_b, cont, 128, 128);
    // 8. modulated deformable conv
    deform_kernel<<<2048, 256, 0, stream>>>(x, offsb, mskb, wT, dc_b, mainf);
    // 9. spatial attention GEMM phase (49 x 384 x 16384)
    sa_gemm_kernel<<<dim3(16, 4, 4), 256, 0, stream>>>(mainf, cont, sa_w, part);
    // 10. attn finalize (49-tap shifted sum + sigmoid)
    attn_fin_kernel<<<64, 256, 0, stream>>>(part, sa_b, attn);
    // 11. fusion 1x1 + BN + ReLU -> fp32 out
    fuse_kernel<<<dim3(32, 16, 4), 256, 0, stream>>>(
        mainf, cont, attn, fu_w, fu_b, fbn_g, fbn_b, fbn_m, fbn_v, out);
}

// Round 5
// 930.337 us; speedup vs baseline: 1.5707x; 1.1863x over previous
//
#include <hip/hip_runtime.h>
#include <hip/hip_bf16.h>
#include <math.h>

// Problem constants
#define BN   4
#define CIN  128
#define COUT 256
#define HWP  4096      // 64*64

typedef __hip_bfloat16 bf16;
typedef __attribute__((ext_vector_type(8))) short sh8;    // 8 bf16 = 4 VGPR
typedef __attribute__((ext_vector_type(4))) float f32x4;  // MFMA accumulator

__device__ __forceinline__ float b2f(bf16 v) { return __bfloat162float(v); }
__device__ __forceinline__ unsigned short f2bfbits(float f) {
    union { bf16 h; unsigned short u; } cv; cv.h = __float2bfloat16(f); return cv.u;
}

__device__ __forceinline__ float ldv(const float* p, size_t i) { return p[i]; }
__device__ __forceinline__ float ldv(const bf16* p, size_t i) { return b2f(p[i]); }
__device__ __forceinline__ void stv(float* p, size_t i, float v) { p[i] = v; }
__device__ __forceinline__ void stv(bf16* p, size_t i, float v) { p[i] = __float2bfloat16(v); }

// ------------------------------------------------- dc_w[co][ci*9+k] f32 -> wB[co][k*128+ci] bf16
__global__ __launch_bounds__(256) void prep_wB_kernel(const float* __restrict__ w,
                                                      bf16* __restrict__ wB) {
    int j = blockIdx.x * 256 + threadIdx.x;   // j = co*1152 + k*128 + ci
    if (j < 256 * 1152) {
        int co = j / 1152, rem = j - co * 1152;
        int k = rem >> 7, ci = rem & 127;
        wB[j] = __float2bfloat16(w[co * 1152 + ci * 9 + k]);
    }
}

// ---------------------------------------------------------------- generic 3x3 conv
template<int ACT, int USE_BN, typename IT, typename OT>
__global__ __launch_bounds__(256) void conv3x3_kernel(
    const IT* __restrict__ in, const float* __restrict__ w, const float* __restrict__ bias,
    const float* __restrict__ bn_g, const float* __restrict__ bn_b,
    const float* __restrict__ bn_m, const float* __restrict__ bn_v,
    OT* __restrict__ out, int CI, int CO)
{
    extern __shared__ float wl[];          // CI*9 floats
    const int co = blockIdx.x, strip = blockIdx.y, b = blockIdx.z;
    const int nt = CI * 9;
    for (int i = threadIdx.x; i < nt; i += 256) wl[i] = w[co * nt + i];
    __syncthreads();

    const int tx = threadIdx.x & 63, ty = threadIdx.x >> 6;
    const int y = strip * 4 + ty, x = tx;
    float acc = bias[co];
    const IT* ip = in + (size_t)(b * CI) * HWP;
    for (int ci = 0; ci < CI; ci++) {
        const IT* p = ip + ci * HWP;
        const float* wp = wl + ci * 9;
        #pragma unroll
        for (int ky = 0; ky < 3; ky++) {
            int yy = y + ky - 1;
            if (yy < 0 || yy > 63) continue;
            #pragma unroll
            for (int kx = 0; kx < 3; kx++) {
                int xx = x + kx - 1;
                if (xx < 0 || xx > 63) continue;
                acc += ldv(p, yy * 64 + xx) * wp[ky * 3 + kx];
            }
        }
    }
    if (USE_BN) {
        float sc = bn_g[co] / sqrtf(bn_v[co] + 1e-5f);
        acc = (acc - bn_m[co]) * sc + bn_b[co];
    }
    if (ACT == 1) acc = fmaxf(acc, 0.f);
    else if (ACT == 2) acc = 1.f / (1.f + expf(-acc));
    stv(out, (size_t)(b * CO + co) * HWP + y * 64 + x, acc);
}

// ---------------------------------------------------------------- depthwise 3x3 + BN + ReLU
__global__ __launch_bounds__(256) void dwconv_kernel(
    const float* __restrict__ in, const float* __restrict__ w, const float* __restrict__ bias,
    const float* __restrict__ bn_g, const float* __restrict__ bn_b,
    const float* __restrict__ bn_m, const float* __restrict__ bn_v,
    bf16* __restrict__ out)
{
    int i = blockIdx.x * 256 + threadIdx.x;
    if (i >= BN * CIN * HWP) return;
    int x = i & 63, y = (i >> 6) & 63, c = (i >> 12) & 127;
    int b = i >> 19;
    float acc = bias[c];
    const float* p = in + (size_t)(b * CIN + c) * HWP;
    #pragma unroll
    for (int ky = 0; ky < 3; ky++) {
        int yy = y + ky - 1;
        if (yy < 0 || yy > 63) continue;
        #pragma unroll
        for (int kx = 0; kx < 3; kx++) {
            int xx = x + kx - 1;
            if (xx < 0 || xx > 63) continue;
            acc += p[yy * 64 + xx] * w[c * 9 + ky * 3 + kx];
        }
    }
    float sc = bn_g[c] / sqrtf(bn_v[c] + 1e-5f);
    acc = (acc - bn_m[c]) * sc + bn_b[c];
    acc = fmaxf(acc, 0.f);
    out[i] = __float2bfloat16(acc);
}

// ---------------------------------------------------------------- pointwise 1x1 (contour pw)
__global__ __launch_bounds__(256) void pw_kernel(
    const bf16* __restrict__ in, const float* __restrict__ w, const float* __restrict__ bias,
    bf16* __restrict__ out, int CI, int CO)
{
    __shared__ float wl[8 * 128];
    const int cog = blockIdx.x, strip = blockIdx.y, b = blockIdx.z;
    const int co0 = cog * 8;
    for (int i = threadIdx.x; i < 8 * CI; i += 256) wl[i] = w[co0 * CI + i];
    __syncthreads();
    const int tx = threadIdx.x & 63, ty = threadIdx.x >> 6;
    const int pos = (strip * 4 + ty) * 64 + tx;
    float acc[8];
    #pragma unroll
    for (int cs = 0; cs < 8; cs++) acc[cs] = bias[co0 + cs];
    const bf16* ip = in + (size_t)b * CI * HWP + pos;
    for (int ci = 0; ci < CI; ci++) {
        float v = b2f(ip[ci * HWP]);
        #pragma unroll
        for (int cs = 0; cs < 8; cs++) acc[cs] += v * wl[cs * CI + ci];
    }
    #pragma unroll
    for (int cs = 0; cs < 8; cs++)
        out[(size_t)(b * CO + co0 + cs) * HWP + pos] = __float2bfloat16(acc[cs]);
}

// ---------------------------------------------------------------- modulated deformable conv (MFMA)
// grid 1024 (= B * 256 tiles of 16 pixels), block 256 = 4 waves. LDS 41.7 KB -> 3 blocks/CU.
// K ordering: kk = k*128 + ci  (wB permuted to match). C = W(256x1152) * V(1152x16).
__global__ __launch_bounds__(256) void deform_kernel(
    const float* __restrict__ x, const float* __restrict__ offs, const float* __restrict__ msk,
    const bf16* __restrict__ wB, const float* __restrict__ bias, bf16* __restrict__ out)
{
    __shared__ __align__(16) bf16 val[16][1160];   // [pix][kk], pad 1152->1160 (2-way = free)
    __shared__ int   ti[144][4];                   // e = k*16+pix -> 4 corner indices
    __shared__ float tw[144][4];                   // 4 corner weights (mask folded in)

    const int bid = blockIdx.x;
    const int b = bid >> 8;
    const int tile = bid & 255;
    const int pos0 = tile * 16;
    const int tid = threadIdx.x;

    if (tid < 144) {                      // e = k*16 + pix
        int k = tid >> 4, pix = tid & 15;
        int pos = pos0 + pix;
        int y = pos >> 6, xc = pos & 63;
        float offy = offs[(size_t)(b * 18 + 2 * k) * HWP + pos];
        float offx = offs[(size_t)(b * 18 + 2 * k + 1) * HWP + pos];
        float m = msk[(size_t)(b * 9 + k) * HWP + pos];
        float py = (float)(y - 1 + k / 3) + offy;
        float px = (float)(xc - 1 + k % 3) + offx;
        float fy = floorf(py), fx = floorf(px);
        float wy1 = py - fy, wx1 = px - fx;
        int y0 = (int)fy, x0 = (int)fx;
        int y1 = y0 + 1, x1 = x0 + 1;
        bool vy0 = (y0 >= 0 && y0 <= 63), vy1 = (y1 >= 0 && y1 <= 63);
        bool vx0 = (x0 >= 0 && x0 <= 63), vx1 = (x1 >= 0 && x1 <= 63);
        int cy0 = min(max(y0, 0), 63), cy1 = min(max(y1, 0), 63);
        int cx0 = min(max(x0, 0), 63), cx1 = min(max(x1, 0), 63);
        ti[tid][0] = cy0 * 64 + cx0;  tw[tid][0] = (vy0 && vx0) ? (1.f - wy1) * (1.f - wx1) * m : 0.f;
        ti[tid][1] = cy0 * 64 + cx1;  tw[tid][1] = (vy0 && vx1) ? (1.f - wy1) * wx1 * m : 0.f;
        ti[tid][2] = cy1 * 64 + cx0;  tw[tid][2] = (vy1 && vx0) ? wy1 * (1.f - wx1) * m : 0.f;
        ti[tid][3] = cy1 * 64 + cx1;  tw[tid][3] = (vy1 && vx1) ? wy1 * wx1 * m : 0.f;
    }
    __syncthreads();

    // ---- gather phase: thread owns pix = tid&15; per k-phase its corner table is registers
    {
        const int pix = tid & 15, grp = tid >> 4;
        const float* xb = x + (size_t)b * CIN * HWP;
        for (int k = 0; k < 9; k++) {
            const int e = k * 16 + pix;
            const int i0 = ti[e][0], i1 = ti[e][1], i2 = ti[e][2], i3 = ti[e][3];
            const float w0 = tw[e][0], w1 = tw[e][1], w2 = tw[e][2], w3 = tw[e][3];
            #pragma unroll
            for (int it = 0; it < 4; it++) {
                const int ci0 = (grp + 16 * it) * 2;          // even ci
                const float* p0 = xb + (size_t)ci0 * HWP;
                const float* p1 = p0 + HWP;
                float g0 = w0 * p0[i0] + w1 * p0[i1] + w2 * p0[i2] + w3 * p0[i3];
                float g1 = w0 * p1[i0] + w1 * p1[i1] + w2 * p1[i2] + w3 * p1[i3];
                unsigned pk = (unsigned)f2bfbits(g0) | ((unsigned)f2bfbits(g1) << 16);
                *(unsigned*)&val[pix][k * 128 + ci0] = pk;    // ds_write_b32, 2 lanes/bank
            }
        }
    }
    __syncthreads();

    // ---- MFMA phase: wave wv owns co [wv*64, wv*64+64) x 16 pixels
    const int lane = tid & 63, wv = tid >> 6;
    const int quad = lane >> 4, l16 = lane & 15;
    f32x4 acc[4] = {f32x4{0,0,0,0}, f32x4{0,0,0,0}, f32x4{0,0,0,0}, f32x4{0,0,0,0}};

    const bf16* wbase = wB + (size_t)(wv * 64 + l16) * 1152 + quad * 8;  // A[m=l16][k=quad*8+j]
    const bf16* vbase = &val[l16][quad * 8];                             // B[n=l16][k=quad*8+j]
    for (int kt = 0; kt < 36; kt++) {
        sh8 bfr = *(const sh8*)(vbase + kt * 32);
        #pragma unroll
        for (int mt = 0; mt < 4; mt++) {
            sh8 afr = *(const sh8*)(wbase + (size_t)mt * 16 * 1152 + kt * 32);
            acc[mt] = __builtin_amdgcn_mfma_f32_16x16x32_bf16(afr, bfr, acc[mt], 0, 0, 0);
        }
    }

    // ---- epilogue: C/D layout col=lane&15 (pix), row=quad*4+reg
    bf16* op = out + (size_t)b * COUT * HWP + pos0 + l16;
    #pragma unroll
    for (int mt = 0; mt < 4; mt++) {
        int co_b = wv * 64 + mt * 16 + quad * 4;
        #pragma unroll
        for (int r = 0; r < 4; r++) {
            int co = co_b + r;
            op[(size_t)co * HWP] = __float2bfloat16(acc[mt][r] + bias[co]);
        }
    }
}

// ---------------------------------------------------------------- spatial attention: GEMM phase
__global__ __launch_bounds__(256) void sa_gemm_kernel(
    const bf16* __restrict__ mainf, const bf16* __restrict__ contf,
    const float* __restrict__ w, float* __restrict__ part)
{
    const int chunk = blockIdx.x, b = blockIdx.y, cs = blockIdx.z;
    const int pos = chunk * 256 + threadIdx.x;
    const int c0 = cs * 96;
    float acc[49];
    #pragma unroll
    for (int j = 0; j < 49; j++) acc[j] = 0.f;

    for (int ci = 0; ci < 96; ci += 8) {
        float v[8];
        #pragma unroll
        for (int u = 0; u < 8; u++) {
            int cc = c0 + ci + u;
            const bf16* p = (cc < 256) ? (mainf + (size_t)(b * COUT + cc) * HWP)
                                       : (contf + (size_t)(b * 128 + (cc - 256)) * HWP);
            v[u] = b2f(p[pos]);
        }
        #pragma unroll
        for (int j = 0; j < 49; j++) {
            #pragma unroll
            for (int u = 0; u < 8; u++)
                acc[j] += v[u] * w[(c0 + ci + u) * 49 + j];   // uniform -> scalar load
        }
    }
    #pragma unroll
    for (int j = 0; j < 49; j++)
        part[(size_t)((cs * 49 + j) * BN + b) * HWP + pos] = acc[j];
}

// ---------------------------------------------------------------- attn finalize: 49-tap shifted sum
__global__ __launch_bounds__(256) void attn_fin_kernel(
    const float* __restrict__ part, const float* __restrict__ sa_b, float* __restrict__ attn)
{
    int i = blockIdx.x * 256 + threadIdx.x;
    if (i >= BN * HWP) return;
    int b = i >> 12, pos = i & 4095;
    int y = pos >> 6, x = pos & 63;
    float s = sa_b[0];
    #pragma unroll
    for (int j = 0; j < 49; j++) {
        int yy = y + j / 7 - 3, xx = x + j % 7 - 3;
        if (yy < 0 || yy > 63 || xx < 0 || xx > 63) continue;
        int p2 = yy * 64 + xx;
        s += part[(size_t)((0 * 49 + j) * BN + b) * HWP + p2]
           + part[(size_t)((1 * 49 + j) * BN + b) * HWP + p2]
           + part[(size_t)((2 * 49 + j) * BN + b) * HWP + p2]
           + part[(size_t)((3 * 49 + j) * BN + b) * HWP + p2];
    }
    attn[i] = 1.f / (1.f + expf(-s));
}

// ---------------------------------------------------------------- fusion 1x1 (384->256) + BN + ReLU
__global__ __launch_bounds__(256) void fuse_kernel(
    const bf16* __restrict__ mainf, const bf16* __restrict__ contf, const float* __restrict__ attn,
    const float* __restrict__ w, const float* __restrict__ bias,
    const float* __restrict__ bn_g, const float* __restrict__ bn_b,
    const float* __restrict__ bn_m, const float* __restrict__ bn_v,
    float* __restrict__ out)
{
    __shared__ float wl[8 * 384];
    const int cog = blockIdx.x, strip = blockIdx.y, b = blockIdx.z;
    const int co0 = cog * 8;
    for (int i = threadIdx.x; i < 8 * 384; i += 256) wl[i] = w[co0 * 384 + i];
    __syncthreads();
    const int tx = threadIdx.x & 63, ty = threadIdx.x >> 6;
    const int pos = (strip * 4 + ty) * 64 + tx;
    float a = attn[b * HWP + pos];
    float acc[8];
    #pragma unroll
    for (int cs = 0; cs < 8; cs++) acc[cs] = 0.f;
    const bf16* mp = mainf + (size_t)b * COUT * HWP + pos;
    for (int ci = 0; ci < 256; ci++) {
        float v = b2f(mp[ci * HWP]);
        #pragma unroll
        for (int cs = 0; cs < 8; cs++) acc[cs] += v * wl[cs * 384 + ci];
    }
    const bf16* cp = contf + (size_t)b * 128 * HWP + pos;
    for (int ci = 0; ci < 128; ci++) {
        float v = b2f(cp[ci * HWP]);
        #pragma unroll
        for (int cs = 0; cs < 8; cs++) acc[cs] += v * wl[cs * 384 + 256 + ci];
    }
    #pragma unroll
    for (int cs = 0; cs < 8; cs++) {
        int co = co0 + cs;
        float o = acc[cs] * a + bias[co];
        float sc = bn_g[co] / sqrtf(bn_v[co] + 1e-5f);
        o = (o - bn_m[co]) * sc + bn_b[co];
        o = fmaxf(o, 0.f);
        out[(size_t)(b * COUT + co) * HWP + pos] = o;
    }
}

// ================================================================ launch
extern "C" void kernel_launch(void* const* d_in, const int* in_sizes, int n_in,
                              void* d_out, int out_size, void* d_ws, size_t ws_size,
                              hipStream_t stream)
{
    const float* x      = (const float*)d_in[0];
    const float* oc1_w  = (const float*)d_in[1];
    const float* oc1_b  = (const float*)d_in[2];
    const float* obn_g  = (const float*)d_in[3];
    const float* obn_b  = (const float*)d_in[4];
    const float* obn_m  = (const float*)d_in[5];
    const float* obn_v  = (const float*)d_in[6];
    const float* oc2_w  = (const float*)d_in[7];
    const float* oc2_b  = (const float*)d_in[8];
    const float* mc1_w  = (const float*)d_in[9];
    const float* mc1_b  = (const float*)d_in[10];
    const float* mbn_g  = (const float*)d_in[11];
    const float* mbn_b  = (const float*)d_in[12];
    const float* mbn_m  = (const float*)d_in[13];
    const float* mbn_v  = (const float*)d_in[14];
    const float* mc2_w  = (const float*)d_in[15];
    const float* mc2_b  = (const float*)d_in[16];
    const float* dc_w   = (const float*)d_in[17];
    const float* dc_b   = (const float*)d_in[18];
    const float* cb_dw_w= (const float*)d_in[19];
    const float* cb_dw_b= (const float*)d_in[20];
    const float* cbn_g  = (const float*)d_in[21];
    const float* cbn_b  = (const float*)d_in[22];
    const float* cbn_m  = (const float*)d_in[23];
    const float* cbn_v  = (const float*)d_in[24];
    const float* cb_pw_w= (const float*)d_in[25];
    const float* cb_pw_b= (const float*)d_in[26];
    const float* sa_w   = (const float*)d_in[27];
    const float* sa_b   = (const float*)d_in[28];
    const float* fu_w   = (const float*)d_in[29];
    const float* fu_b   = (const float*)d_in[30];
    const float* fbn_g  = (const float*)d_in[31];
    const float* fbn_b  = (const float*)d_in[32];
    const float* fbn_m  = (const float*)d_in[33];
    const float* fbn_v  = (const float*)d_in[34];

    // workspace layout (~34.1 MB)
    bf16*  h     = (bf16*)d_ws;                //   524,288 bf16
    bf16*  hm    = h + 524288;                 //   524,288 bf16
    float* offsb = (float*)(hm + 524288);      //   294,912 f32
    float* mskb  = offsb + 294912;             //   147,456 f32
    bf16*  hc    = (bf16*)(mskb + 147456);     // 2,097,152 bf16
    bf16*  cont  = hc + 2097152;               // 2,097,152 bf16
    bf16*  mainf = cont + 2097152;             // 4,194,304 bf16
    float* part  = (float*)(mainf + 4194304);  // 3,211,264 f32 (4cs x 49 x B x HWP)
    float* attn  = part + 3211264;             //    16,384 f32
    bf16*  wB    = (bf16*)(attn + 16384);      //   294,912 bf16

    float* out = (float*)d_out;

    // 1. permute + cast main deform weight: wB[co][k*128+ci]
    prep_wB_kernel<<<1152, 256, 0, stream>>>(dc_w, wB);
    // 2. offset branch conv1 (+BN+ReLU)
    conv3x3_kernel<1, 1><<<dim3(32, 16, 4), 256, 128 * 9 * 4, stream>>>(
        x, oc1_w, oc1_b, obn_g, obn_b, obn_m, obn_v, h, 128, 32);
    // 3. offset conv2 (raw, fp32 out)
    conv3x3_kernel<0, 0><<<dim3(18, 16, 4), 256, 32 * 9 * 4, stream>>>(
        h, oc2_w, oc2_b, (const float*)nullptr, (const float*)nullptr,
        (const float*)nullptr, (const float*)nullptr, offsb, 32, 18);
    // 4. mask branch conv1 (+BN+ReLU)
    conv3x3_kernel<1, 1><<<dim3(32, 16, 4), 256, 128 * 9 * 4, stream>>>(
        x, mc1_w, mc1_b, mbn_g, mbn_b, mbn_m, mbn_v, hm, 128, 32);
    // 5. mask conv2 (+sigmoid, fp32 out)
    conv3x3_kernel<2, 0><<<dim3(9, 16, 4), 256, 32 * 9 * 4, stream>>>(
        hm, mc2_w, mc2_b, (const float*)nullptr, (const float*)nullptr,
        (const float*)nullptr, (const float*)nullptr, mskb, 32, 9);
    // 6. contour depthwise (+BN+ReLU)
    dwconv_kernel<<<8192, 256, 0, stream>>>(x, cb_dw_w, cb_dw_b, cbn_g, cbn_b, cbn_m, cbn_v, hc);
    // 7. contour pointwise
    pw_kernel<<<dim3(16, 16, 4), 256, 0, stream>>>(hc, cb_pw_w, cb_pw_b, cont, 128, 128);
    // 8. modulated deformable conv (MFMA)
    deform_kernel<<<1024, 256, 0, stream>>>(x, offsb, mskb, wB, dc_b, mainf);
    // 9. spatial attention GEMM phase (49 x 384 x 16384)
    sa_gemm_kernel<<<dim3(16, 4, 4), 256, 0, stream>>>(mainf, cont, sa_w, part);
    // 10. attn finalize (49-tap shifted sum + sigmoid)
    attn_fin_kernel<<<64, 256, 0, stream>>>(part, sa_b, attn);
    // 11. fusion 1x1 + BN + ReLU -> fp32 out
    fuse_kernel<<<dim3(32, 16, 4), 256, 0, stream>>>(
        mainf, cont, attn, fu_w, fu_b, fbn_g, fbn_b, fbn_m, fbn_v, out);
}

// Round 6
// 572.350 us; speedup vs baseline: 2.5531x; 1.6255x over previous
//
#include <hip/hip_runtime.h>
#include <hip/hip_bf16.h>
#include <math.h>

// Problem constants
#define BN   4
#define CIN  128
#define COUT 256
#define HWP  4096      // 64*64

typedef __hip_bfloat16 bf16;
typedef __attribute__((ext_vector_type(8))) short sh8;    // 8 bf16 = 4 VGPR
typedef __attribute__((ext_vector_type(4))) float f32x4;  // MFMA accumulator

__device__ __forceinline__ float b2f(bf16 v) { return __bfloat162float(v); }
__device__ __forceinline__ unsigned short f2bfbits(float f) {
    union { bf16 h; unsigned short u; } cv; cv.h = __float2bfloat16(f); return cv.u;
}

__device__ __forceinline__ float ldv(const float* p, size_t i) { return p[i]; }
__device__ __forceinline__ float ldv(const bf16* p, size_t i) { return b2f(p[i]); }
__device__ __forceinline__ void stv(float* p, size_t i, float v) { p[i] = v; }
__device__ __forceinline__ void stv(bf16* p, size_t i, float v) { p[i] = __float2bfloat16(v); }

// ------------------------------------------------- dc_w[co][ci*9+k] f32 -> wB[co][k*128+ci] bf16
__global__ __launch_bounds__(256) void prep_wB_kernel(const float* __restrict__ w,
                                                      bf16* __restrict__ wB) {
    int j = blockIdx.x * 256 + threadIdx.x;   // j = co*1152 + k*128 + ci
    if (j < 256 * 1152) {
        int co = j / 1152, rem = j - co * 1152;
        int k = rem >> 7, ci = rem & 127;
        wB[j] = __float2bfloat16(w[co * 1152 + ci * 9 + k]);
    }
}

// ------------------------------------------------- conv1 prep: combined oc1+mc1 weights + folded BN
// wC[co][k*128+ci] bf16 (co 0-31 = oc1, 32-63 = mc1); ab[0..63]=alpha, ab[64..127]=beta
__global__ __launch_bounds__(256) void prep_conv1_kernel(
    const float* __restrict__ oc1_w, const float* __restrict__ oc1_b,
    const float* __restrict__ obn_g, const float* __restrict__ obn_b,
    const float* __restrict__ obn_m, const float* __restrict__ obn_v,
    const float* __restrict__ mc1_w, const float* __restrict__ mc1_b,
    const float* __restrict__ mbn_g, const float* __restrict__ mbn_b,
    const float* __restrict__ mbn_m, const float* __restrict__ mbn_v,
    bf16* __restrict__ wC, float* __restrict__ ab)
{
    int j = blockIdx.x * 256 + threadIdx.x;
    if (j < 64 * 1152) {
        int co = j / 1152, rem = j - co * 1152;
        int k = rem >> 7, ci = rem & 127;
        float v = (co < 32) ? oc1_w[co * 1152 + ci * 9 + k]
                            : mc1_w[(co - 32) * 1152 + ci * 9 + k];
        wC[j] = __float2bfloat16(v);
    } else if (j < 64 * 1152 + 64) {
        int c = j - 64 * 1152;
        float g, bb, m, vv, bias;
        if (c < 32) { g = obn_g[c]; bb = obn_b[c]; m = obn_m[c]; vv = obn_v[c]; bias = oc1_b[c]; }
        else { int c2 = c - 32; g = mbn_g[c2]; bb = mbn_b[c2]; m = mbn_m[c2]; vv = mbn_v[c2]; bias = mc1_b[c2]; }
        float alpha = g / sqrtf(vv + 1e-5f);
        ab[c] = alpha;
        ab[64 + c] = (bias - m) * alpha + bb;
    }
}

// ---------------------------------------------------------------- conv1 (oc1+mc1) as MFMA im2col GEMM
// grid 1024 (= B * 256 tiles of 16 pixels in one row), block 256 = 4 waves. LDS 37.1 KB.
__global__ __launch_bounds__(256) void conv1_mfma_kernel(
    const float* __restrict__ x, const bf16* __restrict__ wC, const float* __restrict__ ab,
    bf16* __restrict__ h, bf16* __restrict__ hm)
{
    __shared__ __align__(16) bf16 val[16][1160];   // [pix][k*128+ci], pad 1152->1160

    const int bid = blockIdx.x;
    const int b = bid >> 8, tile = bid & 255;
    const int pos0 = tile * 16;
    const int y = tile >> 2, x0 = (tile & 3) * 16;
    const int tid = threadIdx.x;
    const int pix = tid & 15, grp = tid >> 4;
    const int xxb = x0 + pix;

    const float* xb = x + (size_t)b * CIN * HWP;
    #pragma unroll
    for (int k = 0; k < 9; k++) {
        int ky = k / 3, kx = k % 3;
        int yy = y + ky - 1, xx = xxb + kx - 1;
        bool valid = (yy >= 0 && yy <= 63 && xx >= 0 && xx <= 63);
        int src = yy * 64 + xx;
        #pragma unroll
        for (int it = 0; it < 4; it++) {
            int ci0 = (grp + 16 * it) * 2;
            const float* p0 = xb + (size_t)ci0 * HWP;
            float g0 = valid ? p0[src] : 0.f;
            float g1 = valid ? p0[HWP + src] : 0.f;
            unsigned pk = (unsigned)f2bfbits(g0) | ((unsigned)f2bfbits(g1) << 16);
            *(unsigned*)&val[pix][k * 128 + ci0] = pk;
        }
    }
    __syncthreads();

    const int lane = tid & 63, wv = tid >> 6;
    const int quad = lane >> 4, l16 = lane & 15;
    f32x4 acc = {0, 0, 0, 0};
    const bf16* wbase = wC + (size_t)(wv * 16 + l16) * 1152 + quad * 8;  // A[m=l16][k=quad*8+j]
    const bf16* vbase = &val[l16][quad * 8];
    for (int kt = 0; kt < 36; kt++) {
        sh8 bfr = *(const sh8*)(vbase + kt * 32);
        sh8 afr = *(const sh8*)(wbase + kt * 32);
        acc = __builtin_amdgcn_mfma_f32_16x16x32_bf16(afr, bfr, acc, 0, 0, 0);
    }

    #pragma unroll
    for (int r = 0; r < 4; r++) {
        int co = wv * 16 + quad * 4 + r;
        float o = fmaxf(acc[r] * ab[co] + ab[64 + co], 0.f);
        bf16 v16 = __float2bfloat16(o);
        if (co < 32) h[(size_t)(b * 32 + co) * HWP + pos0 + l16] = v16;
        else         hm[(size_t)(b * 32 + (co - 32)) * HWP + pos0 + l16] = v16;
    }
}

// ---------------------------------------------------------------- generic 3x3 conv
template<int ACT, int USE_BN, typename IT, typename OT>
__global__ __launch_bounds__(256) void conv3x3_kernel(
    const IT* __restrict__ in, const float* __restrict__ w, const float* __restrict__ bias,
    const float* __restrict__ bn_g, const float* __restrict__ bn_b,
    const float* __restrict__ bn_m, const float* __restrict__ bn_v,
    OT* __restrict__ out, int CI, int CO)
{
    extern __shared__ float wl[];          // CI*9 floats
    const int co = blockIdx.x, strip = blockIdx.y, b = blockIdx.z;
    const int nt = CI * 9;
    for (int i = threadIdx.x; i < nt; i += 256) wl[i] = w[co * nt + i];
    __syncthreads();

    const int tx = threadIdx.x & 63, ty = threadIdx.x >> 6;
    const int y = strip * 4 + ty, x = tx;
    float acc = bias[co];
    const IT* ip = in + (size_t)(b * CI) * HWP;
    for (int ci = 0; ci < CI; ci++) {
        const IT* p = ip + ci * HWP;
        const float* wp = wl + ci * 9;
        #pragma unroll
        for (int ky = 0; ky < 3; ky++) {
            int yy = y + ky - 1;
            if (yy < 0 || yy > 63) continue;
            #pragma unroll
            for (int kx = 0; kx < 3; kx++) {
                int xx = x + kx - 1;
                if (xx < 0 || xx > 63) continue;
                acc += ldv(p, yy * 64 + xx) * wp[ky * 3 + kx];
            }
        }
    }
    if (USE_BN) {
        float sc = bn_g[co] / sqrtf(bn_v[co] + 1e-5f);
        acc = (acc - bn_m[co]) * sc + bn_b[co];
    }
    if (ACT == 1) acc = fmaxf(acc, 0.f);
    else if (ACT == 2) acc = 1.f / (1.f + expf(-acc));
    stv(out, (size_t)(b * CO + co) * HWP + y * 64 + x, acc);
}

// ---------------------------------------------------------------- depthwise 3x3 + BN + ReLU
__global__ __launch_bounds__(256) void dwconv_kernel(
    const float* __restrict__ in, const float* __restrict__ w, const float* __restrict__ bias,
    const float* __restrict__ bn_g, const float* __restrict__ bn_b,
    const float* __restrict__ bn_m, const float* __restrict__ bn_v,
    bf16* __restrict__ out)
{
    int i = blockIdx.x * 256 + threadIdx.x;
    if (i >= BN * CIN * HWP) return;
    int x = i & 63, y = (i >> 6) & 63, c = (i >> 12) & 127;
    int b = i >> 19;
    float acc = bias[c];
    const float* p = in + (size_t)(b * CIN + c) * HWP;
    #pragma unroll
    for (int ky = 0; ky < 3; ky++) {
        int yy = y + ky - 1;
        if (yy < 0 || yy > 63) continue;
        #pragma unroll
        for (int kx = 0; kx < 3; kx++) {
            int xx = x + kx - 1;
            if (xx < 0 || xx > 63) continue;
            acc += p[yy * 64 + xx] * w[c * 9 + ky * 3 + kx];
        }
    }
    float sc = bn_g[c] / sqrtf(bn_v[c] + 1e-5f);
    acc = (acc - bn_m[c]) * sc + bn_b[c];
    acc = fmaxf(acc, 0.f);
    out[i] = __float2bfloat16(acc);
}

// ---------------------------------------------------------------- pointwise 1x1 (contour pw)
__global__ __launch_bounds__(256) void pw_kernel(
    const bf16* __restrict__ in, const float* __restrict__ w, const float* __restrict__ bias,
    bf16* __restrict__ out, int CI, int CO)
{
    __shared__ float wl[8 * 128];
    const int cog = blockIdx.x, strip = blockIdx.y, b = blockIdx.z;
    const int co0 = cog * 8;
    for (int i = threadIdx.x; i < 8 * CI; i += 256) wl[i] = w[co0 * CI + i];
    __syncthreads();
    const int tx = threadIdx.x & 63, ty = threadIdx.x >> 6;
    const int pos = (strip * 4 + ty) * 64 + tx;
    float acc[8];
    #pragma unroll
    for (int cs = 0; cs < 8; cs++) acc[cs] = bias[co0 + cs];
    const bf16* ip = in + (size_t)b * CI * HWP + pos;
    for (int ci = 0; ci < CI; ci++) {
        float v = b2f(ip[ci * HWP]);
        #pragma unroll
        for (int cs = 0; cs < 8; cs++) acc[cs] += v * wl[cs * CI + ci];
    }
    #pragma unroll
    for (int cs = 0; cs < 8; cs++)
        out[(size_t)(b * CO + co0 + cs) * HWP + pos] = __float2bfloat16(acc[cs]);
}

// ---------------------------------------------------------------- modulated deformable conv (MFMA)
// grid 1024 (= B * 256 tiles of 16 pixels), block 256 = 4 waves. LDS 41.7 KB.
__global__ __launch_bounds__(256) void deform_kernel(
    const float* __restrict__ x, const float* __restrict__ offs, const float* __restrict__ msk,
    const bf16* __restrict__ wB, const float* __restrict__ bias, bf16* __restrict__ out)
{
    __shared__ __align__(16) bf16 val[16][1160];   // [pix][kk], pad 1152->1160
    __shared__ int   ti[144][4];                   // e = k*16+pix -> 4 corner indices
    __shared__ float tw[144][4];                   // 4 corner weights (mask folded in)

    const int bid = blockIdx.x;
    const int b = bid >> 8;
    const int tile = bid & 255;
    const int pos0 = tile * 16;
    const int tid = threadIdx.x;

    if (tid < 144) {                      // e = k*16 + pix
        int k = tid >> 4, pix = tid & 15;
        int pos = pos0 + pix;
        int y = pos >> 6, xc = pos & 63;
        float offy = offs[(size_t)(b * 18 + 2 * k) * HWP + pos];
        float offx = offs[(size_t)(b * 18 + 2 * k + 1) * HWP + pos];
        float m = msk[(size_t)(b * 9 + k) * HWP + pos];
        float py = (float)(y - 1 + k / 3) + offy;
        float px = (float)(xc - 1 + k % 3) + offx;
        float fy = floorf(py), fx = floorf(px);
        float wy1 = py - fy, wx1 = px - fx;
        int y0 = (int)fy, x0 = (int)fx;
        int y1 = y0 + 1, x1 = x0 + 1;
        bool vy0 = (y0 >= 0 && y0 <= 63), vy1 = (y1 >= 0 && y1 <= 63);
        bool vx0 = (x0 >= 0 && x0 <= 63), vx1 = (x1 >= 0 && x1 <= 63);
        int cy0 = min(max(y0, 0), 63), cy1 = min(max(y1, 0), 63);
        int cx0 = min(max(x0, 0), 63), cx1 = min(max(x1, 0), 63);
        ti[tid][0] = cy0 * 64 + cx0;  tw[tid][0] = (vy0 && vx0) ? (1.f - wy1) * (1.f - wx1) * m : 0.f;
        ti[tid][1] = cy0 * 64 + cx1;  tw[tid][1] = (vy0 && vx1) ? (1.f - wy1) * wx1 * m : 0.f;
        ti[tid][2] = cy1 * 64 + cx0;  tw[tid][2] = (vy1 && vx0) ? wy1 * (1.f - wx1) * m : 0.f;
        ti[tid][3] = cy1 * 64 + cx1;  tw[tid][3] = (vy1 && vx1) ? wy1 * wx1 * m : 0.f;
    }
    __syncthreads();

    // ---- gather phase
    {
        const int pix = tid & 15, grp = tid >> 4;
        const float* xb = x + (size_t)b * CIN * HWP;
        for (int k = 0; k < 9; k++) {
            const int e = k * 16 + pix;
            const int i0 = ti[e][0], i1 = ti[e][1], i2 = ti[e][2], i3 = ti[e][3];
            const float w0 = tw[e][0], w1 = tw[e][1], w2 = tw[e][2], w3 = tw[e][3];
            #pragma unroll
            for (int it = 0; it < 4; it++) {
                const int ci0 = (grp + 16 * it) * 2;          // even ci
                const float* p0 = xb + (size_t)ci0 * HWP;
                const float* p1 = p0 + HWP;
                float g0 = w0 * p0[i0] + w1 * p0[i1] + w2 * p0[i2] + w3 * p0[i3];
                float g1 = w0 * p1[i0] + w1 * p1[i1] + w2 * p1[i2] + w3 * p1[i3];
                unsigned pk = (unsigned)f2bfbits(g0) | ((unsigned)f2bfbits(g1) << 16);
                *(unsigned*)&val[pix][k * 128 + ci0] = pk;    // ds_write_b32, 2 lanes/bank
            }
        }
    }
    __syncthreads();

    // ---- MFMA phase: wave wv owns co [wv*64, wv*64+64) x 16 pixels
    const int lane = tid & 63, wv = tid >> 6;
    const int quad = lane >> 4, l16 = lane & 15;
    f32x4 acc[4] = {f32x4{0,0,0,0}, f32x4{0,0,0,0}, f32x4{0,0,0,0}, f32x4{0,0,0,0}};

    const bf16* wbase = wB + (size_t)(wv * 64 + l16) * 1152 + quad * 8;  // A[m=l16][k=quad*8+j]
    const bf16* vbase = &val[l16][quad * 8];                             // B[n=l16][k=quad*8+j]
    for (int kt = 0; kt < 36; kt++) {
        sh8 bfr = *(const sh8*)(vbase + kt * 32);
        #pragma unroll
        for (int mt = 0; mt < 4; mt++) {
            sh8 afr = *(const sh8*)(wbase + (size_t)mt * 16 * 1152 + kt * 32);
            acc[mt] = __builtin_amdgcn_mfma_f32_16x16x32_bf16(afr, bfr, acc[mt], 0, 0, 0);
        }
    }

    // ---- epilogue: C/D layout col=lane&15 (pix), row=quad*4+reg
    bf16* op = out + (size_t)b * COUT * HWP + pos0 + l16;
    #pragma unroll
    for (int mt = 0; mt < 4; mt++) {
        int co_b = wv * 64 + mt * 16 + quad * 4;
        #pragma unroll
        for (int r = 0; r < 4; r++) {
            int co = co_b + r;
            op[(size_t)co * HWP] = __float2bfloat16(acc[mt][r] + bias[co]);
        }
    }
}

// ---------------------------------------------------------------- spatial attention: GEMM phase
__global__ __launch_bounds__(256) void sa_gemm_kernel(
    const bf16* __restrict__ mainf, const bf16* __restrict__ contf,
    const float* __restrict__ w, float* __restrict__ part)
{
    const int chunk = blockIdx.x, b = blockIdx.y, cs = blockIdx.z;
    const int pos = chunk * 256 + threadIdx.x;
    const int c0 = cs * 96;
    float acc[49];
    #pragma unroll
    for (int j = 0; j < 49; j++) acc[j] = 0.f;

    for (int ci = 0; ci < 96; ci += 8) {
        float v[8];
        #pragma unroll
        for (int u = 0; u < 8; u++) {
            int cc = c0 + ci + u;
            const bf16* p = (cc < 256) ? (mainf + (size_t)(b * COUT + cc) * HWP)
                                       : (contf + (size_t)(b * 128 + (cc - 256)) * HWP);
            v[u] = b2f(p[pos]);
        }
        #pragma unroll
        for (int j = 0; j < 49; j++) {
            #pragma unroll
            for (int u = 0; u < 8; u++)
                acc[j] += v[u] * w[(c0 + ci + u) * 49 + j];   // uniform -> scalar load
        }
    }
    #pragma unroll
    for (int j = 0; j < 49; j++)
        part[(size_t)((cs * 49 + j) * BN + b) * HWP + pos] = acc[j];
}

// ---------------------------------------------------------------- attn finalize: 49-tap shifted sum
__global__ __launch_bounds__(256) void attn_fin_kernel(
    const float* __restrict__ part, const float* __restrict__ sa_b, float* __restrict__ attn)
{
    int i = blockIdx.x * 256 + threadIdx.x;
    if (i >= BN * HWP) return;
    int b = i >> 12, pos = i & 4095;
    int y = pos >> 6, x = pos & 63;
    float s = sa_b[0];
    #pragma unroll
    for (int j = 0; j < 49; j++) {
        int yy = y + j / 7 - 3, xx = x + j % 7 - 3;
        if (yy < 0 || yy > 63 || xx < 0 || xx > 63) continue;
        int p2 = yy * 64 + xx;
        s += part[(size_t)((0 * 49 + j) * BN + b) * HWP + p2]
           + part[(size_t)((1 * 49 + j) * BN + b) * HWP + p2]
           + part[(size_t)((2 * 49 + j) * BN + b) * HWP + p2]
           + part[(size_t)((3 * 49 + j) * BN + b) * HWP + p2];
    }
    attn[i] = 1.f / (1.f + expf(-s));
}

// ---------------------------------------------------------------- fusion 1x1 (384->256) + BN + ReLU
__global__ __launch_bounds__(256) void fuse_kernel(
    const bf16* __restrict__ mainf, const bf16* __restrict__ contf, const float* __restrict__ attn,
    const float* __restrict__ w, const float* __restrict__ bias,
    const float* __restrict__ bn_g, const float* __restrict__ bn_b,
    const float* __restrict__ bn_m, const float* __restrict__ bn_v,
    float* __restrict__ out)
{
    __shared__ float wl[8 * 384];
    const int cog = blockIdx.x, strip = blockIdx.y, b = blockIdx.z;
    const int co0 = cog * 8;
    for (int i = threadIdx.x; i < 8 * 384; i += 256) wl[i] = w[co0 * 384 + i];
    __syncthreads();
    const int tx = threadIdx.x & 63, ty = threadIdx.x >> 6;
    const int pos = (strip * 4 + ty) * 64 + tx;
    float a = attn[b * HWP + pos];
    float acc[8];
    #pragma unroll
    for (int cs = 0; cs < 8; cs++) acc[cs] = 0.f;
    const bf16* mp = mainf + (size_t)b * COUT * HWP + pos;
    for (int ci = 0; ci < 256; ci++) {
        float v = b2f(mp[ci * HWP]);
        #pragma unroll
        for (int cs = 0; cs < 8; cs++) acc[cs] += v * wl[cs * 384 + ci];
    }
    const bf16* cp = contf + (size_t)b * 128 * HWP + pos;
    for (int ci = 0; ci < 128; ci++) {
        float v = b2f(cp[ci * HWP]);
        #pragma unroll
        for (int cs = 0; cs < 8; cs++) acc[cs] += v * wl[cs * 384 + 256 + ci];
    }
    #pragma unroll
    for (int cs = 0; cs < 8; cs++) {
        int co = co0 + cs;
        float o = acc[cs] * a + bias[co];
        float sc = bn_g[co] / sqrtf(bn_v[co] + 1e-5f);
        o = (o - bn_m[co]) * sc + bn_b[co];
        o = fmaxf(o, 0.f);
        out[(size_t)(b * COUT + co) * HWP + pos] = o;
    }
}

// ================================================================ launch
extern "C" void kernel_launch(void* const* d_in, const int* in_sizes, int n_in,
                              void* d_out, int out_size, void* d_ws, size_t ws_size,
                              hipStream_t stream)
{
    const float* x      = (const float*)d_in[0];
    const float* oc1_w  = (const float*)d_in[1];
    const float* oc1_b  = (const float*)d_in[2];
    const float* obn_g  = (const float*)d_in[3];
    const float* obn_b  = (const float*)d_in[4];
    const float* obn_m  = (const float*)d_in[5];
    const float* obn_v  = (const float*)d_in[6];
    const float* oc2_w  = (const float*)d_in[7];
    const float* oc2_b  = (const float*)d_in[8];
    const float* mc1_w  = (const float*)d_in[9];
    const float* mc1_b  = (const float*)d_in[10];
    const float* mbn_g  = (const float*)d_in[11];
    const float* mbn_b  = (const float*)d_in[12];
    const float* mbn_m  = (const float*)d_in[13];
    const float* mbn_v  = (const float*)d_in[14];
    const float* mc2_w  = (const float*)d_in[15];
    const float* mc2_b  = (const float*)d_in[16];
    const float* dc_w   = (const float*)d_in[17];
    const float* dc_b   = (const float*)d_in[18];
    const float* cb_dw_w= (const float*)d_in[19];
    const float* cb_dw_b= (const float*)d_in[20];
    const float* cbn_g  = (const float*)d_in[21];
    const float* cbn_b  = (const float*)d_in[22];
    const float* cbn_m  = (const float*)d_in[23];
    const float* cbn_v  = (const float*)d_in[24];
    const float* cb_pw_w= (const float*)d_in[25];
    const float* cb_pw_b= (const float*)d_in[26];
    const float* sa_w   = (const float*)d_in[27];
    const float* sa_b   = (const float*)d_in[28];
    const float* fu_w   = (const float*)d_in[29];
    const float* fu_b   = (const float*)d_in[30];
    const float* fbn_g  = (const float*)d_in[31];
    const float* fbn_b  = (const float*)d_in[32];
    const float* fbn_m  = (const float*)d_in[33];
    const float* fbn_v  = (const float*)d_in[34];

    // workspace layout (~34.3 MB)
    bf16*  h     = (bf16*)d_ws;                //   524,288 bf16
    bf16*  hm    = h + 524288;                 //   524,288 bf16
    float* offsb = (float*)(hm + 524288);      //   294,912 f32
    float* mskb  = offsb + 294912;             //   147,456 f32
    bf16*  hc    = (bf16*)(mskb + 147456);     // 2,097,152 bf16
    bf16*  cont  = hc + 2097152;               // 2,097,152 bf16
    bf16*  mainf = cont + 2097152;             // 4,194,304 bf16
    float* part  = (float*)(mainf + 4194304);  // 3,211,264 f32 (4cs x 49 x B x HWP)
    float* attn  = part + 3211264;             //    16,384 f32
    bf16*  wB    = (bf16*)(attn + 16384);      //   294,912 bf16
    bf16*  wC    = wB + 294912;                //    73,728 bf16
    float* ab    = (float*)(wC + 73728);       //       128 f32

    float* out = (float*)d_out;

    // 1. permute + cast main deform weight: wB[co][k*128+ci]
    prep_wB_kernel<<<1152, 256, 0, stream>>>(dc_w, wB);
    // 1b. conv1 combined weights + folded BN
    prep_conv1_kernel<<<289, 256, 0, stream>>>(oc1_w, oc1_b, obn_g, obn_b, obn_m, obn_v,
                                               mc1_w, mc1_b, mbn_g, mbn_b, mbn_m, mbn_v, wC, ab);
    // 2. oc1 + mc1 fused MFMA conv (+folded BN+ReLU)
    conv1_mfma_kernel<<<1024, 256, 0, stream>>>(x, wC, ab, h, hm);
    // 3. offset conv2 (raw, fp32 out)
    conv3x3_kernel<0, 0><<<dim3(18, 16, 4), 256, 32 * 9 * 4, stream>>>(
        h, oc2_w, oc2_b, (const float*)nullptr, (const float*)nullptr,
        (const float*)nullptr, (const float*)nullptr, offsb, 32, 18);
    // 4. mask conv2 (+sigmoid, fp32 out)
    conv3x3_kernel<2, 0><<<dim3(9, 16, 4), 256, 32 * 9 * 4, stream>>>(
        hm, mc2_w, mc2_b, (const float*)nullptr, (const float*)nullptr,
        (const float*)nullptr, (const float*)nullptr, mskb, 32, 9);
    // 5. contour depthwise (+BN+ReLU)
    dwconv_kernel<<<8192, 256, 0, stream>>>(x, cb_dw_w, cb_dw_b, cbn_g, cbn_b, cbn_m, cbn_v, hc);
    // 6. contour pointwise
    pw_kernel<<<dim3(16, 16, 4), 256, 0, stream>>>(hc, cb_pw_w, cb_pw_b, cont, 128, 128);
    // 7. modulated deformable conv (MFMA)
    deform_kernel<<<1024, 256, 0, stream>>>(x, offsb, mskb, wB, dc_b, mainf);
    // 8. spatial attention GEMM phase (49 x 384 x 16384)
    sa_gemm_kernel<<<dim3(16, 4, 4), 256, 0, stream>>>(mainf, cont, sa_w, part);
    // 9. attn finalize (49-tap shifted sum + sigmoid)
    attn_fin_kernel<<<64, 256, 0, stream>>>(part, sa_b, attn);
    // 10. fusion 1x1 + BN + ReLU -> fp32 out
    fuse_kernel<<<dim3(32, 16, 4), 256, 0, stream>>>(
        mainf, cont, attn, fu_w, fu_b, fbn_g, fbn_b, fbn_m, fbn_v, out);
}

// Round 7
// 432.517 us; speedup vs baseline: 3.3785x; 1.3233x over previous
//
#include <hip/hip_runtime.h>
#include <hip/hip_bf16.h>
#include <math.h>

// Problem constants
#define BN   4
#define CIN  128
#define COUT 256
#define HWP  4096      // 64*64

typedef __hip_bfloat16 bf16;
typedef __attribute__((ext_vector_type(8))) short sh8;    // 8 bf16 = 4 VGPR
typedef __attribute__((ext_vector_type(4))) float f32x4;  // MFMA accumulator

__device__ __forceinline__ float b2f(bf16 v) { return __bfloat162float(v); }
__device__ __forceinline__ float bflo(unsigned u) { return __uint_as_float(u << 16); }
__device__ __forceinline__ float bfhi(unsigned u) { return __uint_as_float(u & 0xffff0000u); }
__device__ __forceinline__ unsigned short f2bfbits(float f) {
    union { bf16 h; unsigned short u; } cv; cv.h = __float2bfloat16(f); return cv.u;
}
__device__ __forceinline__ float bfj(const uint4& c, int j) {
    unsigned u = (&c.x)[j >> 1];
    return (j & 1) ? bfhi(u) : bflo(u);
}

__device__ __forceinline__ float ldv(const float* p, size_t i) { return p[i]; }
__device__ __forceinline__ float ldv(const bf16* p, size_t i) { return b2f(p[i]); }
__device__ __forceinline__ void stv(float* p, size_t i, float v) { p[i] = v; }
__device__ __forceinline__ void stv(bf16* p, size_t i, float v) { p[i] = __float2bfloat16(v); }

// ---------------------------------------------------------------- x [b][ci][pos] f32 -> xt [b][pos][ci] bf16
__global__ __launch_bounds__(256) void transpose_x_kernel(const float* __restrict__ x,
                                                          bf16* __restrict__ xt)
{
    __shared__ bf16 t[64][136];            // stride 136 bf16 = 272 B (16-aligned)
    const int b = blockIdx.x >> 6, chunk = blockIdx.x & 63;
    const int pos0 = chunk * 64;
    const int tid = threadIdx.x;
    const int lane = tid & 63, wv = tid >> 6;
    const float* xb = x + (size_t)b * CIN * HWP + pos0 + lane;
    #pragma unroll 4
    for (int j = 0; j < 32; j++) {
        int ci = wv * 32 + j;              // wave-uniform ci
        t[lane][ci] = __float2bfloat16(xb[(size_t)ci * HWP]);
    }
    __syncthreads();
    const int p = tid >> 2, cig = tid & 3;
    uint4* dst = (uint4*)(xt + ((size_t)b * HWP + pos0 + p) * 128 + cig * 32);
    const uint4* src = (const uint4*)&t[p][cig * 32];
    #pragma unroll
    for (int q = 0; q < 4; q++) dst[q] = src[q];
}

// ------------------------------------------------- dc_w[co][ci*9+k] f32 -> wB[co][k*128+ci] bf16
__global__ __launch_bounds__(256) void prep_wB_kernel(const float* __restrict__ w,
                                                      bf16* __restrict__ wB) {
    int j = blockIdx.x * 256 + threadIdx.x;
    if (j < 256 * 1152) {
        int co = j / 1152, rem = j - co * 1152;
        int k = rem >> 7, ci = rem & 127;
        wB[j] = __float2bfloat16(w[co * 1152 + ci * 9 + k]);
    }
}

// ------------------------------------------------- conv1 prep: combined oc1+mc1 weights + folded BN
__global__ __launch_bounds__(256) void prep_conv1_kernel(
    const float* __restrict__ oc1_w, const float* __restrict__ oc1_b,
    const float* __restrict__ obn_g, const float* __restrict__ obn_b,
    const float* __restrict__ obn_m, const float* __restrict__ obn_v,
    const float* __restrict__ mc1_w, const float* __restrict__ mc1_b,
    const float* __restrict__ mbn_g, const float* __restrict__ mbn_b,
    const float* __restrict__ mbn_m, const float* __restrict__ mbn_v,
    bf16* __restrict__ wC, float* __restrict__ ab)
{
    int j = blockIdx.x * 256 + threadIdx.x;
    if (j < 64 * 1152) {
        int co = j / 1152, rem = j - co * 1152;
        int k = rem >> 7, ci = rem & 127;
        float v = (co < 32) ? oc1_w[co * 1152 + ci * 9 + k]
                            : mc1_w[(co - 32) * 1152 + ci * 9 + k];
        wC[j] = __float2bfloat16(v);
    } else if (j < 64 * 1152 + 64) {
        int c = j - 64 * 1152;
        float g, bb, m, vv, bias;
        if (c < 32) { g = obn_g[c]; bb = obn_b[c]; m = obn_m[c]; vv = obn_v[c]; bias = oc1_b[c]; }
        else { int c2 = c - 32; g = mbn_g[c2]; bb = mbn_b[c2]; m = mbn_m[c2]; vv = mbn_v[c2]; bias = mc1_b[c2]; }
        float alpha = g / sqrtf(vv + 1e-5f);
        ab[c] = alpha;
        ab[64 + c] = (bias - m) * alpha + bb;
    }
}

// ------------------------------------------------- fuse/sa prep: bf16 weights + folded fuse BN
// wF[co][384] bf16 ; wSA[j(64)][384] bf16 (j>=49 zero) ; fab[0..255]=alpha', fab[256..511]=beta
__global__ __launch_bounds__(256) void prep_fuse_kernel(
    const float* __restrict__ fu_w, const float* __restrict__ fu_b,
    const float* __restrict__ fbn_g, const float* __restrict__ fbn_b,
    const float* __restrict__ fbn_m, const float* __restrict__ fbn_v,
    const float* __restrict__ sa_w,
    bf16* __restrict__ wF, bf16* __restrict__ wSA, float* __restrict__ fab)
{
    int j = blockIdx.x * 256 + threadIdx.x;
    if (j < 98304) {
        wF[j] = __float2bfloat16(fu_w[j]);
    } else if (j < 98304 + 24576) {
        int idx = j - 98304;
        int jj = idx / 384, ci = idx - jj * 384;
        wSA[idx] = (jj < 49) ? __float2bfloat16(sa_w[ci * 49 + jj]) : __float2bfloat16(0.f);
    } else if (j < 98304 + 24576 + 256) {
        int co = j - 98304 - 24576;
        float alpha = fbn_g[co] / sqrtf(fbn_v[co] + 1e-5f);
        fab[co] = alpha;
        fab[256 + co] = (fu_b[co] - fbn_m[co]) * alpha + fbn_b[co];
    }
}

// ---------------------------------------------------------------- conv1 (oc1+mc1) MFMA im2col GEMM (xt input)
// grid 1024, block 256 = 4 waves. XCD-affinity swizzle. LDS 37.1 KB.
__global__ __launch_bounds__(256) void conv1_mfma_kernel(
    const bf16* __restrict__ xt, const bf16* __restrict__ wC, const float* __restrict__ ab,
    bf16* __restrict__ h, bf16* __restrict__ hm)
{
    __shared__ __align__(16) bf16 val[16][1160];

    const int bid = blockIdx.x;
    const int b = (bid & 7) >> 1;
    const int tile = ((bid >> 3) << 1) | (bid & 1);
    const int pos0 = tile * 16;
    const int y = tile >> 2, x0 = (tile & 3) * 16;
    const int tid = threadIdx.x;
    const int cig = tid & 15, pix = tid >> 4;
    const int ci0 = cig * 8;
    const int xxp = x0 + pix;

    const bf16* xtb = xt + (size_t)b * HWP * 128;
    #pragma unroll
    for (int k = 0; k < 9; k++) {
        int yy = y + k / 3 - 1, xx = xxp + k % 3 - 1;
        bool valid = (yy >= 0 && yy <= 63 && xx >= 0 && xx <= 63);
        uint4 c = {0, 0, 0, 0};
        if (valid) c = *(const uint4*)(xtb + (size_t)(yy * 64 + xx) * 128 + ci0);
        *(uint4*)&val[pix][k * 128 + ci0] = c;
    }
    __syncthreads();

    const int lane = tid & 63, wv = tid >> 6;
    const int quad = lane >> 4, l16 = lane & 15;
    f32x4 acc = {0, 0, 0, 0};
    const bf16* wbase = wC + (size_t)(wv * 16 + l16) * 1152 + quad * 8;
    const bf16* vbase = &val[l16][quad * 8];
    for (int kt = 0; kt < 36; kt++) {
        sh8 bfr = *(const sh8*)(vbase + kt * 32);
        sh8 afr = *(const sh8*)(wbase + kt * 32);
        acc = __builtin_amdgcn_mfma_f32_16x16x32_bf16(afr, bfr, acc, 0, 0, 0);
    }

    #pragma unroll
    for (int r = 0; r < 4; r++) {
        int co = wv * 16 + quad * 4 + r;
        float o = fmaxf(acc[r] * ab[co] + ab[64 + co], 0.f);
        bf16 v16 = __float2bfloat16(o);
        if (co < 32) h[(size_t)(b * 32 + co) * HWP + pos0 + l16] = v16;
        else         hm[(size_t)(b * 32 + (co - 32)) * HWP + pos0 + l16] = v16;
    }
}

// ---------------------------------------------------------------- generic 3x3 conv (for oc2/mc2)
template<int ACT, int USE_BN, typename IT, typename OT>
__global__ __launch_bounds__(256) void conv3x3_kernel(
    const IT* __restrict__ in, const float* __restrict__ w, const float* __restrict__ bias,
    const float* __restrict__ bn_g, const float* __restrict__ bn_b,
    const float* __restrict__ bn_m, const float* __restrict__ bn_v,
    OT* __restrict__ out, int CI, int CO)
{
    extern __shared__ float wl[];
    const int co = blockIdx.x, strip = blockIdx.y, b = blockIdx.z;
    const int nt = CI * 9;
    for (int i = threadIdx.x; i < nt; i += 256) wl[i] = w[co * nt + i];
    __syncthreads();

    const int tx = threadIdx.x & 63, ty = threadIdx.x >> 6;
    const int y = strip * 4 + ty, x = tx;
    float acc = bias[co];
    const IT* ip = in + (size_t)(b * CI) * HWP;
    for (int ci = 0; ci < CI; ci++) {
        const IT* p = ip + ci * HWP;
        const float* wp = wl + ci * 9;
        #pragma unroll
        for (int ky = 0; ky < 3; ky++) {
            int yy = y + ky - 1;
            if (yy < 0 || yy > 63) continue;
            #pragma unroll
            for (int kx = 0; kx < 3; kx++) {
                int xx = x + kx - 1;
                if (xx < 0 || xx > 63) continue;
                acc += ldv(p, yy * 64 + xx) * wp[ky * 3 + kx];
            }
        }
    }
    if (USE_BN) {
        float sc = bn_g[co] / sqrtf(bn_v[co] + 1e-5f);
        acc = (acc - bn_m[co]) * sc + bn_b[co];
    }
    if (ACT == 1) acc = fmaxf(acc, 0.f);
    else if (ACT == 2) acc = 1.f / (1.f + expf(-acc));
    stv(out, (size_t)(b * CO + co) * HWP + y * 64 + x, acc);
}

// ---------------------------------------------------------------- depthwise 3x3 + BN + ReLU
__global__ __launch_bounds__(256) void dwconv_kernel(
    const float* __restrict__ in, const float* __restrict__ w, const float* __restrict__ bias,
    const float* __restrict__ bn_g, const float* __restrict__ bn_b,
    const float* __restrict__ bn_m, const float* __restrict__ bn_v,
    bf16* __restrict__ out)
{
    int i = blockIdx.x * 256 + threadIdx.x;
    if (i >= BN * CIN * HWP) return;
    int x = i & 63, y = (i >> 6) & 63, c = (i >> 12) & 127;
    int b = i >> 19;
    float acc = bias[c];
    const float* p = in + (size_t)(b * CIN + c) * HWP;
    #pragma unroll
    for (int ky = 0; ky < 3; ky++) {
        int yy = y + ky - 1;
        if (yy < 0 || yy > 63) continue;
        #pragma unroll
        for (int kx = 0; kx < 3; kx++) {
            int xx = x + kx - 1;
            if (xx < 0 || xx > 63) continue;
            acc += p[yy * 64 + xx] * w[c * 9 + ky * 3 + kx];
        }
    }
    float sc = bn_g[c] / sqrtf(bn_v[c] + 1e-5f);
    acc = (acc - bn_m[c]) * sc + bn_b[c];
    acc = fmaxf(acc, 0.f);
    out[i] = __float2bfloat16(acc);
}

// ---------------------------------------------------------------- pointwise 1x1 -> combined_t[pos][256+co]
__global__ __launch_bounds__(256) void pw_kernel(
    const bf16* __restrict__ in, const float* __restrict__ w, const float* __restrict__ bias,
    bf16* __restrict__ combined, int CI)
{
    __shared__ float wl[8 * 128];
    const int cog = blockIdx.x, strip = blockIdx.y, b = blockIdx.z;
    const int co0 = cog * 8;
    for (int i = threadIdx.x; i < 8 * CI; i += 256) wl[i] = w[co0 * CI + i];
    __syncthreads();
    const int tx = threadIdx.x & 63, ty = threadIdx.x >> 6;
    const int pos = (strip * 4 + ty) * 64 + tx;
    float acc[8];
    #pragma unroll
    for (int cs = 0; cs < 8; cs++) acc[cs] = bias[co0 + cs];
    const bf16* ip = in + (size_t)b * CI * HWP + pos;
    for (int ci = 0; ci < CI; ci++) {
        float v = b2f(ip[ci * HWP]);
        #pragma unroll
        for (int cs = 0; cs < 8; cs++) acc[cs] += v * wl[cs * CI + ci];
    }
    uint4 pk;
    pk.x = (unsigned)f2bfbits(acc[0]) | ((unsigned)f2bfbits(acc[1]) << 16);
    pk.y = (unsigned)f2bfbits(acc[2]) | ((unsigned)f2bfbits(acc[3]) << 16);
    pk.z = (unsigned)f2bfbits(acc[4]) | ((unsigned)f2bfbits(acc[5]) << 16);
    pk.w = (unsigned)f2bfbits(acc[6]) | ((unsigned)f2bfbits(acc[7]) << 16);
    *(uint4*)(combined + ((size_t)b * HWP + pos) * 384 + 256 + co0) = pk;
}

// ---------------------------------------------------------------- modulated deformable conv (MFMA, xt gather)
// grid 1024, block 256 = 4 waves. XCD swizzle. Writes combined_t[pos][co].
__global__ __launch_bounds__(256) void deform_kernel(
    const bf16* __restrict__ xt, const float* __restrict__ offs, const float* __restrict__ msk,
    const bf16* __restrict__ wB, const float* __restrict__ bias, bf16* __restrict__ combined)
{
    __shared__ __align__(16) bf16 val[16][1160];
    __shared__ int   ti[144][4];
    __shared__ float tw[144][4];

    const int bid = blockIdx.x;
    const int b = (bid & 7) >> 1;
    const int tile = ((bid >> 3) << 1) | (bid & 1);
    const int pos0 = tile * 16;
    const int tid = threadIdx.x;

    if (tid < 144) {                      // e = k*16 + pix
        int k = tid >> 4, pix = tid & 15;
        int pos = pos0 + pix;
        int y = pos >> 6, xc = pos & 63;
        float offy = offs[(size_t)(b * 18 + 2 * k) * HWP + pos];
        float offx = offs[(size_t)(b * 18 + 2 * k + 1) * HWP + pos];
        float m = msk[(size_t)(b * 9 + k) * HWP + pos];
        float py = (float)(y - 1 + k / 3) + offy;
        float px = (float)(xc - 1 + k % 3) + offx;
        float fy = floorf(py), fx = floorf(px);
        float wy1 = py - fy, wx1 = px - fx;
        int y0 = (int)fy, x0 = (int)fx;
        int y1 = y0 + 1, x1 = x0 + 1;
        bool vy0 = (y0 >= 0 && y0 <= 63), vy1 = (y1 >= 0 && y1 <= 63);
        bool vx0 = (x0 >= 0 && x0 <= 63), vx1 = (x1 >= 0 && x1 <= 63);
        int cy0 = min(max(y0, 0), 63), cy1 = min(max(y1, 0), 63);
        int cx0 = min(max(x0, 0), 63), cx1 = min(max(x1, 0), 63);
        ti[tid][0] = cy0 * 64 + cx0;  tw[tid][0] = (vy0 && vx0) ? (1.f - wy1) * (1.f - wx1) * m : 0.f;
        ti[tid][1] = cy0 * 64 + cx1;  tw[tid][1] = (vy0 && vx1) ? (1.f - wy1) * wx1 * m : 0.f;
        ti[tid][2] = cy1 * 64 + cx0;  tw[tid][2] = (vy1 && vx0) ? wy1 * (1.f - wx1) * m : 0.f;
        ti[tid][3] = cy1 * 64 + cx1;  tw[tid][3] = (vy1 && vx1) ? wy1 * wx1 * m : 0.f;
    }
    __syncthreads();

    // ---- gather: lane = ci-group, fully coalesced dwordx4 from xt
    {
        const int cig = tid & 15, pix = tid >> 4;
        const int ci0 = cig * 8;
        const bf16* xtb = xt + (size_t)b * HWP * 128;
        for (int k = 0; k < 9; k++) {
            const int e = k * 16 + pix;
            const int i0 = ti[e][0], i1 = ti[e][1], i2 = ti[e][2], i3 = ti[e][3];
            const float w0 = tw[e][0], w1 = tw[e][1], w2 = tw[e][2], w3 = tw[e][3];
            uint4 c0 = *(const uint4*)(xtb + (size_t)i0 * 128 + ci0);
            uint4 c1 = *(const uint4*)(xtb + (size_t)i1 * 128 + ci0);
            uint4 c2 = *(const uint4*)(xtb + (size_t)i2 * 128 + ci0);
            uint4 c3 = *(const uint4*)(xtb + (size_t)i3 * 128 + ci0);
            float g[8];
            #pragma unroll
            for (int j = 0; j < 8; j++)
                g[j] = w0 * bfj(c0, j) + w1 * bfj(c1, j) + w2 * bfj(c2, j) + w3 * bfj(c3, j);
            uint4 pk;
            pk.x = (unsigned)f2bfbits(g[0]) | ((unsigned)f2bfbits(g[1]) << 16);
            pk.y = (unsigned)f2bfbits(g[2]) | ((unsigned)f2bfbits(g[3]) << 16);
            pk.z = (unsigned)f2bfbits(g[4]) | ((unsigned)f2bfbits(g[5]) << 16);
            pk.w = (unsigned)f2bfbits(g[6]) | ((unsigned)f2bfbits(g[7]) << 16);
            *(uint4*)&val[pix][k * 128 + ci0] = pk;
        }
    }
    __syncthreads();

    // ---- MFMA: wave wv owns co [wv*64, wv*64+64) x 16 pixels
    const int lane = tid & 63, wv = tid >> 6;
    const int quad = lane >> 4, l16 = lane & 15;
    f32x4 acc[4] = {f32x4{0,0,0,0}, f32x4{0,0,0,0}, f32x4{0,0,0,0}, f32x4{0,0,0,0}};

    const bf16* wbase = wB + (size_t)(wv * 64 + l16) * 1152 + quad * 8;
    const bf16* vbase = &val[l16][quad * 8];
    for (int kt = 0; kt < 36; kt++) {
        sh8 bfr = *(const sh8*)(vbase + kt * 32);
        #pragma unroll
        for (int mt = 0; mt < 4; mt++) {
            sh8 afr = *(const sh8*)(wbase + (size_t)mt * 16 * 1152 + kt * 32);
            acc[mt] = __builtin_amdgcn_mfma_f32_16x16x32_bf16(afr, bfr, acc[mt], 0, 0, 0);
        }
    }

    // ---- epilogue: write combined_t[pos][co], 8 B packed stores
    bf16* ct = combined + ((size_t)b * HWP + pos0 + l16) * 384;
    #pragma unroll
    for (int mt = 0; mt < 4; mt++) {
        int co_b = wv * 64 + mt * 16 + quad * 4;
        uint2 pk;
        pk.x = (unsigned)f2bfbits(acc[mt][0] + bias[co_b])     | ((unsigned)f2bfbits(acc[mt][1] + bias[co_b + 1]) << 16);
        pk.y = (unsigned)f2bfbits(acc[mt][2] + bias[co_b + 2]) | ((unsigned)f2bfbits(acc[mt][3] + bias[co_b + 3]) << 16);
        *(uint2*)(ct + co_b) = pk;
    }
}

// ---------------------------------------------------------------- SA GEMM: D[j][b][pos] = wSA[j]. combined_t[pos]
// grid 1024 (b x 256 tiles), block 256 = 4 waves (wave = 16 j-rows). LDS-free streaming MFMA.
__global__ __launch_bounds__(256) void sa_gemm_kernel(
    const bf16* __restrict__ combined, const bf16* __restrict__ wSA, float* __restrict__ part)
{
    const int bid = blockIdx.x;
    const int b = bid >> 8, tile = bid & 255;
    const int pos0 = tile * 16;
    const int tid = threadIdx.x;
    const int lane = tid & 63, wv = tid >> 6;
    const int quad = lane >> 4, l16 = lane & 15;

    f32x4 acc = {0, 0, 0, 0};
    const bf16* fb = combined + ((size_t)b * HWP + pos0 + l16) * 384 + quad * 8;
    const bf16* aw = wSA + (size_t)(wv * 16 + l16) * 384 + quad * 8;
    for (int kt = 0; kt < 12; kt++) {
        sh8 bfr = *(const sh8*)(fb + kt * 32);
        sh8 afr = *(const sh8*)(aw + kt * 32);
        acc = __builtin_amdgcn_mfma_f32_16x16x32_bf16(afr, bfr, acc, 0, 0, 0);
    }
    #pragma unroll
    for (int r = 0; r < 4; r++) {
        int j = wv * 16 + quad * 4 + r;
        if (j < 49) part[(size_t)(j * BN + b) * HWP + pos0 + l16] = acc[r];
    }
}

// ---------------------------------------------------------------- attn finalize: 49-tap shifted sum
__global__ __launch_bounds__(256) void attn_fin_kernel(
    const float* __restrict__ part, const float* __restrict__ sa_b, float* __restrict__ attn)
{
    int i = blockIdx.x * 256 + threadIdx.x;
    if (i >= BN * HWP) return;
    int b = i >> 12, pos = i & 4095;
    int y = pos >> 6, x = pos & 63;
    float s = sa_b[0];
    #pragma unroll
    for (int j = 0; j < 49; j++) {
        int yy = y + j / 7 - 3, xx = x + j % 7 - 3;
        if (yy < 0 || yy > 63 || xx < 0 || xx > 63) continue;
        s += part[(size_t)(j * BN + b) * HWP + yy * 64 + xx];
    }
    attn[i] = 1.f / (1.f + expf(-s));
}

// ---------------------------------------------------------------- fusion 1x1 MFMA: out = relu(acc*a*alpha + beta)
// grid 1024 (b x 256 tiles), block 256 = 4 waves (wave = 64 co). LDS-free streaming MFMA.
__global__ __launch_bounds__(256) void fuse_kernel(
    const bf16* __restrict__ combined, const float* __restrict__ attn,
    const bf16* __restrict__ wF, const float* __restrict__ fab, float* __restrict__ out)
{
    const int bid = blockIdx.x;
    const int b = bid >> 8, tile = bid & 255;
    const int pos0 = tile * 16;
    const int tid = threadIdx.x;
    const int lane = tid & 63, wv = tid >> 6;
    const int quad = lane >> 4, l16 = lane & 15;

    f32x4 acc[4] = {f32x4{0,0,0,0}, f32x4{0,0,0,0}, f32x4{0,0,0,0}, f32x4{0,0,0,0}};
    const bf16* fb = combined + ((size_t)b * HWP + pos0 + l16) * 384 + quad * 8;
    const bf16* wbase = wF + (size_t)(wv * 64 + l16) * 384 + quad * 8;
    for (int kt = 0; kt < 12; kt++) {
        sh8 bfr = *(const sh8*)(fb + kt * 32);
        #pragma unroll
        for (int mt = 0; mt < 4; mt++) {
            sh8 afr = *(const sh8*)(wbase + (size_t)mt * 16 * 384 + kt * 32);
            acc[mt] = __builtin_amdgcn_mfma_f32_16x16x32_bf16(afr, bfr, acc[mt], 0, 0, 0);
        }
    }

    float a = attn[(size_t)b * HWP + pos0 + l16];
    float* op = out + (size_t)b * COUT * HWP + pos0 + l16;
    #pragma unroll
    for (int mt = 0; mt < 4; mt++) {
        int co_b = wv * 64 + mt * 16 + quad * 4;
        #pragma unroll
        for (int r = 0; r < 4; r++) {
            int co = co_b + r;
            float o = fmaxf(acc[mt][r] * a * fab[co] + fab[256 + co], 0.f);
            op[(size_t)co * HWP] = o;
        }
    }
}

// ================================================================ launch
extern "C" void kernel_launch(void* const* d_in, const int* in_sizes, int n_in,
                              void* d_out, int out_size, void* d_ws, size_t ws_size,
                              hipStream_t stream)
{
    const float* x      = (const float*)d_in[0];
    const float* oc1_w  = (const float*)d_in[1];
    const float* oc1_b  = (const float*)d_in[2];
    const float* obn_g  = (const float*)d_in[3];
    const float* obn_b  = (const float*)d_in[4];
    const float* obn_m  = (const float*)d_in[5];
    const float* obn_v  = (const float*)d_in[6];
    const float* oc2_w  = (const float*)d_in[7];
    const float* oc2_b  = (const float*)d_in[8];
    const float* mc1_w  = (const float*)d_in[9];
    const float* mc1_b  = (const float*)d_in[10];
    const float* mbn_g  = (const float*)d_in[11];
    const float* mbn_b  = (const float*)d_in[12];
    const float* mbn_m  = (const float*)d_in[13];
    const float* mbn_v  = (const float*)d_in[14];
    const float* mc2_w  = (const float*)d_in[15];
    const float* mc2_b  = (const float*)d_in[16];
    const float* dc_w   = (const float*)d_in[17];
    const float* dc_b   = (const float*)d_in[18];
    const float* cb_dw_w= (const float*)d_in[19];
    const float* cb_dw_b= (const float*)d_in[20];
    const float* cbn_g  = (const float*)d_in[21];
    const float* cbn_b  = (const float*)d_in[22];
    const float* cbn_m  = (const float*)d_in[23];
    const float* cbn_v  = (const float*)d_in[24];
    const float* cb_pw_w= (const float*)d_in[25];
    const float* cb_pw_b= (const float*)d_in[26];
    const float* sa_w   = (const float*)d_in[27];
    const float* sa_b   = (const float*)d_in[28];
    const float* fu_w   = (const float*)d_in[29];
    const float* fu_b   = (const float*)d_in[30];
    const float* fbn_g  = (const float*)d_in[31];
    const float* fbn_b  = (const float*)d_in[32];
    const float* fbn_m  = (const float*)d_in[33];
    const float* fbn_v  = (const float*)d_in[34];

    // workspace layout (~29.1 MB)
    bf16*  h     = (bf16*)d_ws;                //   524,288 bf16
    bf16*  hm    = h + 524288;                 //   524,288 bf16
    float* offsb = (float*)(hm + 524288);      //   294,912 f32
    float* mskb  = offsb + 294912;             //   147,456 f32
    bf16*  hc    = (bf16*)(mskb + 147456);     // 2,097,152 bf16
    bf16*  comb  = hc + 2097152;               // 6,291,456 bf16  (combined_t [b][pos][384])
    float* part  = (float*)(comb + 6291456);   //   802,816 f32  (49 x B x HWP)
    float* attn  = part + 802816;              //    16,384 f32
    bf16*  xt    = (bf16*)(attn + 16384);      // 2,097,152 bf16 (x transposed [b][pos][128])
    bf16*  wB    = xt + 2097152;               //   294,912 bf16
    bf16*  wC    = wB + 294912;                //    73,728 bf16
    float* ab    = (float*)(wC + 73728);       //       128 f32
    bf16*  wF    = (bf16*)(ab + 128);          //    98,304 bf16
    bf16*  wSA   = wF + 98304;                 //    24,576 bf16
    float* fab   = (float*)(wSA + 24576);      //       512 f32

    float* out = (float*)d_out;

    // 0. transpose x -> pixel-major bf16
    transpose_x_kernel<<<256, 256, 0, stream>>>(x, xt);
    // 1. weight preps
    prep_wB_kernel<<<1152, 256, 0, stream>>>(dc_w, wB);
    prep_conv1_kernel<<<289, 256, 0, stream>>>(oc1_w, oc1_b, obn_g, obn_b, obn_m, obn_v,
                                               mc1_w, mc1_b, mbn_g, mbn_b, mbn_m, mbn_v, wC, ab);
    prep_fuse_kernel<<<482, 256, 0, stream>>>(fu_w, fu_b, fbn_g, fbn_b, fbn_m, fbn_v, sa_w,
                                              wF, wSA, fab);
    // 2. oc1 + mc1 fused MFMA conv (+folded BN+ReLU)
    conv1_mfma_kernel<<<1024, 256, 0, stream>>>(xt, wC, ab, h, hm);
    // 3. offset conv2 (raw, fp32 out)
    conv3x3_kernel<0, 0><<<dim3(18, 16, 4), 256, 32 * 9 * 4, stream>>>(
        h, oc2_w, oc2_b, (const float*)nullptr, (const float*)nullptr,
        (const float*)nullptr, (const float*)nullptr, offsb, 32, 18);
    // 4. mask conv2 (+sigmoid, fp32 out)
    conv3x3_kernel<2, 0><<<dim3(9, 16, 4), 256, 32 * 9 * 4, stream>>>(
        hm, mc2_w, mc2_b, (const float*)nullptr, (const float*)nullptr,
        (const float*)nullptr, (const float*)nullptr, mskb, 32, 9);
    // 5. contour depthwise (+BN+ReLU)
    dwconv_kernel<<<8192, 256, 0, stream>>>(x, cb_dw_w, cb_dw_b, cbn_g, cbn_b, cbn_m, cbn_v, hc);
    // 6. contour pointwise -> combined_t[:, 256:384]
    pw_kernel<<<dim3(16, 16, 4), 256, 0, stream>>>(hc, cb_pw_w, cb_pw_b, comb, 128);
    // 7. modulated deformable conv (MFMA) -> combined_t[:, 0:256]
    deform_kernel<<<1024, 256, 0, stream>>>(xt, offsb, mskb, wB, dc_b, comb);
    // 8. SA GEMM (MFMA, LDS-free)
    sa_gemm_kernel<<<1024, 256, 0, stream>>>(comb, wSA, part);
    // 9. attn finalize
    attn_fin_kernel<<<64, 256, 0, stream>>>(part, sa_b, attn);
    // 10. fusion 1x1 MFMA (+attn scale, folded BN, ReLU) -> fp32 out
    fuse_kernel<<<1024, 256, 0, stream>>>(comb, attn, wF, fab, out);
}

// Round 8
// 360.687 us; speedup vs baseline: 4.0513x; 1.1991x over previous
//
#include <hip/hip_runtime.h>
#include <hip/hip_bf16.h>
#include <math.h>

// Problem constants
#define BN   4
#define CIN  128
#define COUT 256
#define HWP  4096      // 64*64

typedef __hip_bfloat16 bf16;
typedef __attribute__((ext_vector_type(8))) short sh8;    // 8 bf16 = 4 VGPR
typedef __attribute__((ext_vector_type(4))) float f32x4;  // MFMA accumulator

__device__ __forceinline__ float b2f(bf16 v) { return __bfloat162float(v); }
__device__ __forceinline__ float bflo(unsigned u) { return __uint_as_float(u << 16); }
__device__ __forceinline__ float bfhi(unsigned u) { return __uint_as_float(u & 0xffff0000u); }
__device__ __forceinline__ unsigned short f2bfbits(float f) {
    union { bf16 h; unsigned short u; } cv; cv.h = __float2bfloat16(f); return cv.u;
}
__device__ __forceinline__ float bfj(const uint4& c, int j) {
    unsigned u = (&c.x)[j >> 1];
    return (j & 1) ? bfhi(u) : bflo(u);
}

__device__ __forceinline__ float ldv(const float* p, size_t i) { return p[i]; }
__device__ __forceinline__ float ldv(const bf16* p, size_t i) { return b2f(p[i]); }
__device__ __forceinline__ void stv(float* p, size_t i, float v) { p[i] = v; }
__device__ __forceinline__ void stv(bf16* p, size_t i, float v) { p[i] = __float2bfloat16(v); }

// ---------------------------------------------------------------- x [b][ci][pos] f32 -> xt [b][pos][ci] bf16
__global__ __launch_bounds__(256) void transpose_x_kernel(const float* __restrict__ x,
                                                          bf16* __restrict__ xt)
{
    __shared__ bf16 t[64][136];
    const int b = blockIdx.x >> 6, chunk = blockIdx.x & 63;
    const int pos0 = chunk * 64;
    const int tid = threadIdx.x;
    const int lane = tid & 63, wv = tid >> 6;
    const float* xb = x + (size_t)b * CIN * HWP + pos0 + lane;
    #pragma unroll 4
    for (int j = 0; j < 32; j++) {
        int ci = wv * 32 + j;
        t[lane][ci] = __float2bfloat16(xb[(size_t)ci * HWP]);
    }
    __syncthreads();
    const int p = tid >> 2, cig = tid & 3;
    uint4* dst = (uint4*)(xt + ((size_t)b * HWP + pos0 + p) * 128 + cig * 32);
    const uint4* src = (const uint4*)&t[p][cig * 32];
    #pragma unroll
    for (int q = 0; q < 4; q++) dst[q] = src[q];
}

// ------------------------------------------------- deform weights, fragment-major:
// wBf[ ((wv*36+kt)*4+mt)*64 + quad*16 + l16 ][8j] = dc_w[co=wv*64+mt*16+l16][ci*9+k], kk=kt*32+quad*8+j
__global__ __launch_bounds__(256) void prep_wBf_kernel(const float* __restrict__ w,
                                                       bf16* __restrict__ wBf) {
    int o = blockIdx.x * 256 + threadIdx.x;
    if (o >= 256 * 1152) return;
    int j = o & 7, o2 = o >> 3;
    int lane = o2 & 63, t = o2 >> 6;
    int l16 = lane & 15, quad = lane >> 4;
    int mt = t & 3, t2 = t >> 2;
    int kt = t2 % 36, wv = t2 / 36;
    int co = wv * 64 + mt * 16 + l16;
    int kk = kt * 32 + quad * 8 + j;
    int k = kk >> 7, ci = kk & 127;
    wBf[o] = __float2bfloat16(w[co * 1152 + ci * 9 + k]);
}

// ------------------------------------------------- conv1 weights fragment-major + folded BN
// wCf[ (wv*36+kt)*64 + quad*16+l16 ][8j], co = wv*16+l16
__global__ __launch_bounds__(256) void prep_conv1_kernel(
    const float* __restrict__ oc1_w, const float* __restrict__ oc1_b,
    const float* __restrict__ obn_g, const float* __restrict__ obn_b,
    const float* __restrict__ obn_m, const float* __restrict__ obn_v,
    const float* __restrict__ mc1_w, const float* __restrict__ mc1_b,
    const float* __restrict__ mbn_g, const float* __restrict__ mbn_b,
    const float* __restrict__ mbn_m, const float* __restrict__ mbn_v,
    bf16* __restrict__ wCf, float* __restrict__ ab)
{
    int o = blockIdx.x * 256 + threadIdx.x;
    if (o < 64 * 1152) {
        int j = o & 7, o2 = o >> 3;
        int lane = o2 & 63, t = o2 >> 6;
        int l16 = lane & 15, quad = lane >> 4;
        int kt = t % 36, wv = t / 36;
        int co = wv * 16 + l16;
        int kk = kt * 32 + quad * 8 + j;
        int k = kk >> 7, ci = kk & 127;
        float v = (co < 32) ? oc1_w[co * 1152 + ci * 9 + k]
                            : mc1_w[(co - 32) * 1152 + ci * 9 + k];
        wCf[o] = __float2bfloat16(v);
    } else if (o < 64 * 1152 + 64) {
        int c = o - 64 * 1152;
        float g, bb, m, vv, bias;
        if (c < 32) { g = obn_g[c]; bb = obn_b[c]; m = obn_m[c]; vv = obn_v[c]; bias = oc1_b[c]; }
        else { int c2 = c - 32; g = mbn_g[c2]; bb = mbn_b[c2]; m = mbn_m[c2]; vv = mbn_v[c2]; bias = mc1_b[c2]; }
        float alpha = g / sqrtf(vv + 1e-5f);
        ab[c] = alpha;
        ab[64 + c] = (bias - m) * alpha + bb;
    }
}

// ------------------------------------------------- fuse + SA weights fragment-major + folded fuse BN
__global__ __launch_bounds__(256) void prep_fuse_kernel(
    const float* __restrict__ fu_w, const float* __restrict__ fu_b,
    const float* __restrict__ fbn_g, const float* __restrict__ fbn_b,
    const float* __restrict__ fbn_m, const float* __restrict__ fbn_v,
    const float* __restrict__ sa_w,
    bf16* __restrict__ wFf, bf16* __restrict__ wSAf, float* __restrict__ fab)
{
    int o = blockIdx.x * 256 + threadIdx.x;
    if (o < 98304) {
        // wFf[ ((wv*12+kt)*4+mt)*64 + lane ][8j], co = wv*64+mt*16+l16, kk = kt*32+quad*8+j
        int j = o & 7, o2 = o >> 3;
        int lane = o2 & 63, t = o2 >> 6;
        int l16 = lane & 15, quad = lane >> 4;
        int mt = t & 3, t2 = t >> 2;
        int kt = t2 % 12, wv = t2 / 12;
        int co = wv * 64 + mt * 16 + l16;
        int kk = kt * 32 + quad * 8 + j;
        wFf[o] = __float2bfloat16(fu_w[co * 384 + kk]);
    } else if (o < 98304 + 24576) {
        // wSAf[ (wv*12+kt)*64 + lane ][8j], jr = wv*16+l16, kk = kt*32+quad*8+j
        int idx = o - 98304;
        int j = idx & 7, o2 = idx >> 3;
        int lane = o2 & 63, t = o2 >> 6;
        int l16 = lane & 15, quad = lane >> 4;
        int kt = t % 12, wv = t / 12;
        int jr = wv * 16 + l16;
        int kk = kt * 32 + quad * 8 + j;
        wSAf[idx] = (jr < 49) ? __float2bfloat16(sa_w[kk * 49 + jr]) : __float2bfloat16(0.f);
    } else if (o < 98304 + 24576 + 256) {
        int co = o - 98304 - 24576;
        float alpha = fbn_g[co] / sqrtf(fbn_v[co] + 1e-5f);
        fab[co] = alpha;
        fab[256 + co] = (fu_b[co] - fbn_m[co]) * alpha + fbn_b[co];
    }
}

// ---------------------------------------------------------------- conv1 (oc1+mc1) MFMA im2col GEMM
__global__ __launch_bounds__(256) void conv1_mfma_kernel(
    const bf16* __restrict__ xt, const bf16* __restrict__ wCf, const float* __restrict__ ab,
    bf16* __restrict__ h, bf16* __restrict__ hm)
{
    __shared__ __align__(16) bf16 val[16][1160];

    const int bid = blockIdx.x;
    const int b = (bid & 7) >> 1;
    const int tile = ((bid >> 3) << 1) | (bid & 1);
    const int pos0 = tile * 16;
    const int y = tile >> 2, x0 = (tile & 3) * 16;
    const int tid = threadIdx.x;
    const int cig = tid & 15, pix = tid >> 4;
    const int ci0 = cig * 8;
    const int xxp = x0 + pix;

    const bf16* xtb = xt + (size_t)b * HWP * 128;
    #pragma unroll
    for (int k = 0; k < 9; k++) {
        int yy = y + k / 3 - 1, xx = xxp + k % 3 - 1;
        bool valid = (yy >= 0 && yy <= 63 && xx >= 0 && xx <= 63);
        uint4 c = {0, 0, 0, 0};
        if (valid) c = *(const uint4*)(xtb + (size_t)(yy * 64 + xx) * 128 + ci0);
        *(uint4*)&val[pix][k * 128 + ci0] = c;
    }
    __syncthreads();

    const int lane = tid & 63, wv = tid >> 6;
    const int quad = lane >> 4, l16 = lane & 15;
    f32x4 acc = {0, 0, 0, 0};
    const bf16* wl0 = wCf + (size_t)wv * 36 * 512 + lane * 8;   // frag kt at + kt*512
    const bf16* vbase = &val[l16][quad * 8];

    sh8 af = *(const sh8*)(wl0);
    sh8 bf = *(const sh8*)(vbase);
    sh8 afn, bfn;
    for (int kt = 0; kt < 36; kt++) {
        if (kt < 35) {
            afn = *(const sh8*)(wl0 + (kt + 1) * 512);
            bfn = *(const sh8*)(vbase + (kt + 1) * 32);
        }
        acc = __builtin_amdgcn_mfma_f32_16x16x32_bf16(af, bf, acc, 0, 0, 0);
        af = afn; bf = bfn;
    }

    #pragma unroll
    for (int r = 0; r < 4; r++) {
        int co = wv * 16 + quad * 4 + r;
        float o = fmaxf(acc[r] * ab[co] + ab[64 + co], 0.f);
        bf16 v16 = __float2bfloat16(o);
        if (co < 32) h[(size_t)(b * 32 + co) * HWP + pos0 + l16] = v16;
        else         hm[(size_t)(b * 32 + (co - 32)) * HWP + pos0 + l16] = v16;
    }
}

// ---------------------------------------------------------------- generic 3x3 conv (for oc2/mc2)
template<int ACT, int USE_BN, typename IT, typename OT>
__global__ __launch_bounds__(256) void conv3x3_kernel(
    const IT* __restrict__ in, const float* __restrict__ w, const float* __restrict__ bias,
    const float* __restrict__ bn_g, const float* __restrict__ bn_b,
    const float* __restrict__ bn_m, const float* __restrict__ bn_v,
    OT* __restrict__ out, int CI, int CO)
{
    extern __shared__ float wl[];
    const int co = blockIdx.x, strip = blockIdx.y, b = blockIdx.z;
    const int nt = CI * 9;
    for (int i = threadIdx.x; i < nt; i += 256) wl[i] = w[co * nt + i];
    __syncthreads();

    const int tx = threadIdx.x & 63, ty = threadIdx.x >> 6;
    const int y = strip * 4 + ty, x = tx;
    float acc = bias[co];
    const IT* ip = in + (size_t)(b * CI) * HWP;
    for (int ci = 0; ci < CI; ci++) {
        const IT* p = ip + ci * HWP;
        const float* wp = wl + ci * 9;
        #pragma unroll
        for (int ky = 0; ky < 3; ky++) {
            int yy = y + ky - 1;
            if (yy < 0 || yy > 63) continue;
            #pragma unroll
            for (int kx = 0; kx < 3; kx++) {
                int xx = x + kx - 1;
                if (xx < 0 || xx > 63) continue;
                acc += ldv(p, yy * 64 + xx) * wp[ky * 3 + kx];
            }
        }
    }
    if (USE_BN) {
        float sc = bn_g[co] / sqrtf(bn_v[co] + 1e-5f);
        acc = (acc - bn_m[co]) * sc + bn_b[co];
    }
    if (ACT == 1) acc = fmaxf(acc, 0.f);
    else if (ACT == 2) acc = 1.f / (1.f + expf(-acc));
    stv(out, (size_t)(b * CO + co) * HWP + y * 64 + x, acc);
}

// ---------------------------------------------------------------- depthwise 3x3 + BN + ReLU
__global__ __launch_bounds__(256) void dwconv_kernel(
    const float* __restrict__ in, const float* __restrict__ w, const float* __restrict__ bias,
    const float* __restrict__ bn_g, const float* __restrict__ bn_b,
    const float* __restrict__ bn_m, const float* __restrict__ bn_v,
    bf16* __restrict__ out)
{
    int i = blockIdx.x * 256 + threadIdx.x;
    if (i >= BN * CIN * HWP) return;
    int x = i & 63, y = (i >> 6) & 63, c = (i >> 12) & 127;
    int b = i >> 19;
    float acc = bias[c];
    const float* p = in + (size_t)(b * CIN + c) * HWP;
    #pragma unroll
    for (int ky = 0; ky < 3; ky++) {
        int yy = y + ky - 1;
        if (yy < 0 || yy > 63) continue;
        #pragma unroll
        for (int kx = 0; kx < 3; kx++) {
            int xx = x + kx - 1;
            if (xx < 0 || xx > 63) continue;
            acc += p[yy * 64 + xx] * w[c * 9 + ky * 3 + kx];
        }
    }
    float sc = bn_g[c] / sqrtf(bn_v[c] + 1e-5f);
    acc = (acc - bn_m[c]) * sc + bn_b[c];
    acc = fmaxf(acc, 0.f);
    out[i] = __float2bfloat16(acc);
}

// ---------------------------------------------------------------- pointwise 1x1 -> combined_t[pos][256+co]
__global__ __launch_bounds__(256) void pw_kernel(
    const bf16* __restrict__ in, const float* __restrict__ w, const float* __restrict__ bias,
    bf16* __restrict__ combined, int CI)
{
    __shared__ float wl[8 * 128];
    const int cog = blockIdx.x, strip = blockIdx.y, b = blockIdx.z;
    const int co0 = cog * 8;
    for (int i = threadIdx.x; i < 8 * CI; i += 256) wl[i] = w[co0 * CI + i];
    __syncthreads();
    const int tx = threadIdx.x & 63, ty = threadIdx.x >> 6;
    const int pos = (strip * 4 + ty) * 64 + tx;
    float acc[8];
    #pragma unroll
    for (int cs = 0; cs < 8; cs++) acc[cs] = bias[co0 + cs];
    const bf16* ip = in + (size_t)b * CI * HWP + pos;
    for (int ci = 0; ci < CI; ci++) {
        float v = b2f(ip[ci * HWP]);
        #pragma unroll
        for (int cs = 0; cs < 8; cs++) acc[cs] += v * wl[cs * CI + ci];
    }
    uint4 pk;
    pk.x = (unsigned)f2bfbits(acc[0]) | ((unsigned)f2bfbits(acc[1]) << 16);
    pk.y = (unsigned)f2bfbits(acc[2]) | ((unsigned)f2bfbits(acc[3]) << 16);
    pk.z = (unsigned)f2bfbits(acc[4]) | ((unsigned)f2bfbits(acc[5]) << 16);
    pk.w = (unsigned)f2bfbits(acc[6]) | ((unsigned)f2bfbits(acc[7]) << 16);
    *(uint4*)(combined + ((size_t)b * HWP + pos) * 384 + 256 + co0) = pk;
}

// ---------------------------------------------------------------- modulated deformable conv (MFMA)
__global__ __launch_bounds__(256) void deform_kernel(
    const bf16* __restrict__ xt, const float* __restrict__ offs, const float* __restrict__ msk,
    const bf16* __restrict__ wBf, const float* __restrict__ bias, bf16* __restrict__ combined)
{
    __shared__ __align__(16) bf16 val[16][1160];
    __shared__ int   ti[144][4];
    __shared__ float tw[144][4];

    const int bid = blockIdx.x;
    const int b = (bid & 7) >> 1;
    const int tile = ((bid >> 3) << 1) | (bid & 1);
    const int pos0 = tile * 16;
    const int tid = threadIdx.x;

    if (tid < 144) {                      // e = k*16 + pix
        int k = tid >> 4, pix = tid & 15;
        int pos = pos0 + pix;
        int y = pos >> 6, xc = pos & 63;
        float offy = offs[(size_t)(b * 18 + 2 * k) * HWP + pos];
        float offx = offs[(size_t)(b * 18 + 2 * k + 1) * HWP + pos];
        float m = msk[(size_t)(b * 9 + k) * HWP + pos];
        float py = (float)(y - 1 + k / 3) + offy;
        float px = (float)(xc - 1 + k % 3) + offx;
        float fy = floorf(py), fx = floorf(px);
        float wy1 = py - fy, wx1 = px - fx;
        int y0 = (int)fy, x0 = (int)fx;
        int y1 = y0 + 1, x1 = x0 + 1;
        bool vy0 = (y0 >= 0 && y0 <= 63), vy1 = (y1 >= 0 && y1 <= 63);
        bool vx0 = (x0 >= 0 && x0 <= 63), vx1 = (x1 >= 0 && x1 <= 63);
        int cy0 = min(max(y0, 0), 63), cy1 = min(max(y1, 0), 63);
        int cx0 = min(max(x0, 0), 63), cx1 = min(max(x1, 0), 63);
        ti[tid][0] = cy0 * 64 + cx0;  tw[tid][0] = (vy0 && vx0) ? (1.f - wy1) * (1.f - wx1) * m : 0.f;
        ti[tid][1] = cy0 * 64 + cx1;  tw[tid][1] = (vy0 && vx1) ? (1.f - wy1) * wx1 * m : 0.f;
        ti[tid][2] = cy1 * 64 + cx0;  tw[tid][2] = (vy1 && vx0) ? wy1 * (1.f - wx1) * m : 0.f;
        ti[tid][3] = cy1 * 64 + cx1;  tw[tid][3] = (vy1 && vx1) ? wy1 * wx1 * m : 0.f;
    }
    __syncthreads();

    // ---- gather: lane = ci-group, fully coalesced dwordx4 from xt
    {
        const int cig = tid & 15, pix = tid >> 4;
        const int ci0 = cig * 8;
        const bf16* xtb = xt + (size_t)b * HWP * 128;
        for (int k = 0; k < 9; k++) {
            const int e = k * 16 + pix;
            const int i0 = ti[e][0], i1 = ti[e][1], i2 = ti[e][2], i3 = ti[e][3];
            const float w0 = tw[e][0], w1 = tw[e][1], w2 = tw[e][2], w3 = tw[e][3];
            uint4 c0 = *(const uint4*)(xtb + (size_t)i0 * 128 + ci0);
            uint4 c1 = *(const uint4*)(xtb + (size_t)i1 * 128 + ci0);
            uint4 c2 = *(const uint4*)(xtb + (size_t)i2 * 128 + ci0);
            uint4 c3 = *(const uint4*)(xtb + (size_t)i3 * 128 + ci0);
            float g[8];
            #pragma unroll
            for (int j = 0; j < 8; j++)
                g[j] = w0 * bfj(c0, j) + w1 * bfj(c1, j) + w2 * bfj(c2, j) + w3 * bfj(c3, j);
            uint4 pk;
            pk.x = (unsigned)f2bfbits(g[0]) | ((unsigned)f2bfbits(g[1]) << 16);
            pk.y = (unsigned)f2bfbits(g[2]) | ((unsigned)f2bfbits(g[3]) << 16);
            pk.z = (unsigned)f2bfbits(g[4]) | ((unsigned)f2bfbits(g[5]) << 16);
            pk.w = (unsigned)f2bfbits(g[6]) | ((unsigned)f2bfbits(g[7]) << 16);
            *(uint4*)&val[pix][k * 128 + ci0] = pk;
        }
    }
    __syncthreads();

    // ---- MFMA: wave wv owns co [wv*64, wv*64+64) x 16 pixels; prefetched, coalesced weights
    const int lane = tid & 63, wv = tid >> 6;
    const int quad = lane >> 4, l16 = lane & 15;
    f32x4 acc[4] = {f32x4{0,0,0,0}, f32x4{0,0,0,0}, f32x4{0,0,0,0}, f32x4{0,0,0,0}};

    const bf16* wl0 = wBf + (size_t)wv * 73728 + lane * 8;   // frag(kt,mt) at + (kt*4+mt)*512
    const bf16* vbase = &val[l16][quad * 8];

    sh8 af[4], afn[4], bf, bfn;
    bf = *(const sh8*)(vbase);
    #pragma unroll
    for (int mt = 0; mt < 4; mt++) af[mt] = *(const sh8*)(wl0 + mt * 512);
    for (int kt = 0; kt < 36; kt++) {
        if (kt < 35) {
            bfn = *(const sh8*)(vbase + (kt + 1) * 32);
            #pragma unroll
            for (int mt = 0; mt < 4; mt++)
                afn[mt] = *(const sh8*)(wl0 + ((kt + 1) * 4 + mt) * 512);
        }
        #pragma unroll
        for (int mt = 0; mt < 4; mt++)
            acc[mt] = __builtin_amdgcn_mfma_f32_16x16x32_bf16(af[mt], bf, acc[mt], 0, 0, 0);
        bf = bfn;
        #pragma unroll
        for (int mt = 0; mt < 4; mt++) af[mt] = afn[mt];
    }

    // ---- epilogue: write combined_t[pos][co], 8 B packed stores
    bf16* ct = combined + ((size_t)b * HWP + pos0 + l16) * 384;
    #pragma unroll
    for (int mt = 0; mt < 4; mt++) {
        int co_b = wv * 64 + mt * 16 + quad * 4;
        uint2 pk;
        pk.x = (unsigned)f2bfbits(acc[mt][0] + bias[co_b])     | ((unsigned)f2bfbits(acc[mt][1] + bias[co_b + 1]) << 16);
        pk.y = (unsigned)f2bfbits(acc[mt][2] + bias[co_b + 2]) | ((unsigned)f2bfbits(acc[mt][3] + bias[co_b + 3]) << 16);
        *(uint2*)(ct + co_b) = pk;
    }
}

// ---------------------------------------------------------------- SA GEMM (MFMA, LDS-free, prefetched)
__global__ __launch_bounds__(256) void sa_gemm_kernel(
    const bf16* __restrict__ combined, const bf16* __restrict__ wSAf, float* __restrict__ part)
{
    const int bid = blockIdx.x;
    const int b = bid >> 8, tile = bid & 255;
    const int pos0 = tile * 16;
    const int tid = threadIdx.x;
    const int lane = tid & 63, wv = tid >> 6;
    const int quad = lane >> 4, l16 = lane & 15;

    f32x4 acc = {0, 0, 0, 0};
    const bf16* fb = combined + ((size_t)b * HWP + pos0 + l16) * 384 + quad * 8;
    const bf16* wl0 = wSAf + (size_t)wv * 6144 + lane * 8;   // frag kt at + kt*512

    sh8 af = *(const sh8*)(wl0);
    sh8 bf = *(const sh8*)(fb);
    sh8 afn, bfn;
    for (int kt = 0; kt < 12; kt++) {
        if (kt < 11) {
            afn = *(const sh8*)(wl0 + (kt + 1) * 512);
            bfn = *(const sh8*)(fb + (kt + 1) * 32);
        }
        acc = __builtin_amdgcn_mfma_f32_16x16x32_bf16(af, bf, acc, 0, 0, 0);
        af = afn; bf = bfn;
    }
    #pragma unroll
    for (int r = 0; r < 4; r++) {
        int j = wv * 16 + quad * 4 + r;
        if (j < 49) part[(size_t)(j * BN + b) * HWP + pos0 + l16] = acc[r];
    }
}

// ---------------------------------------------------------------- attn finalize: 49-tap shifted sum
__global__ __launch_bounds__(256) void attn_fin_kernel(
    const float* __restrict__ part, const float* __restrict__ sa_b, float* __restrict__ attn)
{
    int i = blockIdx.x * 256 + threadIdx.x;
    if (i >= BN * HWP) return;
    int b = i >> 12, pos = i & 4095;
    int y = pos >> 6, x = pos & 63;
    float s = sa_b[0];
    #pragma unroll
    for (int j = 0; j < 49; j++) {
        int yy = y + j / 7 - 3, xx = x + j % 7 - 3;
        if (yy < 0 || yy > 63 || xx < 0 || xx > 63) continue;
        s += part[(size_t)(j * BN + b) * HWP + yy * 64 + xx];
    }
    attn[i] = 1.f / (1.f + expf(-s));
}

// ---------------------------------------------------------------- fusion 1x1 MFMA (prefetched)
__global__ __launch_bounds__(256) void fuse_kernel(
    const bf16* __restrict__ combined, const float* __restrict__ attn,
    const bf16* __restrict__ wFf, const float* __restrict__ fab, float* __restrict__ out)
{
    const int bid = blockIdx.x;
    const int b = bid >> 8, tile = bid & 255;
    const int pos0 = tile * 16;
    const int tid = threadIdx.x;
    const int lane = tid & 63, wv = tid >> 6;
    const int quad = lane >> 4, l16 = lane & 15;

    f32x4 acc[4] = {f32x4{0,0,0,0}, f32x4{0,0,0,0}, f32x4{0,0,0,0}, f32x4{0,0,0,0}};
    const bf16* fb = combined + ((size_t)b * HWP + pos0 + l16) * 384 + quad * 8;
    const bf16* wl0 = wFf + (size_t)wv * 24576 + lane * 8;   // frag(kt,mt) at + (kt*4+mt)*512

    sh8 af[4], afn[4], bf, bfn;
    bf = *(const sh8*)(fb);
    #pragma unroll
    for (int mt = 0; mt < 4; mt++) af[mt] = *(const sh8*)(wl0 + mt * 512);
    for (int kt = 0; kt < 12; kt++) {
        if (kt < 11) {
            bfn = *(const sh8*)(fb + (kt + 1) * 32);
            #pragma unroll
            for (int mt = 0; mt < 4; mt++)
                afn[mt] = *(const sh8*)(wl0 + ((kt + 1) * 4 + mt) * 512);
        }
        #pragma unroll
        for (int mt = 0; mt < 4; mt++)
            acc[mt] = __builtin_amdgcn_mfma_f32_16x16x32_bf16(af[mt], bf, acc[mt], 0, 0, 0);
        bf = bfn;
        #pragma unroll
        for (int mt = 0; mt < 4; mt++) af[mt] = afn[mt];
    }

    float a = attn[(size_t)b * HWP + pos0 + l16];
    float* op = out + (size_t)b * COUT * HWP + pos0 + l16;
    #pragma unroll
    for (int mt = 0; mt < 4; mt++) {
        int co_b = wv * 64 + mt * 16 + quad * 4;
        #pragma unroll
        for (int r = 0; r < 4; r++) {
            int co = co_b + r;
            float o = fmaxf(acc[mt][r] * a * fab[co] + fab[256 + co], 0.f);
            op[(size_t)co * HWP] = o;
        }
    }
}

// ================================================================ launch
extern "C" void kernel_launch(void* const* d_in, const int* in_sizes, int n_in,
                              void* d_out, int out_size, void* d_ws, size_t ws_size,
                              hipStream_t stream)
{
    const float* x      = (const float*)d_in[0];
    const float* oc1_w  = (const float*)d_in[1];
    const float* oc1_b  = (const float*)d_in[2];
    const float* obn_g  = (const float*)d_in[3];
    const float* obn_b  = (const float*)d_in[4];
    const float* obn_m  = (const float*)d_in[5];
    const float* obn_v  = (const float*)d_in[6];
    const float* oc2_w  = (const float*)d_in[7];
    const float* oc2_b  = (const float*)d_in[8];
    const float* mc1_w  = (const float*)d_in[9];
    const float* mc1_b  = (const float*)d_in[10];
    const float* mbn_g  = (const float*)d_in[11];
    const float* mbn_b  = (const float*)d_in[12];
    const float* mbn_m  = (const float*)d_in[13];
    const float* mbn_v  = (const float*)d_in[14];
    const float* mc2_w  = (const float*)d_in[15];
    const float* mc2_b  = (const float*)d_in[16];
    const float* dc_w   = (const float*)d_in[17];
    const float* dc_b   = (const float*)d_in[18];
    const float* cb_dw_w= (const float*)d_in[19];
    const float* cb_dw_b= (const float*)d_in[20];
    const float* cbn_g  = (const float*)d_in[21];
    const float* cbn_b  = (const float*)d_in[22];
    const float* cbn_m  = (const float*)d_in[23];
    const float* cbn_v  = (const float*)d_in[24];
    const float* cb_pw_w= (const float*)d_in[25];
    const float* cb_pw_b= (const float*)d_in[26];
    const float* sa_w   = (const float*)d_in[27];
    const float* sa_b   = (const float*)d_in[28];
    const float* fu_w   = (const float*)d_in[29];
    const float* fu_b   = (const float*)d_in[30];
    const float* fbn_g  = (const float*)d_in[31];
    const float* fbn_b  = (const float*)d_in[32];
    const float* fbn_m  = (const float*)d_in[33];
    const float* fbn_v  = (const float*)d_in[34];

    // workspace layout (~29.1 MB)
    bf16*  h     = (bf16*)d_ws;                //   524,288 bf16
    bf16*  hm    = h + 524288;                 //   524,288 bf16
    float* offsb = (float*)(hm + 524288);      //   294,912 f32
    float* mskb  = offsb + 294912;             //   147,456 f32
    bf16*  hc    = (bf16*)(mskb + 147456);     // 2,097,152 bf16
    bf16*  comb  = hc + 2097152;               // 6,291,456 bf16  (combined_t [b][pos][384])
    float* part  = (float*)(comb + 6291456);   //   802,816 f32  (49 x B x HWP)
    float* attn  = part + 802816;              //    16,384 f32
    bf16*  xt    = (bf16*)(attn + 16384);      // 2,097,152 bf16 (x transposed [b][pos][128])
    bf16*  wBf   = xt + 2097152;               //   294,912 bf16
    bf16*  wCf   = wBf + 294912;               //    73,728 bf16
    float* ab    = (float*)(wCf + 73728);      //       128 f32
    bf16*  wFf   = (bf16*)(ab + 128);          //    98,304 bf16
    bf16*  wSAf  = wFf + 98304;                //    24,576 bf16
    float* fab   = (float*)(wSAf + 24576);     //       512 f32

    float* out = (float*)d_out;

    // 0. transpose x -> pixel-major bf16
    transpose_x_kernel<<<256, 256, 0, stream>>>(x, xt);
    // 1. weight preps (fragment-major layouts)
    prep_wBf_kernel<<<1152, 256, 0, stream>>>(dc_w, wBf);
    prep_conv1_kernel<<<289, 256, 0, stream>>>(oc1_w, oc1_b, obn_g, obn_b, obn_m, obn_v,
                                               mc1_w, mc1_b, mbn_g, mbn_b, mbn_m, mbn_v, wCf, ab);
    prep_fuse_kernel<<<482, 256, 0, stream>>>(fu_w, fu_b, fbn_g, fbn_b, fbn_m, fbn_v, sa_w,
                                              wFf, wSAf, fab);
    // 2. oc1 + mc1 fused MFMA conv (+folded BN+ReLU)
    conv1_mfma_kernel<<<1024, 256, 0, stream>>>(xt, wCf, ab, h, hm);
    // 3. offset conv2 (raw, fp32 out)
    conv3x3_kernel<0, 0><<<dim3(18, 16, 4), 256, 32 * 9 * 4, stream>>>(
        h, oc2_w, oc2_b, (const float*)nullptr, (const float*)nullptr,
        (const float*)nullptr, (const float*)nullptr, offsb, 32, 18);
    // 4. mask conv2 (+sigmoid, fp32 out)
    conv3x3_kernel<2, 0><<<dim3(9, 16, 4), 256, 32 * 9 * 4, stream>>>(
        hm, mc2_w, mc2_b, (const float*)nullptr, (const float*)nullptr,
        (const float*)nullptr, (const float*)nullptr, mskb, 32, 9);
    // 5. contour depthwise (+BN+ReLU)
    dwconv_kernel<<<8192, 256, 0, stream>>>(x, cb_dw_w, cb_dw_b, cbn_g, cbn_b, cbn_m, cbn_v, hc);
    // 6. contour pointwise -> combined_t[:, 256:384]
    pw_kernel<<<dim3(16, 16, 4), 256, 0, stream>>>(hc, cb_pw_w, cb_pw_b, comb, 128);
    // 7. modulated deformable conv (MFMA) -> combined_t[:, 0:256]
    deform_kernel<<<1024, 256, 0, stream>>>(xt, offsb, mskb, wBf, dc_b, comb);
    // 8. SA GEMM (MFMA, LDS-free)
    sa_gemm_kernel<<<1024, 256, 0, stream>>>(comb, wSAf, part);
    // 9. attn finalize
    attn_fin_kernel<<<64, 256, 0, stream>>>(part, sa_b, attn);
    // 10. fusion 1x1 MFMA (+attn scale, folded BN, ReLU) -> fp32 out
    fuse_kernel<<<1024, 256, 0, stream>>>(comb, attn, wFf, fab, out);
}

// Round 9
// 237.586 us; speedup vs baseline: 6.1504x; 1.5181x over previous
//
#include <hip/hip_runtime.h>
#include <hip/hip_bf16.h>
#include <math.h>

// Problem constants
#define BN   4
#define CIN  128
#define COUT 256
#define HWP  4096      // 64*64

typedef __hip_bfloat16 bf16;
typedef __attribute__((ext_vector_type(8))) short sh8;    // 8 bf16 = 4 VGPR
typedef __attribute__((ext_vector_type(4))) float f32x4;  // MFMA accumulator

__device__ __forceinline__ float b2f(bf16 v) { return __bfloat162float(v); }
__device__ __forceinline__ float bflo(unsigned u) { return __uint_as_float(u << 16); }
__device__ __forceinline__ float bfhi(unsigned u) { return __uint_as_float(u & 0xffff0000u); }
__device__ __forceinline__ unsigned short f2bfbits(float f) {
    union { bf16 h; unsigned short u; } cv; cv.h = __float2bfloat16(f); return cv.u;
}
__device__ __forceinline__ float bfj(const uint4& c, int j) {
    unsigned u = (&c.x)[j >> 1];
    return (j & 1) ? bfhi(u) : bflo(u);
}

// ---------------------------------------------------------------- x [b][ci][pos] f32 -> xt [b][pos][ci] bf16
__global__ __launch_bounds__(256) void transpose_x_kernel(const float* __restrict__ x,
                                                          bf16* __restrict__ xt)
{
    __shared__ bf16 t[64][136];
    const int b = blockIdx.x >> 6, chunk = blockIdx.x & 63;
    const int pos0 = chunk * 64;
    const int tid = threadIdx.x;
    const int lane = tid & 63, wv = tid >> 6;
    const float* xb = x + (size_t)b * CIN * HWP + pos0 + lane;
    #pragma unroll 4
    for (int j = 0; j < 32; j++) {
        int ci = wv * 32 + j;
        t[lane][ci] = __float2bfloat16(xb[(size_t)ci * HWP]);
    }
    __syncthreads();
    const int p = tid >> 2, cig = tid & 3;
    uint4* dst = (uint4*)(xt + ((size_t)b * HWP + pos0 + p) * 128 + cig * 32);
    const uint4* src = (const uint4*)&t[p][cig * 32];
    #pragma unroll
    for (int q = 0; q < 4; q++) dst[q] = src[q];
}

// ------------------------------------------------- deform weights, fragment-major
__global__ __launch_bounds__(256) void prep_wBf_kernel(const float* __restrict__ w,
                                                       bf16* __restrict__ wBf) {
    int o = blockIdx.x * 256 + threadIdx.x;
    if (o >= 256 * 1152) return;
    int j = o & 7, o2 = o >> 3;
    int lane = o2 & 63, t = o2 >> 6;
    int l16 = lane & 15, quad = lane >> 4;
    int mt = t & 3, t2 = t >> 2;
    int kt = t2 % 36, wv = t2 / 36;
    int co = wv * 64 + mt * 16 + l16;
    int kk = kt * 32 + quad * 8 + j;
    int k = kk >> 7, ci = kk & 127;
    wBf[o] = __float2bfloat16(w[co * 1152 + ci * 9 + k]);
}

// ------------------------------------------------- conv1 weights fragment-major + folded BN
__global__ __launch_bounds__(256) void prep_conv1_kernel(
    const float* __restrict__ oc1_w, const float* __restrict__ oc1_b,
    const float* __restrict__ obn_g, const float* __restrict__ obn_b,
    const float* __restrict__ obn_m, const float* __restrict__ obn_v,
    const float* __restrict__ mc1_w, const float* __restrict__ mc1_b,
    const float* __restrict__ mbn_g, const float* __restrict__ mbn_b,
    const float* __restrict__ mbn_m, const float* __restrict__ mbn_v,
    bf16* __restrict__ wCf, float* __restrict__ ab)
{
    int o = blockIdx.x * 256 + threadIdx.x;
    if (o < 64 * 1152) {
        int j = o & 7, o2 = o >> 3;
        int lane = o2 & 63, t = o2 >> 6;
        int l16 = lane & 15, quad = lane >> 4;
        int kt = t % 36, wv = t / 36;
        int co = wv * 16 + l16;
        int kk = kt * 32 + quad * 8 + j;
        int k = kk >> 7, ci = kk & 127;
        float v = (co < 32) ? oc1_w[co * 1152 + ci * 9 + k]
                            : mc1_w[(co - 32) * 1152 + ci * 9 + k];
        wCf[o] = __float2bfloat16(v);
    } else if (o < 64 * 1152 + 64) {
        int c = o - 64 * 1152;
        float g, bb, m, vv, bias;
        if (c < 32) { g = obn_g[c]; bb = obn_b[c]; m = obn_m[c]; vv = obn_v[c]; bias = oc1_b[c]; }
        else { int c2 = c - 32; g = mbn_g[c2]; bb = mbn_b[c2]; m = mbn_m[c2]; vv = mbn_v[c2]; bias = mc1_b[c2]; }
        float alpha = g / sqrtf(vv + 1e-5f);
        ab[c] = alpha;
        ab[64 + c] = (bias - m) * alpha + bb;
    }
}

// ------------------------------------------------- fuse + SA weights fragment-major + folded fuse BN
__global__ __launch_bounds__(256) void prep_fuse_kernel(
    const float* __restrict__ fu_w, const float* __restrict__ fu_b,
    const float* __restrict__ fbn_g, const float* __restrict__ fbn_b,
    const float* __restrict__ fbn_m, const float* __restrict__ fbn_v,
    const float* __restrict__ sa_w,
    bf16* __restrict__ wFf, bf16* __restrict__ wSAf, float* __restrict__ fab)
{
    int o = blockIdx.x * 256 + threadIdx.x;
    if (o < 98304) {
        int j = o & 7, o2 = o >> 3;
        int lane = o2 & 63, t = o2 >> 6;
        int l16 = lane & 15, quad = lane >> 4;
        int mt = t & 3, t2 = t >> 2;
        int kt = t2 % 12, wv = t2 / 12;
        int co = wv * 64 + mt * 16 + l16;
        int kk = kt * 32 + quad * 8 + j;
        wFf[o] = __float2bfloat16(fu_w[co * 384 + kk]);
    } else if (o < 98304 + 24576) {
        int idx = o - 98304;
        int j = idx & 7, o2 = idx >> 3;
        int lane = o2 & 63, t = o2 >> 6;
        int l16 = lane & 15, quad = lane >> 4;
        int kt = t % 12, wv = t / 12;
        int jr = wv * 16 + l16;
        int kk = kt * 32 + quad * 8 + j;
        wSAf[idx] = (jr < 49) ? __float2bfloat16(sa_w[kk * 49 + jr]) : __float2bfloat16(0.f);
    } else if (o < 98304 + 24576 + 256) {
        int co = o - 98304 - 24576;
        float alpha = fbn_g[co] / sqrtf(fbn_v[co] + 1e-5f);
        fab[co] = alpha;
        fab[256 + co] = (fu_b[co] - fbn_m[co]) * alpha + fbn_b[co];
    }
}

// ------------------------------------------------- misc prep: wDf (conv2), wPf (pw), dw folded BN
// wDf[((kt*2+mt)*64+lane)*8+j]: co=mt*16+l16, kk=kt*32+quad*8+j, kk = k*64 + c
__global__ __launch_bounds__(256) void prep_misc_kernel(
    const float* __restrict__ oc2_w, const float* __restrict__ mc2_w,
    const float* __restrict__ cb_pw_w,
    const float* __restrict__ cb_dw_b, const float* __restrict__ cbn_g,
    const float* __restrict__ cbn_b, const float* __restrict__ cbn_m,
    const float* __restrict__ cbn_v,
    bf16* __restrict__ wDf, bf16* __restrict__ wPf, float* __restrict__ dwab)
{
    int o = blockIdx.x * 256 + threadIdx.x;
    if (o < 18432) {
        int j = o & 7, o2 = o >> 3;
        int lane = o2 & 63, t = o2 >> 6;       // t in [0,36)
        int l16 = lane & 15, quad = lane >> 4;
        int mt = t & 1, kt = t >> 1;
        int co = mt * 16 + l16;
        int kk = kt * 32 + quad * 8 + j;
        int k = kk >> 6, c = kk & 63;
        float v = 0.f;
        if (co < 18 && c < 32) v = oc2_w[co * 288 + c * 9 + k];
        else if (co >= 18 && co < 27 && c >= 32) v = mc2_w[(co - 18) * 288 + (c - 32) * 9 + k];
        wDf[o] = __float2bfloat16(v);
    } else if (o < 18432 + 16384) {
        int idx = o - 18432;
        int j = idx & 7, o2 = idx >> 3;
        int lane = o2 & 63, t = o2 >> 6;       // t in [0,32)
        int l16 = lane & 15, quad = lane >> 4;
        int wv = t >> 3, kt = (t >> 1) & 3, mt = t & 1;
        int co = wv * 32 + mt * 16 + l16;
        int kk = kt * 32 + quad * 8 + j;
        wPf[idx] = __float2bfloat16(cb_pw_w[co * 128 + kk]);
    } else if (o < 18432 + 16384 + 128) {
        int c = o - 18432 - 16384;
        float alpha = cbn_g[c] / sqrtf(cbn_v[c] + 1e-5f);
        dwab[c] = alpha;
        dwab[128 + c] = (cb_dw_b[c] - cbn_m[c]) * alpha + cbn_b[c];
    }
}

// ---------------------------------------------------------------- conv1 (oc1+mc1) MFMA -> ht[b][pos][64]
__global__ __launch_bounds__(256) void conv1_mfma_kernel(
    const bf16* __restrict__ xt, const bf16* __restrict__ wCf, const float* __restrict__ ab,
    bf16* __restrict__ ht)
{
    __shared__ __align__(16) bf16 val[16][1160];

    const int bid = blockIdx.x;
    const int b = (bid & 7) >> 1;
    const int tile = ((bid >> 3) << 1) | (bid & 1);
    const int pos0 = tile * 16;
    const int y = tile >> 2, x0 = (tile & 3) * 16;
    const int tid = threadIdx.x;
    const int cig = tid & 15, pix = tid >> 4;
    const int ci0 = cig * 8;
    const int xxp = x0 + pix;

    const bf16* xtb = xt + (size_t)b * HWP * 128;
    #pragma unroll
    for (int k = 0; k < 9; k++) {
        int yy = y + k / 3 - 1, xx = xxp + k % 3 - 1;
        bool valid = (yy >= 0 && yy <= 63 && xx >= 0 && xx <= 63);
        uint4 c = {0, 0, 0, 0};
        if (valid) c = *(const uint4*)(xtb + (size_t)(yy * 64 + xx) * 128 + ci0);
        *(uint4*)&val[pix][k * 128 + ci0] = c;
    }
    __syncthreads();

    const int lane = tid & 63, wv = tid >> 6;
    const int quad = lane >> 4, l16 = lane & 15;
    f32x4 acc = {0, 0, 0, 0};
    const bf16* wl0 = wCf + (size_t)wv * 36 * 512 + lane * 8;
    const bf16* vbase = &val[l16][quad * 8];

    sh8 af = *(const sh8*)(wl0);
    sh8 bf = *(const sh8*)(vbase);
    sh8 afn, bfn;
    for (int kt = 0; kt < 36; kt++) {
        if (kt < 35) {
            afn = *(const sh8*)(wl0 + (kt + 1) * 512);
            bfn = *(const sh8*)(vbase + (kt + 1) * 32);
        }
        acc = __builtin_amdgcn_mfma_f32_16x16x32_bf16(af, bf, acc, 0, 0, 0);
        af = afn; bf = bfn;
    }

    // write ht pixel-major: co = wv*16 + quad*4 + r, pixel = pos0+l16
    float o0 = fmaxf(acc[0] * ab[wv * 16 + quad * 4 + 0] + ab[64 + wv * 16 + quad * 4 + 0], 0.f);
    float o1 = fmaxf(acc[1] * ab[wv * 16 + quad * 4 + 1] + ab[64 + wv * 16 + quad * 4 + 1], 0.f);
    float o2 = fmaxf(acc[2] * ab[wv * 16 + quad * 4 + 2] + ab[64 + wv * 16 + quad * 4 + 2], 0.f);
    float o3 = fmaxf(acc[3] * ab[wv * 16 + quad * 4 + 3] + ab[64 + wv * 16 + quad * 4 + 3], 0.f);
    uint2 pk;
    pk.x = (unsigned)f2bfbits(o0) | ((unsigned)f2bfbits(o1) << 16);
    pk.y = (unsigned)f2bfbits(o2) | ((unsigned)f2bfbits(o3) << 16);
    *(uint2*)(ht + ((size_t)b * HWP + pos0 + l16) * 64 + wv * 16 + quad * 4) = pk;
}

// ---------------------------------------------------------------- conv2 (oc2+mc2) MFMA im2col GEMM
// grid 512 (= B * 128 tiles of 32 px), block 256 = 4 waves (wave: ph=wv>>1 pixel-half, mt=wv&1).
__global__ __launch_bounds__(256) void conv2_mfma_kernel(
    const bf16* __restrict__ ht, const bf16* __restrict__ wDf,
    const float* __restrict__ oc2_b, const float* __restrict__ mc2_b,
    float* __restrict__ offsb, float* __restrict__ mskb)
{
    __shared__ __align__(16) bf16 val[32][584];   // [pix][k*64+c], pad 576->584

    const int bid = blockIdx.x;
    const int b = bid >> 7, tile = bid & 127;
    const int y = tile >> 1, x0 = (tile & 1) * 32;
    const int tid = threadIdx.x;

    {
        const int cig = tid & 7, pix = tid >> 3;   // 32 px x 8 ch-groups
        const int xxp = x0 + pix;
        const bf16* hb = ht + (size_t)b * HWP * 64;
        #pragma unroll
        for (int k = 0; k < 9; k++) {
            int yy = y + k / 3 - 1, xx = xxp + k % 3 - 1;
            bool valid = (yy >= 0 && yy <= 63 && xx >= 0 && xx <= 63);
            uint4 c = {0, 0, 0, 0};
            if (valid) c = *(const uint4*)(hb + (size_t)(yy * 64 + xx) * 64 + cig * 8);
            *(uint4*)&val[pix][k * 64 + cig * 8] = c;
        }
    }
    __syncthreads();

    const int lane = tid & 63, wv = tid >> 6;
    const int quad = lane >> 4, l16 = lane & 15;
    const int ph = wv >> 1, mt = wv & 1;
    f32x4 acc = {0, 0, 0, 0};
    const bf16* wl0 = wDf + ((size_t)mt * 64 + lane) * 8;     // frag kt at + kt*1024
    const bf16* vbase = &val[ph * 16 + l16][quad * 8];

    sh8 af = *(const sh8*)(wl0);
    sh8 bf = *(const sh8*)(vbase);
    sh8 afn, bfn;
    for (int kt = 0; kt < 18; kt++) {
        if (kt < 17) {
            afn = *(const sh8*)(wl0 + (kt + 1) * 1024);
            bfn = *(const sh8*)(vbase + (kt + 1) * 32);
        }
        acc = __builtin_amdgcn_mfma_f32_16x16x32_bf16(af, bf, acc, 0, 0, 0);
        af = afn; bf = bfn;
    }

    const int pos = y * 64 + x0 + ph * 16 + l16;
    #pragma unroll
    for (int r = 0; r < 4; r++) {
        int co = mt * 16 + quad * 4 + r;
        if (co < 18) {
            offsb[(size_t)(b * 18 + co) * HWP + pos] = acc[r] + oc2_b[co];
        } else if (co < 27) {
            float s = acc[r] + mc2_b[co - 18];
            mskb[(size_t)(b * 9 + (co - 18)) * HWP + pos] = 1.f / (1.f + expf(-s));
        }
    }
}

// ---------------------------------------------------------------- depthwise 3x3 (pixel-major) + folded BN + ReLU
// grid 1024 (16 px/block); thread = (pix, 8ch). -> htc[b][pos][128]
__global__ __launch_bounds__(256) void dwconv_px_kernel(
    const bf16* __restrict__ xt, const float* __restrict__ dw_w, const float* __restrict__ dwab,
    bf16* __restrict__ htc)
{
    __shared__ float wl[1152];
    __shared__ float abl[256];
    const int bid = blockIdx.x;
    const int b = bid >> 8, tile = bid & 255;
    const int y = tile >> 2, x0 = (tile & 3) * 16;
    const int tid = threadIdx.x;
    for (int i = tid; i < 1152; i += 256) wl[i] = dw_w[i];
    if (tid < 256) abl[tid] = dwab[tid];
    __syncthreads();

    const int cig = tid & 15, pix = tid >> 4;
    const int ci0 = cig * 8;
    const int xxp = x0 + pix;
    const bf16* xtb = xt + (size_t)b * HWP * 128;

    float g[8] = {0, 0, 0, 0, 0, 0, 0, 0};
    #pragma unroll
    for (int k = 0; k < 9; k++) {
        int yy = y + k / 3 - 1, xx = xxp + k % 3 - 1;
        if (yy < 0 || yy > 63 || xx < 0 || xx > 63) continue;
        uint4 c = *(const uint4*)(xtb + (size_t)(yy * 64 + xx) * 128 + ci0);
        #pragma unroll
        for (int j = 0; j < 8; j++)
            g[j] += wl[(ci0 + j) * 9 + k] * bfj(c, j);
    }
    float o[8];
    #pragma unroll
    for (int j = 0; j < 8; j++)
        o[j] = fmaxf(g[j] * abl[ci0 + j] + abl[128 + ci0 + j], 0.f);
    uint4 pk;
    pk.x = (unsigned)f2bfbits(o[0]) | ((unsigned)f2bfbits(o[1]) << 16);
    pk.y = (unsigned)f2bfbits(o[2]) | ((unsigned)f2bfbits(o[3]) << 16);
    pk.z = (unsigned)f2bfbits(o[4]) | ((unsigned)f2bfbits(o[5]) << 16);
    pk.w = (unsigned)f2bfbits(o[6]) | ((unsigned)f2bfbits(o[7]) << 16);
    *(uint4*)(htc + ((size_t)b * HWP + y * 64 + xxp) * 128 + ci0) = pk;
}

// ---------------------------------------------------------------- contour pw 1x1 MFMA (LDS-free) -> comb[..][256:]
// grid 1024 (16 px), block 256 = 4 waves (wave = 32 co).
__global__ __launch_bounds__(256) void pw_mfma_kernel(
    const bf16* __restrict__ htc, const bf16* __restrict__ wPf, const float* __restrict__ bias,
    bf16* __restrict__ combined)
{
    const int bid = blockIdx.x;
    const int b = bid >> 8, tile = bid & 255;
    const int pos0 = tile * 16;
    const int tid = threadIdx.x;
    const int lane = tid & 63, wv = tid >> 6;
    const int quad = lane >> 4, l16 = lane & 15;

    f32x4 acc[2] = {f32x4{0,0,0,0}, f32x4{0,0,0,0}};
    const bf16* fb = htc + ((size_t)b * HWP + pos0 + l16) * 128 + quad * 8;
    const bf16* wl0 = wPf + (size_t)wv * 4096 + lane * 8;    // frag(kt,mt) at + (kt*2+mt)*512
    for (int kt = 0; kt < 4; kt++) {
        sh8 bf = *(const sh8*)(fb + kt * 32);
        #pragma unroll
        for (int mt = 0; mt < 2; mt++) {
            sh8 af = *(const sh8*)(wl0 + (kt * 2 + mt) * 512);
            acc[mt] = __builtin_amdgcn_mfma_f32_16x16x32_bf16(af, bf, acc[mt], 0, 0, 0);
        }
    }

    bf16* ct = combined + ((size_t)b * HWP + pos0 + l16) * 384 + 256;
    #pragma unroll
    for (int mt = 0; mt < 2; mt++) {
        int co_b = wv * 32 + mt * 16 + quad * 4;
        uint2 pk;
        pk.x = (unsigned)f2bfbits(acc[mt][0] + bias[co_b])     | ((unsigned)f2bfbits(acc[mt][1] + bias[co_b + 1]) << 16);
        pk.y = (unsigned)f2bfbits(acc[mt][2] + bias[co_b + 2]) | ((unsigned)f2bfbits(acc[mt][3] + bias[co_b + 3]) << 16);
        *(uint2*)(ct + co_b) = pk;
    }
}

// ---------------------------------------------------------------- modulated deformable conv (MFMA)
__global__ __launch_bounds__(256) void deform_kernel(
    const bf16* __restrict__ xt, const float* __restrict__ offs, const float* __restrict__ msk,
    const bf16* __restrict__ wBf, const float* __restrict__ bias, bf16* __restrict__ combined)
{
    __shared__ __align__(16) bf16 val[16][1160];
    __shared__ int   ti[144][4];
    __shared__ float tw[144][4];

    const int bid = blockIdx.x;
    const int b = (bid & 7) >> 1;
    const int tile = ((bid >> 3) << 1) | (bid & 1);
    const int pos0 = tile * 16;
    const int tid = threadIdx.x;

    if (tid < 144) {                      // e = k*16 + pix
        int k = tid >> 4, pix = tid & 15;
        int pos = pos0 + pix;
        int y = pos >> 6, xc = pos & 63;
        float offy = offs[(size_t)(b * 18 + 2 * k) * HWP + pos];
        float offx = offs[(size_t)(b * 18 + 2 * k + 1) * HWP + pos];
        float m = msk[(size_t)(b * 9 + k) * HWP + pos];
        float py = (float)(y - 1 + k / 3) + offy;
        float px = (float)(xc - 1 + k % 3) + offx;
        float fy = floorf(py), fx = floorf(px);
        float wy1 = py - fy, wx1 = px - fx;
        int y0 = (int)fy, x0 = (int)fx;
        int y1 = y0 + 1, x1 = x0 + 1;
        bool vy0 = (y0 >= 0 && y0 <= 63), vy1 = (y1 >= 0 && y1 <= 63);
        bool vx0 = (x0 >= 0 && x0 <= 63), vx1 = (x1 >= 0 && x1 <= 63);
        int cy0 = min(max(y0, 0), 63), cy1 = min(max(y1, 0), 63);
        int cx0 = min(max(x0, 0), 63), cx1 = min(max(x1, 0), 63);
        ti[tid][0] = cy0 * 64 + cx0;  tw[tid][0] = (vy0 && vx0) ? (1.f - wy1) * (1.f - wx1) * m : 0.f;
        ti[tid][1] = cy0 * 64 + cx1;  tw[tid][1] = (vy0 && vx1) ? (1.f - wy1) * wx1 * m : 0.f;
        ti[tid][2] = cy1 * 64 + cx0;  tw[tid][2] = (vy1 && vx0) ? wy1 * (1.f - wx1) * m : 0.f;
        ti[tid][3] = cy1 * 64 + cx1;  tw[tid][3] = (vy1 && vx1) ? wy1 * wx1 * m : 0.f;
    }
    __syncthreads();

    {
        const int cig = tid & 15, pix = tid >> 4;
        const int ci0 = cig * 8;
        const bf16* xtb = xt + (size_t)b * HWP * 128;
        for (int k = 0; k < 9; k++) {
            const int e = k * 16 + pix;
            const int i0 = ti[e][0], i1 = ti[e][1], i2 = ti[e][2], i3 = ti[e][3];
            const float w0 = tw[e][0], w1 = tw[e][1], w2 = tw[e][2], w3 = tw[e][3];
            uint4 c0 = *(const uint4*)(xtb + (size_t)i0 * 128 + ci0);
            uint4 c1 = *(const uint4*)(xtb + (size_t)i1 * 128 + ci0);
            uint4 c2 = *(const uint4*)(xtb + (size_t)i2 * 128 + ci0);
            uint4 c3 = *(const uint4*)(xtb + (size_t)i3 * 128 + ci0);
            float g[8];
            #pragma unroll
            for (int j = 0; j < 8; j++)
                g[j] = w0 * bfj(c0, j) + w1 * bfj(c1, j) + w2 * bfj(c2, j) + w3 * bfj(c3, j);
            uint4 pk;
            pk.x = (unsigned)f2bfbits(g[0]) | ((unsigned)f2bfbits(g[1]) << 16);
            pk.y = (unsigned)f2bfbits(g[2]) | ((unsigned)f2bfbits(g[3]) << 16);
            pk.z = (unsigned)f2bfbits(g[4]) | ((unsigned)f2bfbits(g[5]) << 16);
            pk.w = (unsigned)f2bfbits(g[6]) | ((unsigned)f2bfbits(g[7]) << 16);
            *(uint4*)&val[pix][k * 128 + ci0] = pk;
        }
    }
    __syncthreads();

    const int lane = tid & 63, wv = tid >> 6;
    const int quad = lane >> 4, l16 = lane & 15;
    f32x4 acc[4] = {f32x4{0,0,0,0}, f32x4{0,0,0,0}, f32x4{0,0,0,0}, f32x4{0,0,0,0}};

    const bf16* wl0 = wBf + (size_t)wv * 73728 + lane * 8;
    const bf16* vbase = &val[l16][quad * 8];

    sh8 af[4], afn[4], bf, bfn;
    bf = *(const sh8*)(vbase);
    #pragma unroll
    for (int mt = 0; mt < 4; mt++) af[mt] = *(const sh8*)(wl0 + mt * 512);
    for (int kt = 0; kt < 36; kt++) {
        if (kt < 35) {
            bfn = *(const sh8*)(vbase + (kt + 1) * 32);
            #pragma unroll
            for (int mt = 0; mt < 4; mt++)
                afn[mt] = *(const sh8*)(wl0 + ((kt + 1) * 4 + mt) * 512);
        }
        #pragma unroll
        for (int mt = 0; mt < 4; mt++)
            acc[mt] = __builtin_amdgcn_mfma_f32_16x16x32_bf16(af[mt], bf, acc[mt], 0, 0, 0);
        bf = bfn;
        #pragma unroll
        for (int mt = 0; mt < 4; mt++) af[mt] = afn[mt];
    }

    bf16* ct = combined + ((size_t)b * HWP + pos0 + l16) * 384;
    #pragma unroll
    for (int mt = 0; mt < 4; mt++) {
        int co_b = wv * 64 + mt * 16 + quad * 4;
        uint2 pk;
        pk.x = (unsigned)f2bfbits(acc[mt][0] + bias[co_b])     | ((unsigned)f2bfbits(acc[mt][1] + bias[co_b + 1]) << 16);
        pk.y = (unsigned)f2bfbits(acc[mt][2] + bias[co_b + 2]) | ((unsigned)f2bfbits(acc[mt][3] + bias[co_b + 3]) << 16);
        *(uint2*)(ct + co_b) = pk;
    }
}

// ---------------------------------------------------------------- SA GEMM (MFMA, LDS-free, prefetched)
__global__ __launch_bounds__(256) void sa_gemm_kernel(
    const bf16* __restrict__ combined, const bf16* __restrict__ wSAf, float* __restrict__ part)
{
    const int bid = blockIdx.x;
    const int b = bid >> 8, tile = bid & 255;
    const int pos0 = tile * 16;
    const int tid = threadIdx.x;
    const int lane = tid & 63, wv = tid >> 6;
    const int quad = lane >> 4, l16 = lane & 15;

    f32x4 acc = {0, 0, 0, 0};
    const bf16* fb = combined + ((size_t)b * HWP + pos0 + l16) * 384 + quad * 8;
    const bf16* wl0 = wSAf + (size_t)wv * 6144 + lane * 8;

    sh8 af = *(const sh8*)(wl0);
    sh8 bf = *(const sh8*)(fb);
    sh8 afn, bfn;
    for (int kt = 0; kt < 12; kt++) {
        if (kt < 11) {
            afn = *(const sh8*)(wl0 + (kt + 1) * 512);
            bfn = *(const sh8*)(fb + (kt + 1) * 32);
        }
        acc = __builtin_amdgcn_mfma_f32_16x16x32_bf16(af, bf, acc, 0, 0, 0);
        af = afn; bf = bfn;
    }
    #pragma unroll
    for (int r = 0; r < 4; r++) {
        int j = wv * 16 + quad * 4 + r;
        if (j < 49) part[(size_t)(j * BN + b) * HWP + pos0 + l16] = acc[r];
    }
}

// ---------------------------------------------------------------- attn finalize: 49-tap shifted sum
__global__ __launch_bounds__(256) void attn_fin_kernel(
    const float* __restrict__ part, const float* __restrict__ sa_b, float* __restrict__ attn)
{
    int i = blockIdx.x * 256 + threadIdx.x;
    if (i >= BN * HWP) return;
    int b = i >> 12, pos = i & 4095;
    int y = pos >> 6, x = pos & 63;
    float s = sa_b[0];
    #pragma unroll
    for (int j = 0; j < 49; j++) {
        int yy = y + j / 7 - 3, xx = x + j % 7 - 3;
        if (yy < 0 || yy > 63 || xx < 0 || xx > 63) continue;
        s += part[(size_t)(j * BN + b) * HWP + yy * 64 + xx];
    }
    attn[i] = 1.f / (1.f + expf(-s));
}

// ---------------------------------------------------------------- fusion 1x1 MFMA (prefetched)
__global__ __launch_bounds__(256) void fuse_kernel(
    const bf16* __restrict__ combined, const float* __restrict__ attn,
    const bf16* __restrict__ wFf, const float* __restrict__ fab, float* __restrict__ out)
{
    const int bid = blockIdx.x;
    const int b = bid >> 8, tile = bid & 255;
    const int pos0 = tile * 16;
    const int tid = threadIdx.x;
    const int lane = tid & 63, wv = tid >> 6;
    const int quad = lane >> 4, l16 = lane & 15;

    f32x4 acc[4] = {f32x4{0,0,0,0}, f32x4{0,0,0,0}, f32x4{0,0,0,0}, f32x4{0,0,0,0}};
    const bf16* fb = combined + ((size_t)b * HWP + pos0 + l16) * 384 + quad * 8;
    const bf16* wl0 = wFf + (size_t)wv * 24576 + lane * 8;

    sh8 af[4], afn[4], bf, bfn;
    bf = *(const sh8*)(fb);
    #pragma unroll
    for (int mt = 0; mt < 4; mt++) af[mt] = *(const sh8*)(wl0 + mt * 512);
    for (int kt = 0; kt < 12; kt++) {
        if (kt < 11) {
            bfn = *(const sh8*)(fb + (kt + 1) * 32);
            #pragma unroll
            for (int mt = 0; mt < 4; mt++)
                afn[mt] = *(const sh8*)(wl0 + ((kt + 1) * 4 + mt) * 512);
        }
        #pragma unroll
        for (int mt = 0; mt < 4; mt++)
            acc[mt] = __builtin_amdgcn_mfma_f32_16x16x32_bf16(af[mt], bf, acc[mt], 0, 0, 0);
        bf = bfn;
        #pragma unroll
        for (int mt = 0; mt < 4; mt++) af[mt] = afn[mt];
    }

    float a = attn[(size_t)b * HWP + pos0 + l16];
    float* op = out + (size_t)b * COUT * HWP + pos0 + l16;
    #pragma unroll
    for (int mt = 0; mt < 4; mt++) {
        int co_b = wv * 64 + mt * 16 + quad * 4;
        #pragma unroll
        for (int r = 0; r < 4; r++) {
            int co = co_b + r;
            float o = fmaxf(acc[mt][r] * a * fab[co] + fab[256 + co], 0.f);
            op[(size_t)co * HWP] = o;
        }
    }
}

// ================================================================ launch
extern "C" void kernel_launch(void* const* d_in, const int* in_sizes, int n_in,
                              void* d_out, int out_size, void* d_ws, size_t ws_size,
                              hipStream_t stream)
{
    const float* x      = (const float*)d_in[0];
    const float* oc1_w  = (const float*)d_in[1];
    const float* oc1_b  = (const float*)d_in[2];
    const float* obn_g  = (const float*)d_in[3];
    const float* obn_b  = (const float*)d_in[4];
    const float* obn_m  = (const float*)d_in[5];
    const float* obn_v  = (const float*)d_in[6];
    const float* oc2_w  = (const float*)d_in[7];
    const float* oc2_b  = (const float*)d_in[8];
    const float* mc1_w  = (const float*)d_in[9];
    const float* mc1_b  = (const float*)d_in[10];
    const float* mbn_g  = (const float*)d_in[11];
    const float* mbn_b  = (const float*)d_in[12];
    const float* mbn_m  = (const float*)d_in[13];
    const float* mbn_v  = (const float*)d_in[14];
    const float* mc2_w  = (const float*)d_in[15];
    const float* mc2_b  = (const float*)d_in[16];
    const float* dc_w   = (const float*)d_in[17];
    const float* dc_b   = (const float*)d_in[18];
    const float* cb_dw_w= (const float*)d_in[19];
    const float* cb_dw_b= (const float*)d_in[20];
    const float* cbn_g  = (const float*)d_in[21];
    const float* cbn_b  = (const float*)d_in[22];
    const float* cbn_m  = (const float*)d_in[23];
    const float* cbn_v  = (const float*)d_in[24];
    const float* cb_pw_w= (const float*)d_in[25];
    const float* cb_pw_b= (const float*)d_in[26];
    const float* sa_w   = (const float*)d_in[27];
    const float* sa_b   = (const float*)d_in[28];
    const float* fu_w   = (const float*)d_in[29];
    const float* fu_b   = (const float*)d_in[30];
    const float* fbn_g  = (const float*)d_in[31];
    const float* fbn_b  = (const float*)d_in[32];
    const float* fbn_m  = (const float*)d_in[33];
    const float* fbn_v  = (const float*)d_in[34];

    // workspace layout (~29.2 MB)
    bf16*  ht    = (bf16*)d_ws;                // 1,048,576 bf16 (conv1 out, pixel-major [b][pos][64])
    bf16*  htc   = ht + 1048576;               // 2,097,152 bf16 (dw out, pixel-major [b][pos][128])
    float* offsb = (float*)(htc + 2097152);    //   294,912 f32
    float* mskb  = offsb + 294912;             //   147,456 f32
    bf16*  comb  = (bf16*)(mskb + 147456);     // 6,291,456 bf16 (combined_t [b][pos][384])
    float* part  = (float*)(comb + 6291456);   //   802,816 f32
    float* attn  = part + 802816;              //    16,384 f32
    bf16*  xt    = (bf16*)(attn + 16384);      // 2,097,152 bf16
    bf16*  wBf   = xt + 2097152;               //   294,912 bf16
    bf16*  wCf   = wBf + 294912;               //    73,728 bf16
    float* ab    = (float*)(wCf + 73728);      //       128 f32
    bf16*  wFf   = (bf16*)(ab + 128);          //    98,304 bf16
    bf16*  wSAf  = wFf + 98304;                //    24,576 bf16
    float* fab   = (float*)(wSAf + 24576);     //       512 f32
    bf16*  wDf   = (bf16*)(fab + 512);         //    18,432 bf16
    bf16*  wPf   = wDf + 18432;                //    16,384 bf16
    float* dwab  = (float*)(wPf + 16384);      //       256 f32

    float* out = (float*)d_out;

    // 0. transpose x -> pixel-major bf16
    transpose_x_kernel<<<256, 256, 0, stream>>>(x, xt);
    // 1. weight preps (fragment-major layouts)
    prep_wBf_kernel<<<1152, 256, 0, stream>>>(dc_w, wBf);
    prep_conv1_kernel<<<289, 256, 0, stream>>>(oc1_w, oc1_b, obn_g, obn_b, obn_m, obn_v,
                                               mc1_w, mc1_b, mbn_g, mbn_b, mbn_m, mbn_v, wCf, ab);
    prep_fuse_kernel<<<482, 256, 0, stream>>>(fu_w, fu_b, fbn_g, fbn_b, fbn_m, fbn_v, sa_w,
                                              wFf, wSAf, fab);
    prep_misc_kernel<<<137, 256, 0, stream>>>(oc2_w, mc2_w, cb_pw_w,
                                              cb_dw_b, cbn_g, cbn_b, cbn_m, cbn_v,
                                              wDf, wPf, dwab);
    // 2. oc1 + mc1 fused MFMA conv -> ht pixel-major
    conv1_mfma_kernel<<<1024, 256, 0, stream>>>(xt, wCf, ab, ht);
    // 3. oc2 + mc2 fused MFMA conv -> offsets + sigmoid masks
    conv2_mfma_kernel<<<512, 256, 0, stream>>>(ht, wDf, oc2_b, mc2_b, offsb, mskb);
    // 4. contour depthwise (pixel-major, folded BN+ReLU) -> htc
    dwconv_px_kernel<<<1024, 256, 0, stream>>>(xt, cb_dw_w, dwab, htc);
    // 5. contour pointwise MFMA -> combined_t[:, 256:384]
    pw_mfma_kernel<<<1024, 256, 0, stream>>>(htc, wPf, cb_pw_b, comb);
    // 6. modulated deformable conv (MFMA) -> combined_t[:, 0:256]
    deform_kernel<<<1024, 256, 0, stream>>>(xt, offsb, mskb, wBf, dc_b, comb);
    // 7. SA GEMM (MFMA, LDS-free)
    sa_gemm_kernel<<<1024, 256, 0, stream>>>(comb, wSAf, part);
    // 8. attn finalize
    attn_fin_kernel<<<64, 256, 0, stream>>>(part, sa_b, attn);
    // 9. fusion 1x1 MFMA (+attn scale, folded BN, ReLU) -> fp32 out
    fuse_kernel<<<1024, 256, 0, stream>>>(comb, attn, wFf, fab, out);
}

// Round 10
// 212.870 us; speedup vs baseline: 6.8645x; 1.1161x over previous
//
#include <hip/hip_runtime.h>
#include <hip/hip_bf16.h>
#include <math.h>

// Problem constants
#define BN   4
#define CIN  128
#define COUT 256
#define HWP  4096      // 64*64

typedef __hip_bfloat16 bf16;
typedef __attribute__((ext_vector_type(8))) short sh8;    // 8 bf16 = 4 VGPR
typedef __attribute__((ext_vector_type(4))) float f32x4;  // MFMA accumulator

__device__ __forceinline__ float b2f(bf16 v) { return __bfloat162float(v); }
__device__ __forceinline__ float bflo(unsigned u) { return __uint_as_float(u << 16); }
__device__ __forceinline__ float bfhi(unsigned u) { return __uint_as_float(u & 0xffff0000u); }
__device__ __forceinline__ unsigned short f2bfbits(float f) {
    union { bf16 h; unsigned short u; } cv; cv.h = __float2bfloat16(f); return cv.u;
}
__device__ __forceinline__ float bfj(const uint4& c, int j) {
    unsigned u = (&c.x)[j >> 1];
    return (j & 1) ? bfhi(u) : bflo(u);
}

// ---------------------------------------------------------------- x [b][ci][pos] f32 -> xt [b][pos][ci] bf16
__global__ __launch_bounds__(256) void transpose_x_kernel(const float* __restrict__ x,
                                                          bf16* __restrict__ xt)
{
    __shared__ bf16 t[64][136];
    const int b = blockIdx.x >> 6, chunk = blockIdx.x & 63;
    const int pos0 = chunk * 64;
    const int tid = threadIdx.x;
    const int lane = tid & 63, wv = tid >> 6;
    const float* xb = x + (size_t)b * CIN * HWP + pos0 + lane;
    #pragma unroll 4
    for (int j = 0; j < 32; j++) {
        int ci = wv * 32 + j;
        t[lane][ci] = __float2bfloat16(xb[(size_t)ci * HWP]);
    }
    __syncthreads();
    const int p = tid >> 2, cig = tid & 3;
    uint4* dst = (uint4*)(xt + ((size_t)b * HWP + pos0 + p) * 128 + cig * 32);
    const uint4* src = (const uint4*)&t[p][cig * 32];
    #pragma unroll
    for (int q = 0; q < 4; q++) dst[q] = src[q];
}

// ---------------------------------------------------------------- all weight preps in one kernel
// seg0: wBf2 [0, 294912)           deform weights, 32px/K-split frag-major
// seg1: wCf  [294912, 368640), ab [368640, 368704)
// seg2: wFf  [368704, 467008), wSAf [467008, 491584), fab [491584, 491840)
// seg3: wDf  [491840, 510272), wPf [510272, 526656), dwab [526656, 526784)
__global__ __launch_bounds__(256) void prep_all_kernel(
    const float* __restrict__ dc_w,
    const float* __restrict__ oc1_w, const float* __restrict__ oc1_b,
    const float* __restrict__ obn_g, const float* __restrict__ obn_b,
    const float* __restrict__ obn_m, const float* __restrict__ obn_v,
    const float* __restrict__ mc1_w, const float* __restrict__ mc1_b,
    const float* __restrict__ mbn_g, const float* __restrict__ mbn_b,
    const float* __restrict__ mbn_m, const float* __restrict__ mbn_v,
    const float* __restrict__ fu_w, const float* __restrict__ fu_b,
    const float* __restrict__ fbn_g, const float* __restrict__ fbn_b,
    const float* __restrict__ fbn_m, const float* __restrict__ fbn_v,
    const float* __restrict__ sa_w,
    const float* __restrict__ oc2_w, const float* __restrict__ mc2_w,
    const float* __restrict__ cb_pw_w,
    const float* __restrict__ cb_dw_b, const float* __restrict__ cbn_g,
    const float* __restrict__ cbn_b, const float* __restrict__ cbn_m,
    const float* __restrict__ cbn_v,
    bf16* __restrict__ wBf2, bf16* __restrict__ wCf, float* __restrict__ ab,
    bf16* __restrict__ wFf, bf16* __restrict__ wSAf, float* __restrict__ fab,
    bf16* __restrict__ wDf, bf16* __restrict__ wPf, float* __restrict__ dwab)
{
    int o = blockIdx.x * 256 + threadIdx.x;
    if (o < 294912) {
        // wBf2[(((wv*2+h)*18+kt)*4+mt)*64+lane][8j]; co=wv*64+mt*16+l16; kkh=kt*32+quad*8+j
        int j = o & 7, o2 = o >> 3;
        int lane = o2 & 63, t = o2 >> 6;
        int l16 = lane & 15, quad = lane >> 4;
        int mt = t & 3, t2 = t >> 2;
        int kt = t2 % 18, t3 = t2 / 18;
        int h = t3 & 1, wv = t3 >> 1;
        int co = wv * 64 + mt * 16 + l16;
        int kkh = kt * 32 + quad * 8 + j;
        int k = kkh >> 6, ci = h * 64 + (kkh & 63);
        wBf2[o] = __float2bfloat16(dc_w[co * 1152 + ci * 9 + k]);
    } else if (o < 368640) {
        int idx = o - 294912;
        int j = idx & 7, o2 = idx >> 3;
        int lane = o2 & 63, t = o2 >> 6;
        int l16 = lane & 15, quad = lane >> 4;
        int kt = t % 36, wv = t / 36;
        int co = wv * 16 + l16;
        int kk = kt * 32 + quad * 8 + j;
        int k = kk >> 7, ci = kk & 127;
        float v = (co < 32) ? oc1_w[co * 1152 + ci * 9 + k]
                            : mc1_w[(co - 32) * 1152 + ci * 9 + k];
        wCf[idx] = __float2bfloat16(v);
    } else if (o < 368704) {
        int c = o - 368640;
        float g, bb, m, vv, bias;
        if (c < 32) { g = obn_g[c]; bb = obn_b[c]; m = obn_m[c]; vv = obn_v[c]; bias = oc1_b[c]; }
        else { int c2 = c - 32; g = mbn_g[c2]; bb = mbn_b[c2]; m = mbn_m[c2]; vv = mbn_v[c2]; bias = mc1_b[c2]; }
        float alpha = g / sqrtf(vv + 1e-5f);
        ab[c] = alpha;
        ab[64 + c] = (bias - m) * alpha + bb;
    } else if (o < 467008) {
        int idx = o - 368704;
        int j = idx & 7, o2 = idx >> 3;
        int lane = o2 & 63, t = o2 >> 6;
        int l16 = lane & 15, quad = lane >> 4;
        int mt = t & 3, t2 = t >> 2;
        int kt = t2 % 12, wv = t2 / 12;
        int co = wv * 64 + mt * 16 + l16;
        int kk = kt * 32 + quad * 8 + j;
        wFf[idx] = __float2bfloat16(fu_w[co * 384 + kk]);
    } else if (o < 491584) {
        int idx = o - 467008;
        int j = idx & 7, o2 = idx >> 3;
        int lane = o2 & 63, t = o2 >> 6;
        int l16 = lane & 15, quad = lane >> 4;
        int kt = t % 12, wv = t / 12;
        int jr = wv * 16 + l16;
        int kk = kt * 32 + quad * 8 + j;
        wSAf[idx] = (jr < 49) ? __float2bfloat16(sa_w[kk * 49 + jr]) : __float2bfloat16(0.f);
    } else if (o < 491840) {
        int co = o - 491584;
        float alpha = fbn_g[co] / sqrtf(fbn_v[co] + 1e-5f);
        fab[co] = alpha;
        fab[256 + co] = (fu_b[co] - fbn_m[co]) * alpha + fbn_b[co];
    } else if (o < 510272) {
        int idx = o - 491840;
        int j = idx & 7, o2 = idx >> 3;
        int lane = o2 & 63, t = o2 >> 6;       // t in [0,36)
        int l16 = lane & 15, quad = lane >> 4;
        int mt = t & 1, kt = t >> 1;
        int co = mt * 16 + l16;
        int kk = kt * 32 + quad * 8 + j;
        int k = kk >> 6, c = kk & 63;
        float v = 0.f;
        if (co < 18 && c < 32) v = oc2_w[co * 288 + c * 9 + k];
        else if (co >= 18 && co < 27 && c >= 32) v = mc2_w[(co - 18) * 288 + (c - 32) * 9 + k];
        wDf[idx] = __float2bfloat16(v);
    } else if (o < 526656) {
        int idx = o - 510272;
        int j = idx & 7, o2 = idx >> 3;
        int lane = o2 & 63, t = o2 >> 6;       // t in [0,32)
        int l16 = lane & 15, quad = lane >> 4;
        int wv = t >> 3, kt = (t >> 1) & 3, mt = t & 1;
        int co = wv * 32 + mt * 16 + l16;
        int kk = kt * 32 + quad * 8 + j;
        wPf[idx] = __float2bfloat16(cb_pw_w[co * 128 + kk]);
    } else if (o < 526784) {
        int c = o - 526656;
        float alpha = cbn_g[c] / sqrtf(cbn_v[c] + 1e-5f);
        dwab[c] = alpha;
        dwab[128 + c] = (cb_dw_b[c] - cbn_m[c]) * alpha + cbn_b[c];
    }
}

// ---------------------------------------------------------------- conv1 (oc1+mc1) MFMA -> ht[b][pos][64]
__global__ __launch_bounds__(256) void conv1_mfma_kernel(
    const bf16* __restrict__ xt, const bf16* __restrict__ wCf, const float* __restrict__ ab,
    bf16* __restrict__ ht)
{
    __shared__ __align__(16) bf16 val[16][1160];

    const int bid = blockIdx.x;
    const int b = (bid & 7) >> 1;
    const int tile = ((bid >> 3) << 1) | (bid & 1);
    const int pos0 = tile * 16;
    const int y = tile >> 2, x0 = (tile & 3) * 16;
    const int tid = threadIdx.x;
    const int cig = tid & 15, pix = tid >> 4;
    const int ci0 = cig * 8;
    const int xxp = x0 + pix;

    const bf16* xtb = xt + (size_t)b * HWP * 128;
    #pragma unroll
    for (int k = 0; k < 9; k++) {
        int yy = y + k / 3 - 1, xx = xxp + k % 3 - 1;
        bool valid = (yy >= 0 && yy <= 63 && xx >= 0 && xx <= 63);
        uint4 c = {0, 0, 0, 0};
        if (valid) c = *(const uint4*)(xtb + (size_t)(yy * 64 + xx) * 128 + ci0);
        *(uint4*)&val[pix][k * 128 + ci0] = c;
    }
    __syncthreads();

    const int lane = tid & 63, wv = tid >> 6;
    const int quad = lane >> 4, l16 = lane & 15;
    f32x4 acc = {0, 0, 0, 0};
    const bf16* wl0 = wCf + (size_t)wv * 36 * 512 + lane * 8;
    const bf16* vbase = &val[l16][quad * 8];

    sh8 af = *(const sh8*)(wl0);
    sh8 bf = *(const sh8*)(vbase);
    sh8 afn, bfn;
    for (int kt = 0; kt < 36; kt++) {
        if (kt < 35) {
            afn = *(const sh8*)(wl0 + (kt + 1) * 512);
            bfn = *(const sh8*)(vbase + (kt + 1) * 32);
        }
        acc = __builtin_amdgcn_mfma_f32_16x16x32_bf16(af, bf, acc, 0, 0, 0);
        af = afn; bf = bfn;
    }

    float o0 = fmaxf(acc[0] * ab[wv * 16 + quad * 4 + 0] + ab[64 + wv * 16 + quad * 4 + 0], 0.f);
    float o1 = fmaxf(acc[1] * ab[wv * 16 + quad * 4 + 1] + ab[64 + wv * 16 + quad * 4 + 1], 0.f);
    float o2 = fmaxf(acc[2] * ab[wv * 16 + quad * 4 + 2] + ab[64 + wv * 16 + quad * 4 + 2], 0.f);
    float o3 = fmaxf(acc[3] * ab[wv * 16 + quad * 4 + 3] + ab[64 + wv * 16 + quad * 4 + 3], 0.f);
    uint2 pk;
    pk.x = (unsigned)f2bfbits(o0) | ((unsigned)f2bfbits(o1) << 16);
    pk.y = (unsigned)f2bfbits(o2) | ((unsigned)f2bfbits(o3) << 16);
    *(uint2*)(ht + ((size_t)b * HWP + pos0 + l16) * 64 + wv * 16 + quad * 4) = pk;
}

// ---------------------------------------------------------------- conv2 (oc2+mc2) MFMA im2col GEMM
__global__ __launch_bounds__(256) void conv2_mfma_kernel(
    const bf16* __restrict__ ht, const bf16* __restrict__ wDf,
    const float* __restrict__ oc2_b, const float* __restrict__ mc2_b,
    float* __restrict__ offsb, float* __restrict__ mskb)
{
    __shared__ __align__(16) bf16 val[32][584];   // [pix][k*64+c], pad 576->584

    const int bid = blockIdx.x;
    const int b = bid >> 7, tile = bid & 127;
    const int y = tile >> 1, x0 = (tile & 1) * 32;
    const int tid = threadIdx.x;

    {
        const int cig = tid & 7, pix = tid >> 3;
        const int xxp = x0 + pix;
        const bf16* hb = ht + (size_t)b * HWP * 64;
        #pragma unroll
        for (int k = 0; k < 9; k++) {
            int yy = y + k / 3 - 1, xx = xxp + k % 3 - 1;
            bool valid = (yy >= 0 && yy <= 63 && xx >= 0 && xx <= 63);
            uint4 c = {0, 0, 0, 0};
            if (valid) c = *(const uint4*)(hb + (size_t)(yy * 64 + xx) * 64 + cig * 8);
            *(uint4*)&val[pix][k * 64 + cig * 8] = c;
        }
    }
    __syncthreads();

    const int lane = tid & 63, wv = tid >> 6;
    const int quad = lane >> 4, l16 = lane & 15;
    const int ph = wv >> 1, mt = wv & 1;
    f32x4 acc = {0, 0, 0, 0};
    const bf16* wl0 = wDf + ((size_t)mt * 64 + lane) * 8;
    const bf16* vbase = &val[ph * 16 + l16][quad * 8];

    sh8 af = *(const sh8*)(wl0);
    sh8 bf = *(const sh8*)(vbase);
    sh8 afn, bfn;
    for (int kt = 0; kt < 18; kt++) {
        if (kt < 17) {
            afn = *(const sh8*)(wl0 + (kt + 1) * 1024);
            bfn = *(const sh8*)(vbase + (kt + 1) * 32);
        }
        acc = __builtin_amdgcn_mfma_f32_16x16x32_bf16(af, bf, acc, 0, 0, 0);
        af = afn; bf = bfn;
    }

    const int pos = y * 64 + x0 + ph * 16 + l16;
    #pragma unroll
    for (int r = 0; r < 4; r++) {
        int co = mt * 16 + quad * 4 + r;
        if (co < 18) {
            offsb[(size_t)(b * 18 + co) * HWP + pos] = acc[r] + oc2_b[co];
        } else if (co < 27) {
            float s = acc[r] + mc2_b[co - 18];
            mskb[(size_t)(b * 9 + (co - 18)) * HWP + pos] = 1.f / (1.f + expf(-s));
        }
    }
}

// ---------------------------------------------------------------- fused depthwise + pointwise -> comb[..][256:384]
// grid 1024 (16 px/block). Phase1: dw in registers -> LDS; Phase2: pw MFMA from LDS.
__global__ __launch_bounds__(256) void dwpw_kernel(
    const bf16* __restrict__ xt, const float* __restrict__ dw_w, const float* __restrict__ dwab,
    const bf16* __restrict__ wPf, const float* __restrict__ pw_b, bf16* __restrict__ combined)
{
    __shared__ float wl[1152];
    __shared__ float abl[256];
    __shared__ __align__(16) bf16 vdw[16][136];   // [pix][128], pad 136
    const int bid = blockIdx.x;
    const int b = bid >> 8, tile = bid & 255;
    const int pos0 = tile * 16;
    const int y = tile >> 2, x0 = (tile & 3) * 16;
    const int tid = threadIdx.x;
    for (int i = tid; i < 1152; i += 256) wl[i] = dw_w[i];
    abl[tid] = dwab[tid];
    __syncthreads();

    {
        const int cig = tid & 15, pix = tid >> 4;
        const int ci0 = cig * 8;
        const int xxp = x0 + pix;
        const bf16* xtb = xt + (size_t)b * HWP * 128;
        float g[8] = {0, 0, 0, 0, 0, 0, 0, 0};
        #pragma unroll
        for (int k = 0; k < 9; k++) {
            int yy = y + k / 3 - 1, xx = xxp + k % 3 - 1;
            if (yy < 0 || yy > 63 || xx < 0 || xx > 63) continue;
            uint4 c = *(const uint4*)(xtb + (size_t)(yy * 64 + xx) * 128 + ci0);
            #pragma unroll
            for (int j = 0; j < 8; j++)
                g[j] += wl[(ci0 + j) * 9 + k] * bfj(c, j);
        }
        uint4 pk;
        float o[8];
        #pragma unroll
        for (int j = 0; j < 8; j++)
            o[j] = fmaxf(g[j] * abl[ci0 + j] + abl[128 + ci0 + j], 0.f);
        pk.x = (unsigned)f2bfbits(o[0]) | ((unsigned)f2bfbits(o[1]) << 16);
        pk.y = (unsigned)f2bfbits(o[2]) | ((unsigned)f2bfbits(o[3]) << 16);
        pk.z = (unsigned)f2bfbits(o[4]) | ((unsigned)f2bfbits(o[5]) << 16);
        pk.w = (unsigned)f2bfbits(o[6]) | ((unsigned)f2bfbits(o[7]) << 16);
        *(uint4*)&vdw[pix][ci0] = pk;
    }
    __syncthreads();

    const int lane = tid & 63, wv = tid >> 6;
    const int quad = lane >> 4, l16 = lane & 15;
    f32x4 acc[2] = {f32x4{0,0,0,0}, f32x4{0,0,0,0}};
    const bf16* fb = &vdw[l16][quad * 8];
    const bf16* wl0 = wPf + (size_t)wv * 4096 + lane * 8;
    #pragma unroll
    for (int kt = 0; kt < 4; kt++) {
        sh8 bf = *(const sh8*)(fb + kt * 32);
        #pragma unroll
        for (int mt = 0; mt < 2; mt++) {
            sh8 af = *(const sh8*)(wl0 + (kt * 2 + mt) * 512);
            acc[mt] = __builtin_amdgcn_mfma_f32_16x16x32_bf16(af, bf, acc[mt], 0, 0, 0);
        }
    }

    bf16* ct = combined + ((size_t)b * HWP + pos0 + l16) * 384 + 256;
    #pragma unroll
    for (int mt = 0; mt < 2; mt++) {
        int co_b = wv * 32 + mt * 16 + quad * 4;
        uint2 pk;
        pk.x = (unsigned)f2bfbits(acc[mt][0] + pw_b[co_b])     | ((unsigned)f2bfbits(acc[mt][1] + pw_b[co_b + 1]) << 16);
        pk.y = (unsigned)f2bfbits(acc[mt][2] + pw_b[co_b + 2]) | ((unsigned)f2bfbits(acc[mt][3] + pw_b[co_b + 3]) << 16);
        *(uint2*)(ct + co_b) = pk;
    }
}

// ---------------------------------------------------------------- modulated deformable conv (MFMA, 32px, K-split)
// grid 512, block 256 = 4 waves. LDS ~46 KB.
__global__ __launch_bounds__(256) void deform_kernel(
    const bf16* __restrict__ xt, const float* __restrict__ offs, const float* __restrict__ msk,
    const bf16* __restrict__ wBf2, const float* __restrict__ bias, bf16* __restrict__ combined)
{
    __shared__ __align__(16) bf16 val[32][584];    // [pix][K-half 576], pad 584
    __shared__ int   ti[288][4];
    __shared__ float tw[288][4];

    const int bid = blockIdx.x;
    const int b = (bid & 7) >> 1;                  // XCD-affinity
    const int tile = ((bid >> 3) << 1) | (bid & 1);  // [0,128)
    const int pos0 = tile * 32;
    const int tid = threadIdx.x;

    for (int e = tid; e < 288; e += 256) {         // e = k*32 + pix
        int k = e >> 5, pix = e & 31;
        int pos = pos0 + pix;
        int y = pos >> 6, xc = pos & 63;
        float offy = offs[(size_t)(b * 18 + 2 * k) * HWP + pos];
        float offx = offs[(size_t)(b * 18 + 2 * k + 1) * HWP + pos];
        float m = msk[(size_t)(b * 9 + k) * HWP + pos];
        float py = (float)(y - 1 + k / 3) + offy;
        float px = (float)(xc - 1 + k % 3) + offx;
        float fy = floorf(py), fx = floorf(px);
        float wy1 = py - fy, wx1 = px - fx;
        int y0 = (int)fy, x0 = (int)fx;
        int y1 = y0 + 1, x1 = x0 + 1;
        bool vy0 = (y0 >= 0 && y0 <= 63), vy1 = (y1 >= 0 && y1 <= 63);
        bool vx0 = (x0 >= 0 && x0 <= 63), vx1 = (x1 >= 0 && x1 <= 63);
        int cy0 = min(max(y0, 0), 63), cy1 = min(max(y1, 0), 63);
        int cx0 = min(max(x0, 0), 63), cx1 = min(max(x1, 0), 63);
        ti[e][0] = cy0 * 64 + cx0;  tw[e][0] = (vy0 && vx0) ? (1.f - wy1) * (1.f - wx1) * m : 0.f;
        ti[e][1] = cy0 * 64 + cx1;  tw[e][1] = (vy0 && vx1) ? (1.f - wy1) * wx1 * m : 0.f;
        ti[e][2] = cy1 * 64 + cx0;  tw[e][2] = (vy1 && vx0) ? wy1 * (1.f - wx1) * m : 0.f;
        ti[e][3] = cy1 * 64 + cx1;  tw[e][3] = (vy1 && vx1) ? wy1 * wx1 * m : 0.f;
    }
    __syncthreads();

    const int lane = tid & 63, wv = tid >> 6;
    const int quad = lane >> 4, l16 = lane & 15;
    f32x4 acc[4][2] = {{f32x4{0,0,0,0}, f32x4{0,0,0,0}}, {f32x4{0,0,0,0}, f32x4{0,0,0,0}},
                       {f32x4{0,0,0,0}, f32x4{0,0,0,0}}, {f32x4{0,0,0,0}, f32x4{0,0,0,0}}};
    const bf16* xtb = xt + (size_t)b * HWP * 128;

    #pragma unroll
    for (int h = 0; h < 2; h++) {
        if (h) __syncthreads();                    // protect val before regather
        // ---- gather half h: 32 px x 8 ch-groups (64 ch)
        {
            const int cig = tid & 7, pix = tid >> 3;
            const int ci0 = h * 64 + cig * 8;
            for (int k = 0; k < 9; k++) {
                const int e = k * 32 + pix;
                const int i0 = ti[e][0], i1 = ti[e][1], i2 = ti[e][2], i3 = ti[e][3];
                const float w0 = tw[e][0], w1 = tw[e][1], w2 = tw[e][2], w3 = tw[e][3];
                uint4 c0 = *(const uint4*)(xtb + (size_t)i0 * 128 + ci0);
                uint4 c1 = *(const uint4*)(xtb + (size_t)i1 * 128 + ci0);
                uint4 c2 = *(const uint4*)(xtb + (size_t)i2 * 128 + ci0);
                uint4 c3 = *(const uint4*)(xtb + (size_t)i3 * 128 + ci0);
                float g[8];
                #pragma unroll
                for (int j = 0; j < 8; j++)
                    g[j] = w0 * bfj(c0, j) + w1 * bfj(c1, j) + w2 * bfj(c2, j) + w3 * bfj(c3, j);
                uint4 pk;
                pk.x = (unsigned)f2bfbits(g[0]) | ((unsigned)f2bfbits(g[1]) << 16);
                pk.y = (unsigned)f2bfbits(g[2]) | ((unsigned)f2bfbits(g[3]) << 16);
                pk.z = (unsigned)f2bfbits(g[4]) | ((unsigned)f2bfbits(g[5]) << 16);
                pk.w = (unsigned)f2bfbits(g[6]) | ((unsigned)f2bfbits(g[7]) << 16);
                *(uint4*)&val[pix][k * 64 + cig * 8] = pk;
            }
        }
        __syncthreads();

        // ---- MFMA half h: wave = 64 co x 32 px (2 pixel groups)
        const bf16* wl0 = wBf2 + ((size_t)(wv * 2 + h) * 72) * 512 + lane * 8;  // frag(kt,mt) at +(kt*4+mt)*512
        const bf16* vb0 = &val[l16][quad * 8];
        const bf16* vb1 = &val[16 + l16][quad * 8];
        sh8 af[4], afn[4];
        #pragma unroll
        for (int mt = 0; mt < 4; mt++) af[mt] = *(const sh8*)(wl0 + mt * 512);
        for (int kt = 0; kt < 18; kt++) {
            sh8 b0 = *(const sh8*)(vb0 + kt * 32);
            sh8 b1 = *(const sh8*)(vb1 + kt * 32);
            if (kt < 17) {
                #pragma unroll
                for (int mt = 0; mt < 4; mt++)
                    afn[mt] = *(const sh8*)(wl0 + ((kt + 1) * 4 + mt) * 512);
            }
            #pragma unroll
            for (int mt = 0; mt < 4; mt++) {
                acc[mt][0] = __builtin_amdgcn_mfma_f32_16x16x32_bf16(af[mt], b0, acc[mt][0], 0, 0, 0);
                acc[mt][1] = __builtin_amdgcn_mfma_f32_16x16x32_bf16(af[mt], b1, acc[mt][1], 0, 0, 0);
            }
            #pragma unroll
            for (int mt = 0; mt < 4; mt++) af[mt] = afn[mt];
        }
    }

    // ---- epilogue: write combined_t[pos][co]
    #pragma unroll
    for (int ph = 0; ph < 2; ph++) {
        bf16* ct = combined + ((size_t)b * HWP + pos0 + ph * 16 + l16) * 384;
        #pragma unroll
        for (int mt = 0; mt < 4; mt++) {
            int co_b = wv * 64 + mt * 16 + quad * 4;
            uint2 pk;
            pk.x = (unsigned)f2bfbits(acc[mt][ph][0] + bias[co_b])     | ((unsigned)f2bfbits(acc[mt][ph][1] + bias[co_b + 1]) << 16);
            pk.y = (unsigned)f2bfbits(acc[mt][ph][2] + bias[co_b + 2]) | ((unsigned)f2bfbits(acc[mt][ph][3] + bias[co_b + 3]) << 16);
            *(uint2*)(ct + co_b) = pk;
        }
    }
}

// ---------------------------------------------------------------- SA GEMM (MFMA, LDS-free, prefetched)
__global__ __launch_bounds__(256) void sa_gemm_kernel(
    const bf16* __restrict__ combined, const bf16* __restrict__ wSAf, float* __restrict__ part)
{
    const int bid = blockIdx.x;
    const int b = bid >> 8, tile = bid & 255;
    const int pos0 = tile * 16;
    const int tid = threadIdx.x;
    const int lane = tid & 63, wv = tid >> 6;
    const int quad = lane >> 4, l16 = lane & 15;

    f32x4 acc = {0, 0, 0, 0};
    const bf16* fb = combined + ((size_t)b * HWP + pos0 + l16) * 384 + quad * 8;
    const bf16* wl0 = wSAf + (size_t)wv * 6144 + lane * 8;

    sh8 af = *(const sh8*)(wl0);
    sh8 bf = *(const sh8*)(fb);
    sh8 afn, bfn;
    for (int kt = 0; kt < 12; kt++) {
        if (kt < 11) {
            afn = *(const sh8*)(wl0 + (kt + 1) * 512);
            bfn = *(const sh8*)(fb + (kt + 1) * 32);
        }
        acc = __builtin_amdgcn_mfma_f32_16x16x32_bf16(af, bf, acc, 0, 0, 0);
        af = afn; bf = bfn;
    }
    #pragma unroll
    for (int r = 0; r < 4; r++) {
        int j = wv * 16 + quad * 4 + r;
        if (j < 49) part[(size_t)(j * BN + b) * HWP + pos0 + l16] = acc[r];
    }
}

// ---------------------------------------------------------------- fusion 1x1 MFMA + in-block attn finalize
__global__ __launch_bounds__(256) void fuse_kernel(
    const bf16* __restrict__ combined, const float* __restrict__ part, const float* __restrict__ sa_b,
    const bf16* __restrict__ wFf, const float* __restrict__ fab, float* __restrict__ out)
{
    __shared__ float sattn[16][17];
    __shared__ float lattn[16];

    const int bid = blockIdx.x;
    const int b = bid >> 8, tile = bid & 255;
    const int pos0 = tile * 16;
    const int y = tile >> 2, x0 = (tile & 3) * 16;
    const int tid = threadIdx.x;

    // ---- attn phase: 16 px x 16 groups, each sums taps j = g, g+16, g+32
    {
        const int px = tid & 15, g = tid >> 4;
        const int xp = x0 + px;
        float s = 0.f;
        for (int j = g; j < 49; j += 16) {
            int yy = y + j / 7 - 3, xx = xp + j % 7 - 3;
            if (yy < 0 || yy > 63 || xx < 0 || xx > 63) continue;
            s += part[(size_t)(j * BN + b) * HWP + yy * 64 + xx];
        }
        sattn[px][g] = s;
    }
    __syncthreads();
    if (tid < 16) {
        float t = sa_b[0];
        #pragma unroll
        for (int g = 0; g < 16; g++) t += sattn[tid][g];
        lattn[tid] = 1.f / (1.f + expf(-t));
    }
    __syncthreads();

    const int lane = tid & 63, wv = tid >> 6;
    const int quad = lane >> 4, l16 = lane & 15;

    f32x4 acc[4] = {f32x4{0,0,0,0}, f32x4{0,0,0,0}, f32x4{0,0,0,0}, f32x4{0,0,0,0}};
    const bf16* fb = combined + ((size_t)b * HWP + pos0 + l16) * 384 + quad * 8;
    const bf16* wl0 = wFf + (size_t)wv * 24576 + lane * 8;

    sh8 af[4], afn[4], bf, bfn;
    bf = *(const sh8*)(fb);
    #pragma unroll
    for (int mt = 0; mt < 4; mt++) af[mt] = *(const sh8*)(wl0 + mt * 512);
    for (int kt = 0; kt < 12; kt++) {
        if (kt < 11) {
            bfn = *(const sh8*)(fb + (kt + 1) * 32);
            #pragma unroll
            for (int mt = 0; mt < 4; mt++)
                afn[mt] = *(const sh8*)(wl0 + ((kt + 1) * 4 + mt) * 512);
        }
        #pragma unroll
        for (int mt = 0; mt < 4; mt++)
            acc[mt] = __builtin_amdgcn_mfma_f32_16x16x32_bf16(af[mt], bf, acc[mt], 0, 0, 0);
        bf = bfn;
        #pragma unroll
        for (int mt = 0; mt < 4; mt++) af[mt] = afn[mt];
    }

    float a = lattn[l16];
    float* op = out + (size_t)b * COUT * HWP + pos0 + l16;
    #pragma unroll
    for (int mt = 0; mt < 4; mt++) {
        int co_b = wv * 64 + mt * 16 + quad * 4;
        #pragma unroll
        for (int r = 0; r < 4; r++) {
            int co = co_b + r;
            float o = fmaxf(acc[mt][r] * a * fab[co] + fab[256 + co], 0.f);
            op[(size_t)co * HWP] = o;
        }
    }
}

// ================================================================ launch
extern "C" void kernel_launch(void* const* d_in, const int* in_sizes, int n_in,
                              void* d_out, int out_size, void* d_ws, size_t ws_size,
                              hipStream_t stream)
{
    const float* x      = (const float*)d_in[0];
    const float* oc1_w  = (const float*)d_in[1];
    const float* oc1_b  = (const float*)d_in[2];
    const float* obn_g  = (const float*)d_in[3];
    const float* obn_b  = (const float*)d_in[4];
    const float* obn_m  = (const float*)d_in[5];
    const float* obn_v  = (const float*)d_in[6];
    const float* oc2_w  = (const float*)d_in[7];
    const float* oc2_b  = (const float*)d_in[8];
    const float* mc1_w  = (const float*)d_in[9];
    const float* mc1_b  = (const float*)d_in[10];
    const float* mbn_g  = (const float*)d_in[11];
    const float* mbn_b  = (const float*)d_in[12];
    const float* mbn_m  = (const float*)d_in[13];
    const float* mbn_v  = (const float*)d_in[14];
    const float* mc2_w  = (const float*)d_in[15];
    const float* mc2_b  = (const float*)d_in[16];
    const float* dc_w   = (const float*)d_in[17];
    const float* dc_b   = (const float*)d_in[18];
    const float* cb_dw_w= (const float*)d_in[19];
    const float* cb_dw_b= (const float*)d_in[20];
    const float* cbn_g  = (const float*)d_in[21];
    const float* cbn_b  = (const float*)d_in[22];
    const float* cbn_m  = (const float*)d_in[23];
    const float* cbn_v  = (const float*)d_in[24];
    const float* cb_pw_w= (const float*)d_in[25];
    const float* cb_pw_b= (const float*)d_in[26];
    const float* sa_w   = (const float*)d_in[27];
    const float* sa_b   = (const float*)d_in[28];
    const float* fu_w   = (const float*)d_in[29];
    const float* fu_b   = (const float*)d_in[30];
    const float* fbn_g  = (const float*)d_in[31];
    const float* fbn_b  = (const float*)d_in[32];
    const float* fbn_m  = (const float*)d_in[33];
    const float* fbn_v  = (const float*)d_in[34];

    // workspace layout
    bf16*  ht    = (bf16*)d_ws;                // 1,048,576 bf16
    float* offsb = (float*)(ht + 1048576);     //   294,912 f32
    float* mskb  = offsb + 294912;             //   147,456 f32
    bf16*  comb  = (bf16*)(mskb + 147456);     // 6,291,456 bf16
    float* part  = (float*)(comb + 6291456);   //   802,816 f32
    bf16*  xt    = (bf16*)(part + 802816);     // 2,097,152 bf16
    bf16*  wBf2  = xt + 2097152;               //   294,912 bf16
    bf16*  wCf   = wBf2 + 294912;              //    73,728 bf16
    float* ab    = (float*)(wCf + 73728);      //       128 f32
    bf16*  wFf   = (bf16*)(ab + 128);          //    98,304 bf16
    bf16*  wSAf  = wFf + 98304;                //    24,576 bf16
    float* fab   = (float*)(wSAf + 24576);     //       512 f32
    bf16*  wDf   = (bf16*)(fab + 512);         //    18,432 bf16
    bf16*  wPf   = wDf + 18432;                //    16,384 bf16
    float* dwab  = (float*)(wPf + 16384);      //       256 f32

    float* out = (float*)d_out;

    // 0. transpose x -> pixel-major bf16
    transpose_x_kernel<<<256, 256, 0, stream>>>(x, xt);
    // 1. all weight preps (one kernel)
    prep_all_kernel<<<2058, 256, 0, stream>>>(
        dc_w, oc1_w, oc1_b, obn_g, obn_b, obn_m, obn_v,
        mc1_w, mc1_b, mbn_g, mbn_b, mbn_m, mbn_v,
        fu_w, fu_b, fbn_g, fbn_b, fbn_m, fbn_v, sa_w,
        oc2_w, mc2_w, cb_pw_w, cb_dw_b, cbn_g, cbn_b, cbn_m, cbn_v,
        wBf2, wCf, ab, wFf, wSAf, fab, wDf, wPf, dwab);
    // 2. oc1 + mc1 fused MFMA conv -> ht pixel-major
    conv1_mfma_kernel<<<1024, 256, 0, stream>>>(xt, wCf, ab, ht);
    // 3. oc2 + mc2 fused MFMA conv -> offsets + sigmoid masks
    conv2_mfma_kernel<<<512, 256, 0, stream>>>(ht, wDf, oc2_b, mc2_b, offsb, mskb);
    // 4. fused contour depthwise + pointwise -> combined_t[:, 256:384]
    dwpw_kernel<<<1024, 256, 0, stream>>>(xt, cb_dw_w, dwab, wPf, cb_pw_b, comb);
    // 5. modulated deformable conv (MFMA, 32px, K-split) -> combined_t[:, 0:256]
    deform_kernel<<<512, 256, 0, stream>>>(xt, offsb, mskb, wBf2, dc_b, comb);
    // 6. SA GEMM (MFMA, LDS-free)
    sa_gemm_kernel<<<1024, 256, 0, stream>>>(comb, wSAf, part);
    // 7. fusion 1x1 MFMA (+in-block attn, folded BN, ReLU) -> fp32 out
    fuse_kernel<<<1024, 256, 0, stream>>>(comb, part, sa_b, wFf, fab, out);
}

// Round 11
// 207.020 us; speedup vs baseline: 7.0585x; 1.0283x over previous
//
#include <hip/hip_runtime.h>
#include <hip/hip_bf16.h>
#include <math.h>

// Problem constants
#define BN   4
#define CIN  128
#define COUT 256
#define HWP  4096      // 64*64

typedef __hip_bfloat16 bf16;
typedef __attribute__((ext_vector_type(8))) short sh8;    // 8 bf16 = 4 VGPR
typedef __attribute__((ext_vector_type(4))) float f32x4;  // MFMA accumulator

__device__ __forceinline__ float b2f(bf16 v) { return __bfloat162float(v); }
__device__ __forceinline__ float bflo(unsigned u) { return __uint_as_float(u << 16); }
__device__ __forceinline__ float bfhi(unsigned u) { return __uint_as_float(u & 0xffff0000u); }
__device__ __forceinline__ unsigned short f2bfbits(float f) {
    union { bf16 h; unsigned short u; } cv; cv.h = __float2bfloat16(f); return cv.u;
}
__device__ __forceinline__ float bfj(const uint4& c, int j) {
    unsigned u = (&c.x)[j >> 1];
    return (j & 1) ? bfhi(u) : bflo(u);
}

// ---------------------------------------------------------------- prep_all (+x transpose in blocks [0,256))
// seg0: wBf2 [0, 294912)  deform weights 32px/K-split frag-major
// seg1: wCf2 [294912, 368640), ab [368640, 368704)   conv1 32px/K-split frag-major
// seg2: wFf  [368704, 467008), wSAf [467008, 491584), fab [491584, 491840)
// seg3: wDf  [491840, 510272), wPf [510272, 526656), dwab [526656, 526784)
__global__ __launch_bounds__(256) void prep_all_kernel(
    const float* __restrict__ x, bf16* __restrict__ xt,
    const float* __restrict__ dc_w,
    const float* __restrict__ oc1_w, const float* __restrict__ oc1_b,
    const float* __restrict__ obn_g, const float* __restrict__ obn_b,
    const float* __restrict__ obn_m, const float* __restrict__ obn_v,
    const float* __restrict__ mc1_w, const float* __restrict__ mc1_b,
    const float* __restrict__ mbn_g, const float* __restrict__ mbn_b,
    const float* __restrict__ mbn_m, const float* __restrict__ mbn_v,
    const float* __restrict__ fu_w, const float* __restrict__ fu_b,
    const float* __restrict__ fbn_g, const float* __restrict__ fbn_b,
    const float* __restrict__ fbn_m, const float* __restrict__ fbn_v,
    const float* __restrict__ sa_w,
    const float* __restrict__ oc2_w, const float* __restrict__ mc2_w,
    const float* __restrict__ cb_pw_w,
    const float* __restrict__ cb_dw_b, const float* __restrict__ cbn_g,
    const float* __restrict__ cbn_b, const float* __restrict__ cbn_m,
    const float* __restrict__ cbn_v,
    bf16* __restrict__ wBf2, bf16* __restrict__ wCf2, float* __restrict__ ab,
    bf16* __restrict__ wFf, bf16* __restrict__ wSAf, float* __restrict__ fab,
    bf16* __restrict__ wDf, bf16* __restrict__ wPf, float* __restrict__ dwab)
{
    __shared__ bf16 t[64][136];
    if (blockIdx.x < 256) {
        // ---- x transpose: [b][ci][pos] f32 -> xt [b][pos][ci] bf16
        const int b = blockIdx.x >> 6, chunk = blockIdx.x & 63;
        const int pos0 = chunk * 64;
        const int tid = threadIdx.x;
        const int lane = tid & 63, wv = tid >> 6;
        const float* xb = x + (size_t)b * CIN * HWP + pos0 + lane;
        #pragma unroll 4
        for (int j = 0; j < 32; j++) {
            int ci = wv * 32 + j;
            t[lane][ci] = __float2bfloat16(xb[(size_t)ci * HWP]);
        }
        __syncthreads();
        const int p = tid >> 2, cig = tid & 3;
        uint4* dst = (uint4*)(xt + ((size_t)b * HWP + pos0 + p) * 128 + cig * 32);
        const uint4* src = (const uint4*)&t[p][cig * 32];
        #pragma unroll
        for (int q = 0; q < 4; q++) dst[q] = src[q];
        return;
    }

    int o = (blockIdx.x - 256) * 256 + threadIdx.x;
    if (o < 294912) {
        // wBf2[(((wv*2+h)*18+kt)*4+mt)*64+lane][8j]; co=wv*64+mt*16+l16; kkh=kt*32+quad*8+j
        int j = o & 7, o2 = o >> 3;
        int lane = o2 & 63, t_ = o2 >> 6;
        int l16 = lane & 15, quad = lane >> 4;
        int mt = t_ & 3, t2 = t_ >> 2;
        int kt = t2 % 18, t3 = t2 / 18;
        int h = t3 & 1, wv = t3 >> 1;
        int co = wv * 64 + mt * 16 + l16;
        int kkh = kt * 32 + quad * 8 + j;
        int k = kkh >> 6, ci = h * 64 + (kkh & 63);
        wBf2[o] = __float2bfloat16(dc_w[co * 1152 + ci * 9 + k]);
    } else if (o < 368640) {
        // wCf2[((wv*2+h)*18+kt)*64+lane][8j]; co=wv*16+l16; kkh=kt*32+quad*8+j
        int idx = o - 294912;
        int j = idx & 7, o2 = idx >> 3;
        int lane = o2 & 63, t_ = o2 >> 6;          // t_ in [0,144)
        int l16 = lane & 15, quad = lane >> 4;
        int kt = t_ % 18, t2 = t_ / 18;            // t2 in [0,8)
        int h = t2 & 1, wv = t2 >> 1;
        int co = wv * 16 + l16;
        int kkh = kt * 32 + quad * 8 + j;
        int k = kkh >> 6, ci = h * 64 + (kkh & 63);
        float v = (co < 32) ? oc1_w[co * 1152 + ci * 9 + k]
                            : mc1_w[(co - 32) * 1152 + ci * 9 + k];
        wCf2[idx] = __float2bfloat16(v);
    } else if (o < 368704) {
        int c = o - 368640;
        float g, bb, m, vv, bias;
        if (c < 32) { g = obn_g[c]; bb = obn_b[c]; m = obn_m[c]; vv = obn_v[c]; bias = oc1_b[c]; }
        else { int c2 = c - 32; g = mbn_g[c2]; bb = mbn_b[c2]; m = mbn_m[c2]; vv = mbn_v[c2]; bias = mc1_b[c2]; }
        float alpha = g / sqrtf(vv + 1e-5f);
        ab[c] = alpha;
        ab[64 + c] = (bias - m) * alpha + bb;
    } else if (o < 467008) {
        int idx = o - 368704;
        int j = idx & 7, o2 = idx >> 3;
        int lane = o2 & 63, t_ = o2 >> 6;
        int l16 = lane & 15, quad = lane >> 4;
        int mt = t_ & 3, t2 = t_ >> 2;
        int kt = t2 % 12, wv = t2 / 12;
        int co = wv * 64 + mt * 16 + l16;
        int kk = kt * 32 + quad * 8 + j;
        wFf[idx] = __float2bfloat16(fu_w[co * 384 + kk]);
    } else if (o < 491584) {
        int idx = o - 467008;
        int j = idx & 7, o2 = idx >> 3;
        int lane = o2 & 63, t_ = o2 >> 6;
        int l16 = lane & 15, quad = lane >> 4;
        int kt = t_ % 12, wv = t_ / 12;
        int jr = wv * 16 + l16;
        int kk = kt * 32 + quad * 8 + j;
        wSAf[idx] = (jr < 49) ? __float2bfloat16(sa_w[kk * 49 + jr]) : __float2bfloat16(0.f);
    } else if (o < 491840) {
        int co = o - 491584;
        float alpha = fbn_g[co] / sqrtf(fbn_v[co] + 1e-5f);
        fab[co] = alpha;
        fab[256 + co] = (fu_b[co] - fbn_m[co]) * alpha + fbn_b[co];
    } else if (o < 510272) {
        int idx = o - 491840;
        int j = idx & 7, o2 = idx >> 3;
        int lane = o2 & 63, t_ = o2 >> 6;       // t_ in [0,36)
        int l16 = lane & 15, quad = lane >> 4;
        int mt = t_ & 1, kt = t_ >> 1;
        int co = mt * 16 + l16;
        int kk = kt * 32 + quad * 8 + j;
        int k = kk >> 6, c = kk & 63;
        float v = 0.f;
        if (co < 18 && c < 32) v = oc2_w[co * 288 + c * 9 + k];
        else if (co >= 18 && co < 27 && c >= 32) v = mc2_w[(co - 18) * 288 + (c - 32) * 9 + k];
        wDf[idx] = __float2bfloat16(v);
    } else if (o < 526656) {
        int idx = o - 510272;
        int j = idx & 7, o2 = idx >> 3;
        int lane = o2 & 63, t_ = o2 >> 6;       // t_ in [0,32)
        int l16 = lane & 15, quad = lane >> 4;
        int wv = t_ >> 3, kt = (t_ >> 1) & 3, mt = t_ & 1;
        int co = wv * 32 + mt * 16 + l16;
        int kk = kt * 32 + quad * 8 + j;
        wPf[idx] = __float2bfloat16(cb_pw_w[co * 128 + kk]);
    } else if (o < 526784) {
        int c = o - 526656;
        float alpha = cbn_g[c] / sqrtf(cbn_v[c] + 1e-5f);
        dwab[c] = alpha;
        dwab[128 + c] = (cb_dw_b[c] - cbn_m[c]) * alpha + cbn_b[c];
    }
}

// ---------------------------------------------------------------- conv1 (oc1+mc1) MFMA, 32px K-split -> ht[b][pos][64]
// grid 512, block 256 = 4 waves (wave = 16 co x 32 px). LDS ~37 KB.
__global__ __launch_bounds__(256) void conv1_mfma_kernel(
    const bf16* __restrict__ xt, const bf16* __restrict__ wCf2, const float* __restrict__ ab,
    bf16* __restrict__ ht)
{
    __shared__ __align__(16) bf16 val[32][584];

    const int bid = blockIdx.x;
    const int b = (bid & 7) >> 1;
    const int tile = ((bid >> 3) << 1) | (bid & 1);   // [0,128)
    const int pos0 = tile * 32;
    const int y = tile >> 1, x0 = (tile & 1) * 32;
    const int tid = threadIdx.x;
    const int lane = tid & 63, wv = tid >> 6;
    const int quad = lane >> 4, l16 = lane & 15;

    f32x4 acc[2] = {f32x4{0,0,0,0}, f32x4{0,0,0,0}};
    const bf16* xtb = xt + (size_t)b * HWP * 128;

    #pragma unroll
    for (int h = 0; h < 2; h++) {
        if (h) __syncthreads();
        {
            const int cig = tid & 7, pix = tid >> 3;
            const int ci0 = h * 64 + cig * 8;
            const int xxp = x0 + pix;
            #pragma unroll
            for (int k = 0; k < 9; k++) {
                int yy = y + k / 3 - 1, xx = xxp + k % 3 - 1;
                bool valid = (yy >= 0 && yy <= 63 && xx >= 0 && xx <= 63);
                uint4 c = {0, 0, 0, 0};
                if (valid) c = *(const uint4*)(xtb + (size_t)(yy * 64 + xx) * 128 + ci0);
                *(uint4*)&val[pix][k * 64 + cig * 8] = c;
            }
        }
        __syncthreads();

        const bf16* wl0 = wCf2 + ((size_t)(wv * 2 + h) * 18) * 512 + lane * 8;
        const bf16* vb0 = &val[l16][quad * 8];
        const bf16* vb1 = &val[16 + l16][quad * 8];
        for (int kt = 0; kt < 18; kt++) {
            sh8 af = *(const sh8*)(wl0 + kt * 512);
            sh8 b0 = *(const sh8*)(vb0 + kt * 32);
            sh8 b1 = *(const sh8*)(vb1 + kt * 32);
            acc[0] = __builtin_amdgcn_mfma_f32_16x16x32_bf16(af, b0, acc[0], 0, 0, 0);
            acc[1] = __builtin_amdgcn_mfma_f32_16x16x32_bf16(af, b1, acc[1], 0, 0, 0);
        }
    }

    const int co0 = wv * 16 + quad * 4;
    #pragma unroll
    for (int ph = 0; ph < 2; ph++) {
        float o0 = fmaxf(acc[ph][0] * ab[co0 + 0] + ab[64 + co0 + 0], 0.f);
        float o1 = fmaxf(acc[ph][1] * ab[co0 + 1] + ab[64 + co0 + 1], 0.f);
        float o2 = fmaxf(acc[ph][2] * ab[co0 + 2] + ab[64 + co0 + 2], 0.f);
        float o3 = fmaxf(acc[ph][3] * ab[co0 + 3] + ab[64 + co0 + 3], 0.f);
        uint2 pk;
        pk.x = (unsigned)f2bfbits(o0) | ((unsigned)f2bfbits(o1) << 16);
        pk.y = (unsigned)f2bfbits(o2) | ((unsigned)f2bfbits(o3) << 16);
        *(uint2*)(ht + ((size_t)b * HWP + pos0 + ph * 16 + l16) * 64 + co0) = pk;
    }
}

// ---------------------------------------------------------------- fused depthwise + pointwise -> comb[..][256:384]
__global__ __launch_bounds__(256) void dwpw_kernel(
    const bf16* __restrict__ xt, const float* __restrict__ dw_w, const float* __restrict__ dwab,
    const bf16* __restrict__ wPf, const float* __restrict__ pw_b, bf16* __restrict__ combined)
{
    __shared__ float wl[1152];
    __shared__ float abl[256];
    __shared__ __align__(16) bf16 vdw[16][136];
    const int bid = blockIdx.x;
    const int b = bid >> 8, tile = bid & 255;
    const int pos0 = tile * 16;
    const int y = tile >> 2, x0 = (tile & 3) * 16;
    const int tid = threadIdx.x;
    for (int i = tid; i < 1152; i += 256) wl[i] = dw_w[i];
    abl[tid] = dwab[tid];
    __syncthreads();

    {
        const int cig = tid & 15, pix = tid >> 4;
        const int ci0 = cig * 8;
        const int xxp = x0 + pix;
        const bf16* xtb = xt + (size_t)b * HWP * 128;
        float g[8] = {0, 0, 0, 0, 0, 0, 0, 0};
        #pragma unroll
        for (int k = 0; k < 9; k++) {
            int yy = y + k / 3 - 1, xx = xxp + k % 3 - 1;
            if (yy < 0 || yy > 63 || xx < 0 || xx > 63) continue;
            uint4 c = *(const uint4*)(xtb + (size_t)(yy * 64 + xx) * 128 + ci0);
            #pragma unroll
            for (int j = 0; j < 8; j++)
                g[j] += wl[(ci0 + j) * 9 + k] * bfj(c, j);
        }
        uint4 pk;
        float o[8];
        #pragma unroll
        for (int j = 0; j < 8; j++)
            o[j] = fmaxf(g[j] * abl[ci0 + j] + abl[128 + ci0 + j], 0.f);
        pk.x = (unsigned)f2bfbits(o[0]) | ((unsigned)f2bfbits(o[1]) << 16);
        pk.y = (unsigned)f2bfbits(o[2]) | ((unsigned)f2bfbits(o[3]) << 16);
        pk.z = (unsigned)f2bfbits(o[4]) | ((unsigned)f2bfbits(o[5]) << 16);
        pk.w = (unsigned)f2bfbits(o[6]) | ((unsigned)f2bfbits(o[7]) << 16);
        *(uint4*)&vdw[pix][ci0] = pk;
    }
    __syncthreads();

    const int lane = tid & 63, wv = tid >> 6;
    const int quad = lane >> 4, l16 = lane & 15;
    f32x4 acc[2] = {f32x4{0,0,0,0}, f32x4{0,0,0,0}};
    const bf16* fb = &vdw[l16][quad * 8];
    const bf16* wl0 = wPf + (size_t)wv * 4096 + lane * 8;
    #pragma unroll
    for (int kt = 0; kt < 4; kt++) {
        sh8 bf = *(const sh8*)(fb + kt * 32);
        #pragma unroll
        for (int mt = 0; mt < 2; mt++) {
            sh8 af = *(const sh8*)(wl0 + (kt * 2 + mt) * 512);
            acc[mt] = __builtin_amdgcn_mfma_f32_16x16x32_bf16(af, bf, acc[mt], 0, 0, 0);
        }
    }

    bf16* ct = combined + ((size_t)b * HWP + pos0 + l16) * 384 + 256;
    #pragma unroll
    for (int mt = 0; mt < 2; mt++) {
        int co_b = wv * 32 + mt * 16 + quad * 4;
        uint2 pk;
        pk.x = (unsigned)f2bfbits(acc[mt][0] + pw_b[co_b])     | ((unsigned)f2bfbits(acc[mt][1] + pw_b[co_b + 1]) << 16);
        pk.y = (unsigned)f2bfbits(acc[mt][2] + pw_b[co_b + 2]) | ((unsigned)f2bfbits(acc[mt][3] + pw_b[co_b + 3]) << 16);
        *(uint2*)(ct + co_b) = pk;
    }
}

// ---------------------------------------------------------------- fused conv2 + modulated deformable conv (MFMA)
// grid 512, block 256 = 4 waves. Phase A: conv2 MFMA from ht-im2col -> offsets/masks in LDS.
// Phase B: bilinear tables. Phase C/D: K-split gather + MFMA. LDS ~51 KB.
__global__ __launch_bounds__(256) void deform_kernel(
    const bf16* __restrict__ xt, const bf16* __restrict__ ht, const bf16* __restrict__ wDf,
    const float* __restrict__ oc2_b, const float* __restrict__ mc2_b,
    const bf16* __restrict__ wBf2, const float* __restrict__ bias, bf16* __restrict__ combined)
{
    __shared__ __align__(16) bf16 val[32][584];
    __shared__ int   ti[288][4];
    __shared__ float tw[288][4];
    __shared__ float loff[18][32];
    __shared__ float lmsk[9][32];

    const int bid = blockIdx.x;
    const int b = (bid & 7) >> 1;                    // XCD-affinity
    const int tile = ((bid >> 3) << 1) | (bid & 1);  // [0,128)
    const int pos0 = tile * 32;
    const int y = tile >> 1, x0 = (tile & 1) * 32;
    const int tid = threadIdx.x;
    const int lane = tid & 63, wv = tid >> 6;
    const int quad = lane >> 4, l16 = lane & 15;

    // ---- Phase A: conv2 (oc2+mc2) for this tile's 32 pixels
    {
        const int cig = tid & 7, pix = tid >> 3;
        const int xxp = x0 + pix;
        const bf16* hb = ht + (size_t)b * HWP * 64;
        #pragma unroll
        for (int k = 0; k < 9; k++) {
            int yy = y + k / 3 - 1, xx = xxp + k % 3 - 1;
            bool valid = (yy >= 0 && yy <= 63 && xx >= 0 && xx <= 63);
            uint4 c = {0, 0, 0, 0};
            if (valid) c = *(const uint4*)(hb + (size_t)(yy * 64 + xx) * 64 + cig * 8);
            *(uint4*)&val[pix][k * 64 + cig * 8] = c;
        }
    }
    __syncthreads();
    {
        const int ph = wv >> 1, mt = wv & 1;
        f32x4 acc2 = {0, 0, 0, 0};
        const bf16* wl0 = wDf + ((size_t)mt * 64 + lane) * 8;     // frag kt at + kt*1024
        const bf16* vbase = &val[ph * 16 + l16][quad * 8];
        for (int kt = 0; kt < 18; kt++) {
            sh8 af = *(const sh8*)(wl0 + kt * 1024);
            sh8 bf = *(const sh8*)(vbase + kt * 32);
            acc2 = __builtin_amdgcn_mfma_f32_16x16x32_bf16(af, bf, acc2, 0, 0, 0);
        }
        const int pix2 = ph * 16 + l16;
        #pragma unroll
        for (int r = 0; r < 4; r++) {
            int co = mt * 16 + quad * 4 + r;
            if (co < 18) {
                loff[co][pix2] = acc2[r] + oc2_b[co];
            } else if (co < 27) {
                float s = acc2[r] + mc2_b[co - 18];
                lmsk[co - 18][pix2] = 1.f / (1.f + expf(-s));
            }
        }
    }
    __syncthreads();

    // ---- Phase B: bilinear corner tables from LDS offsets
    for (int e = tid; e < 288; e += 256) {           // e = k*32 + pix
        int k = e >> 5, pix = e & 31;
        int pos = pos0 + pix;
        int yp = pos >> 6, xc = pos & 63;
        float offy = loff[2 * k][pix];
        float offx = loff[2 * k + 1][pix];
        float m = lmsk[k][pix];
        float py = (float)(yp - 1 + k / 3) + offy;
        float px = (float)(xc - 1 + k % 3) + offx;
        float fy = floorf(py), fx = floorf(px);
        float wy1 = py - fy, wx1 = px - fx;
        int y0 = (int)fy, x0c = (int)fx;
        int y1 = y0 + 1, x1 = x0c + 1;
        bool vy0 = (y0 >= 0 && y0 <= 63), vy1 = (y1 >= 0 && y1 <= 63);
        bool vx0 = (x0c >= 0 && x0c <= 63), vx1 = (x1 >= 0 && x1 <= 63);
        int cy0 = min(max(y0, 0), 63), cy1 = min(max(y1, 0), 63);
        int cx0 = min(max(x0c, 0), 63), cx1 = min(max(x1, 0), 63);
        ti[e][0] = cy0 * 64 + cx0;  tw[e][0] = (vy0 && vx0) ? (1.f - wy1) * (1.f - wx1) * m : 0.f;
        ti[e][1] = cy0 * 64 + cx1;  tw[e][1] = (vy0 && vx1) ? (1.f - wy1) * wx1 * m : 0.f;
        ti[e][2] = cy1 * 64 + cx0;  tw[e][2] = (vy1 && vx0) ? wy1 * (1.f - wx1) * m : 0.f;
        ti[e][3] = cy1 * 64 + cx1;  tw[e][3] = (vy1 && vx1) ? wy1 * wx1 * m : 0.f;
    }
    __syncthreads();

    // ---- Phase C/D: K-split gather + MFMA
    f32x4 acc[4][2] = {{f32x4{0,0,0,0}, f32x4{0,0,0,0}}, {f32x4{0,0,0,0}, f32x4{0,0,0,0}},
                       {f32x4{0,0,0,0}, f32x4{0,0,0,0}}, {f32x4{0,0,0,0}, f32x4{0,0,0,0}}};
    const bf16* xtb = xt + (size_t)b * HWP * 128;

    #pragma unroll
    for (int h = 0; h < 2; h++) {
        if (h) __syncthreads();
        {
            const int cig = tid & 7, pix = tid >> 3;
            const int ci0 = h * 64 + cig * 8;
            for (int k = 0; k < 9; k++) {
                const int e = k * 32 + pix;
                const int i0 = ti[e][0], i1 = ti[e][1], i2 = ti[e][2], i3 = ti[e][3];
                const float w0 = tw[e][0], w1 = tw[e][1], w2 = tw[e][2], w3 = tw[e][3];
                uint4 c0 = *(const uint4*)(xtb + (size_t)i0 * 128 + ci0);
                uint4 c1 = *(const uint4*)(xtb + (size_t)i1 * 128 + ci0);
                uint4 c2 = *(const uint4*)(xtb + (size_t)i2 * 128 + ci0);
                uint4 c3 = *(const uint4*)(xtb + (size_t)i3 * 128 + ci0);
                float g[8];
                #pragma unroll
                for (int j = 0; j < 8; j++)
                    g[j] = w0 * bfj(c0, j) + w1 * bfj(c1, j) + w2 * bfj(c2, j) + w3 * bfj(c3, j);
                uint4 pk;
                pk.x = (unsigned)f2bfbits(g[0]) | ((unsigned)f2bfbits(g[1]) << 16);
                pk.y = (unsigned)f2bfbits(g[2]) | ((unsigned)f2bfbits(g[3]) << 16);
                pk.z = (unsigned)f2bfbits(g[4]) | ((unsigned)f2bfbits(g[5]) << 16);
                pk.w = (unsigned)f2bfbits(g[6]) | ((unsigned)f2bfbits(g[7]) << 16);
                *(uint4*)&val[pix][k * 64 + cig * 8] = pk;
            }
        }
        __syncthreads();

        const bf16* wl0 = wBf2 + ((size_t)(wv * 2 + h) * 72) * 512 + lane * 8;
        const bf16* vb0 = &val[l16][quad * 8];
        const bf16* vb1 = &val[16 + l16][quad * 8];
        sh8 af[4], afn[4];
        #pragma unroll
        for (int mt = 0; mt < 4; mt++) af[mt] = *(const sh8*)(wl0 + mt * 512);
        for (int kt = 0; kt < 18; kt++) {
            sh8 b0 = *(const sh8*)(vb0 + kt * 32);
            sh8 b1 = *(const sh8*)(vb1 + kt * 32);
            if (kt < 17) {
                #pragma unroll
                for (int mt = 0; mt < 4; mt++)
                    afn[mt] = *(const sh8*)(wl0 + ((kt + 1) * 4 + mt) * 512);
            }
            #pragma unroll
            for (int mt = 0; mt < 4; mt++) {
                acc[mt][0] = __builtin_amdgcn_mfma_f32_16x16x32_bf16(af[mt], b0, acc[mt][0], 0, 0, 0);
                acc[mt][1] = __builtin_amdgcn_mfma_f32_16x16x32_bf16(af[mt], b1, acc[mt][1], 0, 0, 0);
            }
            #pragma unroll
            for (int mt = 0; mt < 4; mt++) af[mt] = afn[mt];
        }
    }

    #pragma unroll
    for (int ph = 0; ph < 2; ph++) {
        bf16* ct = combined + ((size_t)b * HWP + pos0 + ph * 16 + l16) * 384;
        #pragma unroll
        for (int mt = 0; mt < 4; mt++) {
            int co_b = wv * 64 + mt * 16 + quad * 4;
            uint2 pk;
            pk.x = (unsigned)f2bfbits(acc[mt][ph][0] + bias[co_b])     | ((unsigned)f2bfbits(acc[mt][ph][1] + bias[co_b + 1]) << 16);
            pk.y = (unsigned)f2bfbits(acc[mt][ph][2] + bias[co_b + 2]) | ((unsigned)f2bfbits(acc[mt][ph][3] + bias[co_b + 3]) << 16);
            *(uint2*)(ct + co_b) = pk;
        }
    }
}

// ---------------------------------------------------------------- SA GEMM (MFMA, LDS-free, prefetched)
__global__ __launch_bounds__(256) void sa_gemm_kernel(
    const bf16* __restrict__ combined, const bf16* __restrict__ wSAf, float* __restrict__ part)
{
    const int bid = blockIdx.x;
    const int b = bid >> 8, tile = bid & 255;
    const int pos0 = tile * 16;
    const int tid = threadIdx.x;
    const int lane = tid & 63, wv = tid >> 6;
    const int quad = lane >> 4, l16 = lane & 15;

    f32x4 acc = {0, 0, 0, 0};
    const bf16* fb = combined + ((size_t)b * HWP + pos0 + l16) * 384 + quad * 8;
    const bf16* wl0 = wSAf + (size_t)wv * 6144 + lane * 8;

    sh8 af = *(const sh8*)(wl0);
    sh8 bf = *(const sh8*)(fb);
    sh8 afn, bfn;
    for (int kt = 0; kt < 12; kt++) {
        if (kt < 11) {
            afn = *(const sh8*)(wl0 + (kt + 1) * 512);
            bfn = *(const sh8*)(fb + (kt + 1) * 32);
        }
        acc = __builtin_amdgcn_mfma_f32_16x16x32_bf16(af, bf, acc, 0, 0, 0);
        af = afn; bf = bfn;
    }
    #pragma unroll
    for (int r = 0; r < 4; r++) {
        int j = wv * 16 + quad * 4 + r;
        if (j < 49) part[(size_t)(j * BN + b) * HWP + pos0 + l16] = acc[r];
    }
}

// ---------------------------------------------------------------- fusion 1x1 MFMA + in-block attn finalize
__global__ __launch_bounds__(256) void fuse_kernel(
    const bf16* __restrict__ combined, const float* __restrict__ part, const float* __restrict__ sa_b,
    const bf16* __restrict__ wFf, const float* __restrict__ fab, float* __restrict__ out)
{
    __shared__ float sattn[16][17];
    __shared__ float lattn[16];

    const int bid = blockIdx.x;
    const int b = bid >> 8, tile = bid & 255;
    const int pos0 = tile * 16;
    const int y = tile >> 2, x0 = (tile & 3) * 16;
    const int tid = threadIdx.x;

    {
        const int px = tid & 15, g = tid >> 4;
        const int xp = x0 + px;
        float s = 0.f;
        for (int j = g; j < 49; j += 16) {
            int yy = y + j / 7 - 3, xx = xp + j % 7 - 3;
            if (yy < 0 || yy > 63 || xx < 0 || xx > 63) continue;
            s += part[(size_t)(j * BN + b) * HWP + yy * 64 + xx];
        }
        sattn[px][g] = s;
    }
    __syncthreads();
    if (tid < 16) {
        float t = sa_b[0];
        #pragma unroll
        for (int g = 0; g < 16; g++) t += sattn[tid][g];
        lattn[tid] = 1.f / (1.f + expf(-t));
    }
    __syncthreads();

    const int lane = tid & 63, wv = tid >> 6;
    const int quad = lane >> 4, l16 = lane & 15;

    f32x4 acc[4] = {f32x4{0,0,0,0}, f32x4{0,0,0,0}, f32x4{0,0,0,0}, f32x4{0,0,0,0}};
    const bf16* fb = combined + ((size_t)b * HWP + pos0 + l16) * 384 + quad * 8;
    const bf16* wl0 = wFf + (size_t)wv * 24576 + lane * 8;

    sh8 af[4], afn[4], bf, bfn;
    bf = *(const sh8*)(fb);
    #pragma unroll
    for (int mt = 0; mt < 4; mt++) af[mt] = *(const sh8*)(wl0 + mt * 512);
    for (int kt = 0; kt < 12; kt++) {
        if (kt < 11) {
            bfn = *(const sh8*)(fb + (kt + 1) * 32);
            #pragma unroll
            for (int mt = 0; mt < 4; mt++)
                afn[mt] = *(const sh8*)(wl0 + ((kt + 1) * 4 + mt) * 512);
        }
        #pragma unroll
        for (int mt = 0; mt < 4; mt++)
            acc[mt] = __builtin_amdgcn_mfma_f32_16x16x32_bf16(af[mt], bf, acc[mt], 0, 0, 0);
        bf = bfn;
        #pragma unroll
        for (int mt = 0; mt < 4; mt++) af[mt] = afn[mt];
    }

    float a = lattn[l16];
    float* op = out + (size_t)b * COUT * HWP + pos0 + l16;
    #pragma unroll
    for (int mt = 0; mt < 4; mt++) {
        int co_b = wv * 64 + mt * 16 + quad * 4;
        #pragma unroll
        for (int r = 0; r < 4; r++) {
            int co = co_b + r;
            float o = fmaxf(acc[mt][r] * a * fab[co] + fab[256 + co], 0.f);
            op[(size_t)co * HWP] = o;
        }
    }
}

// ================================================================ launch
extern "C" void kernel_launch(void* const* d_in, const int* in_sizes, int n_in,
                              void* d_out, int out_size, void* d_ws, size_t ws_size,
                              hipStream_t stream)
{
    const float* x      = (const float*)d_in[0];
    const float* oc1_w  = (const float*)d_in[1];
    const float* oc1_b  = (const float*)d_in[2];
    const float* obn_g  = (const float*)d_in[3];
    const float* obn_b  = (const float*)d_in[4];
    const float* obn_m  = (const float*)d_in[5];
    const float* obn_v  = (const float*)d_in[6];
    const float* oc2_w  = (const float*)d_in[7];
    const float* oc2_b  = (const float*)d_in[8];
    const float* mc1_w  = (const float*)d_in[9];
    const float* mc1_b  = (const float*)d_in[10];
    const float* mbn_g  = (const float*)d_in[11];
    const float* mbn_b  = (const float*)d_in[12];
    const float* mbn_m  = (const float*)d_in[13];
    const float* mbn_v  = (const float*)d_in[14];
    const float* mc2_w  = (const float*)d_in[15];
    const float* mc2_b  = (const float*)d_in[16];
    const float* dc_w   = (const float*)d_in[17];
    const float* dc_b   = (const float*)d_in[18];
    const float* cb_dw_w= (const float*)d_in[19];
    const float* cb_dw_b= (const float*)d_in[20];
    const float* cbn_g  = (const float*)d_in[21];
    const float* cbn_b  = (const float*)d_in[22];
    const float* cbn_m  = (const float*)d_in[23];
    const float* cbn_v  = (const float*)d_in[24];
    const float* cb_pw_w= (const float*)d_in[25];
    const float* cb_pw_b= (const float*)d_in[26];
    const float* sa_w   = (const float*)d_in[27];
    const float* sa_b   = (const float*)d_in[28];
    const float* fu_w   = (const float*)d_in[29];
    const float* fu_b   = (const float*)d_in[30];
    const float* fbn_g  = (const float*)d_in[31];
    const float* fbn_b  = (const float*)d_in[32];
    const float* fbn_m  = (const float*)d_in[33];
    const float* fbn_v  = (const float*)d_in[34];

    // workspace layout
    bf16*  ht    = (bf16*)d_ws;                // 1,048,576 bf16
    bf16*  comb  = ht + 1048576;               // 6,291,456 bf16
    float* part  = (float*)(comb + 6291456);   //   802,816 f32
    bf16*  xt    = (bf16*)(part + 802816);     // 2,097,152 bf16
    bf16*  wBf2  = xt + 2097152;               //   294,912 bf16
    bf16*  wCf2  = wBf2 + 294912;              //    73,728 bf16
    float* ab    = (float*)(wCf2 + 73728);     //       128 f32
    bf16*  wFf   = (bf16*)(ab + 128);          //    98,304 bf16
    bf16*  wSAf  = wFf + 98304;                //    24,576 bf16
    float* fab   = (float*)(wSAf + 24576);     //       512 f32
    bf16*  wDf   = (bf16*)(fab + 512);         //    18,432 bf16
    bf16*  wPf   = wDf + 18432;                //    16,384 bf16
    float* dwab  = (float*)(wPf + 16384);      //       256 f32

    float* out = (float*)d_out;

    // 1. x transpose + all weight preps (one kernel)
    prep_all_kernel<<<256 + 2058, 256, 0, stream>>>(
        x, xt,
        dc_w, oc1_w, oc1_b, obn_g, obn_b, obn_m, obn_v,
        mc1_w, mc1_b, mbn_g, mbn_b, mbn_m, mbn_v,
        fu_w, fu_b, fbn_g, fbn_b, fbn_m, fbn_v, sa_w,
        oc2_w, mc2_w, cb_pw_w, cb_dw_b, cbn_g, cbn_b, cbn_m, cbn_v,
        wBf2, wCf2, ab, wFf, wSAf, fab, wDf, wPf, dwab);
    // 2. oc1 + mc1 fused MFMA conv (32px K-split) -> ht pixel-major
    conv1_mfma_kernel<<<512, 256, 0, stream>>>(xt, wCf2, ab, ht);
    // 3. fused contour depthwise + pointwise -> combined_t[:, 256:384]
    dwpw_kernel<<<1024, 256, 0, stream>>>(xt, cb_dw_w, dwab, wPf, cb_pw_b, comb);
    // 4. fused conv2 + modulated deformable conv -> combined_t[:, 0:256]
    deform_kernel<<<512, 256, 0, stream>>>(xt, ht, wDf, oc2_b, mc2_b, wBf2, dc_b, comb);
    // 5. SA GEMM (MFMA, LDS-free)
    sa_gemm_kernel<<<1024, 256, 0, stream>>>(comb, wSAf, part);
    // 6. fusion 1x1 MFMA (+in-block attn, folded BN, ReLU) -> fp32 out
    fuse_kernel<<<1024, 256, 0, stream>>>(comb, part, sa_b, wFf, fab, out);
}

// Round 12
// 200.074 us; speedup vs baseline: 7.3036x; 1.0347x over previous
//
#include <hip/hip_runtime.h>
#include <hip/hip_bf16.h>
#include <math.h>

// Problem constants
#define BN   4
#define CIN  128
#define COUT 256
#define HWP  4096      // 64*64

typedef __hip_bfloat16 bf16;
typedef __attribute__((ext_vector_type(8))) short sh8;    // 8 bf16 = 4 VGPR
typedef __attribute__((ext_vector_type(4))) float f32x4;  // MFMA accumulator

__device__ __forceinline__ float b2f(bf16 v) { return __bfloat162float(v); }
__device__ __forceinline__ float bflo(unsigned u) { return __uint_as_float(u << 16); }
__device__ __forceinline__ float bfhi(unsigned u) { return __uint_as_float(u & 0xffff0000u); }
__device__ __forceinline__ unsigned short f2bfbits(float f) {
    union { bf16 h; unsigned short u; } cv; cv.h = __float2bfloat16(f); return cv.u;
}
__device__ __forceinline__ float bfj(const uint4& c, int j) {
    unsigned u = (&c.x)[j >> 1];
    return (j & 1) ? bfhi(u) : bflo(u);
}

// ---------------------------------------------------------------- prep_all (+x transpose in blocks [0,256))
__global__ __launch_bounds__(256) void prep_all_kernel(
    const float* __restrict__ x, bf16* __restrict__ xt,
    const float* __restrict__ dc_w,
    const float* __restrict__ oc1_w, const float* __restrict__ oc1_b,
    const float* __restrict__ obn_g, const float* __restrict__ obn_b,
    const float* __restrict__ obn_m, const float* __restrict__ obn_v,
    const float* __restrict__ mc1_w, const float* __restrict__ mc1_b,
    const float* __restrict__ mbn_g, const float* __restrict__ mbn_b,
    const float* __restrict__ mbn_m, const float* __restrict__ mbn_v,
    const float* __restrict__ fu_w, const float* __restrict__ fu_b,
    const float* __restrict__ fbn_g, const float* __restrict__ fbn_b,
    const float* __restrict__ fbn_m, const float* __restrict__ fbn_v,
    const float* __restrict__ sa_w,
    const float* __restrict__ oc2_w, const float* __restrict__ mc2_w,
    const float* __restrict__ cb_pw_w,
    const float* __restrict__ cb_dw_b, const float* __restrict__ cbn_g,
    const float* __restrict__ cbn_b, const float* __restrict__ cbn_m,
    const float* __restrict__ cbn_v,
    bf16* __restrict__ wBf2, bf16* __restrict__ wCf2, float* __restrict__ ab,
    bf16* __restrict__ wFf, bf16* __restrict__ wSAf, float* __restrict__ fab,
    bf16* __restrict__ wDf, bf16* __restrict__ wPf, float* __restrict__ dwab)
{
    __shared__ bf16 t[64][136];
    if (blockIdx.x < 256) {
        const int b = blockIdx.x >> 6, chunk = blockIdx.x & 63;
        const int pos0 = chunk * 64;
        const int tid = threadIdx.x;
        const int lane = tid & 63, wv = tid >> 6;
        const float* xb = x + (size_t)b * CIN * HWP + pos0 + lane;
        #pragma unroll 4
        for (int j = 0; j < 32; j++) {
            int ci = wv * 32 + j;
            t[lane][ci] = __float2bfloat16(xb[(size_t)ci * HWP]);
        }
        __syncthreads();
        const int p = tid >> 2, cig = tid & 3;
        uint4* dst = (uint4*)(xt + ((size_t)b * HWP + pos0 + p) * 128 + cig * 32);
        const uint4* src = (const uint4*)&t[p][cig * 32];
        #pragma unroll
        for (int q = 0; q < 4; q++) dst[q] = src[q];
        return;
    }

    int o = (blockIdx.x - 256) * 256 + threadIdx.x;
    if (o < 294912) {
        int j = o & 7, o2 = o >> 3;
        int lane = o2 & 63, t_ = o2 >> 6;
        int l16 = lane & 15, quad = lane >> 4;
        int mt = t_ & 3, t2 = t_ >> 2;
        int kt = t2 % 18, t3 = t2 / 18;
        int h = t3 & 1, wv = t3 >> 1;
        int co = wv * 64 + mt * 16 + l16;
        int kkh = kt * 32 + quad * 8 + j;
        int k = kkh >> 6, ci = h * 64 + (kkh & 63);
        wBf2[o] = __float2bfloat16(dc_w[co * 1152 + ci * 9 + k]);
    } else if (o < 368640) {
        int idx = o - 294912;
        int j = idx & 7, o2 = idx >> 3;
        int lane = o2 & 63, t_ = o2 >> 6;
        int l16 = lane & 15, quad = lane >> 4;
        int kt = t_ % 18, t2 = t_ / 18;
        int h = t2 & 1, wv = t2 >> 1;
        int co = wv * 16 + l16;
        int kkh = kt * 32 + quad * 8 + j;
        int k = kkh >> 6, ci = h * 64 + (kkh & 63);
        float v = (co < 32) ? oc1_w[co * 1152 + ci * 9 + k]
                            : mc1_w[(co - 32) * 1152 + ci * 9 + k];
        wCf2[idx] = __float2bfloat16(v);
    } else if (o < 368704) {
        int c = o - 368640;
        float g, bb, m, vv, bias;
        if (c < 32) { g = obn_g[c]; bb = obn_b[c]; m = obn_m[c]; vv = obn_v[c]; bias = oc1_b[c]; }
        else { int c2 = c - 32; g = mbn_g[c2]; bb = mbn_b[c2]; m = mbn_m[c2]; vv = mbn_v[c2]; bias = mc1_b[c2]; }
        float alpha = g / sqrtf(vv + 1e-5f);
        ab[c] = alpha;
        ab[64 + c] = (bias - m) * alpha + bb;
    } else if (o < 467008) {
        int idx = o - 368704;
        int j = idx & 7, o2 = idx >> 3;
        int lane = o2 & 63, t_ = o2 >> 6;
        int l16 = lane & 15, quad = lane >> 4;
        int mt = t_ & 3, t2 = t_ >> 2;
        int kt = t2 % 12, wv = t2 / 12;
        int co = wv * 64 + mt * 16 + l16;
        int kk = kt * 32 + quad * 8 + j;
        wFf[idx] = __float2bfloat16(fu_w[co * 384 + kk]);
    } else if (o < 491584) {
        int idx = o - 467008;
        int j = idx & 7, o2 = idx >> 3;
        int lane = o2 & 63, t_ = o2 >> 6;
        int l16 = lane & 15, quad = lane >> 4;
        int kt = t_ % 12, wv = t_ / 12;
        int jr = wv * 16 + l16;
        int kk = kt * 32 + quad * 8 + j;
        wSAf[idx] = (jr < 49) ? __float2bfloat16(sa_w[kk * 49 + jr]) : __float2bfloat16(0.f);
    } else if (o < 491840) {
        int co = o - 491584;
        float alpha = fbn_g[co] / sqrtf(fbn_v[co] + 1e-5f);
        fab[co] = alpha;
        fab[256 + co] = (fu_b[co] - fbn_m[co]) * alpha + fbn_b[co];
    } else if (o < 510272) {
        int idx = o - 491840;
        int j = idx & 7, o2 = idx >> 3;
        int lane = o2 & 63, t_ = o2 >> 6;
        int l16 = lane & 15, quad = lane >> 4;
        int mt = t_ & 1, kt = t_ >> 1;
        int co = mt * 16 + l16;
        int kk = kt * 32 + quad * 8 + j;
        int k = kk >> 6, c = kk & 63;
        float v = 0.f;
        if (co < 18 && c < 32) v = oc2_w[co * 288 + c * 9 + k];
        else if (co >= 18 && co < 27 && c >= 32) v = mc2_w[(co - 18) * 288 + (c - 32) * 9 + k];
        wDf[idx] = __float2bfloat16(v);
    } else if (o < 526656) {
        int idx = o - 510272;
        int j = idx & 7, o2 = idx >> 3;
        int lane = o2 & 63, t_ = o2 >> 6;
        int l16 = lane & 15, quad = lane >> 4;
        int wv = t_ >> 3, kt = (t_ >> 1) & 3, mt = t_ & 1;
        int co = wv * 32 + mt * 16 + l16;
        int kk = kt * 32 + quad * 8 + j;
        wPf[idx] = __float2bfloat16(cb_pw_w[co * 128 + kk]);
    } else if (o < 526784) {
        int c = o - 526656;
        float alpha = cbn_g[c] / sqrtf(cbn_v[c] + 1e-5f);
        dwab[c] = alpha;
        dwab[128 + c] = (cb_dw_b[c] - cbn_m[c]) * alpha + cbn_b[c];
    }
}

// ---------------------------------------------------------------- conv1 (oc1+mc1) MFMA, 32px K-split -> ht
__global__ __launch_bounds__(256) void conv1_mfma_kernel(
    const bf16* __restrict__ xt, const bf16* __restrict__ wCf2, const float* __restrict__ ab,
    bf16* __restrict__ ht)
{
    __shared__ __align__(16) bf16 val[32][584];

    const int bid = blockIdx.x;
    const int b = (bid & 7) >> 1;
    const int tile = ((bid >> 3) << 1) | (bid & 1);
    const int pos0 = tile * 32;
    const int y = tile >> 1, x0 = (tile & 1) * 32;
    const int tid = threadIdx.x;
    const int lane = tid & 63, wv = tid >> 6;
    const int quad = lane >> 4, l16 = lane & 15;

    f32x4 acc[2] = {f32x4{0,0,0,0}, f32x4{0,0,0,0}};
    const bf16* xtb = xt + (size_t)b * HWP * 128;

    #pragma unroll
    for (int h = 0; h < 2; h++) {
        if (h) __syncthreads();
        {
            const int cig = tid & 7, pix = tid >> 3;
            const int ci0 = h * 64 + cig * 8;
            const int xxp = x0 + pix;
            #pragma unroll
            for (int k = 0; k < 9; k++) {
                int yy = y + k / 3 - 1, xx = xxp + k % 3 - 1;
                bool valid = (yy >= 0 && yy <= 63 && xx >= 0 && xx <= 63);
                uint4 c = {0, 0, 0, 0};
                if (valid) c = *(const uint4*)(xtb + (size_t)(yy * 64 + xx) * 128 + ci0);
                *(uint4*)&val[pix][k * 64 + cig * 8] = c;
            }
        }
        __syncthreads();

        const bf16* wl0 = wCf2 + ((size_t)(wv * 2 + h) * 18) * 512 + lane * 8;
        const bf16* vb0 = &val[l16][quad * 8];
        const bf16* vb1 = &val[16 + l16][quad * 8];
        for (int kt = 0; kt < 18; kt++) {
            sh8 af = *(const sh8*)(wl0 + kt * 512);
            sh8 b0 = *(const sh8*)(vb0 + kt * 32);
            sh8 b1 = *(const sh8*)(vb1 + kt * 32);
            acc[0] = __builtin_amdgcn_mfma_f32_16x16x32_bf16(af, b0, acc[0], 0, 0, 0);
            acc[1] = __builtin_amdgcn_mfma_f32_16x16x32_bf16(af, b1, acc[1], 0, 0, 0);
        }
    }

    const int co0 = wv * 16 + quad * 4;
    #pragma unroll
    for (int ph = 0; ph < 2; ph++) {
        float o0 = fmaxf(acc[ph][0] * ab[co0 + 0] + ab[64 + co0 + 0], 0.f);
        float o1 = fmaxf(acc[ph][1] * ab[co0 + 1] + ab[64 + co0 + 1], 0.f);
        float o2 = fmaxf(acc[ph][2] * ab[co0 + 2] + ab[64 + co0 + 2], 0.f);
        float o3 = fmaxf(acc[ph][3] * ab[co0 + 3] + ab[64 + co0 + 3], 0.f);
        uint2 pk;
        pk.x = (unsigned)f2bfbits(o0) | ((unsigned)f2bfbits(o1) << 16);
        pk.y = (unsigned)f2bfbits(o2) | ((unsigned)f2bfbits(o3) << 16);
        *(uint2*)(ht + ((size_t)b * HWP + pos0 + ph * 16 + l16) * 64 + co0) = pk;
    }
}

// ---------------------------------------------------------------- fused depthwise + pointwise + SA(contour)
// grid 1024 (16 px/block). Phase1: dw -> LDS; Phase2: pw MFMA; Phase3: SA kt 8-11 -> part_b.
__global__ __launch_bounds__(256) void dwpw_kernel(
    const bf16* __restrict__ xt, const float* __restrict__ dw_w, const float* __restrict__ dwab,
    const bf16* __restrict__ wPf, const float* __restrict__ pw_b,
    const bf16* __restrict__ wSAf, bf16* __restrict__ combined, float* __restrict__ part_b)
{
    __shared__ float wl[1152];
    __shared__ float abl[256];
    __shared__ __align__(16) bf16 vdw[16][136];
    const int bid = blockIdx.x;
    const int b = bid >> 8, tile = bid & 255;
    const int pos0 = tile * 16;
    const int y = tile >> 2, x0 = (tile & 3) * 16;
    const int tid = threadIdx.x;
    for (int i = tid; i < 1152; i += 256) wl[i] = dw_w[i];
    abl[tid] = dwab[tid];
    __syncthreads();

    {
        const int cig = tid & 15, pix = tid >> 4;
        const int ci0 = cig * 8;
        const int xxp = x0 + pix;
        const bf16* xtb = xt + (size_t)b * HWP * 128;
        float g[8] = {0, 0, 0, 0, 0, 0, 0, 0};
        #pragma unroll
        for (int k = 0; k < 9; k++) {
            int yy = y + k / 3 - 1, xx = xxp + k % 3 - 1;
            if (yy < 0 || yy > 63 || xx < 0 || xx > 63) continue;
            uint4 c = *(const uint4*)(xtb + (size_t)(yy * 64 + xx) * 128 + ci0);
            #pragma unroll
            for (int j = 0; j < 8; j++)
                g[j] += wl[(ci0 + j) * 9 + k] * bfj(c, j);
        }
        uint4 pk;
        float o[8];
        #pragma unroll
        for (int j = 0; j < 8; j++)
            o[j] = fmaxf(g[j] * abl[ci0 + j] + abl[128 + ci0 + j], 0.f);
        pk.x = (unsigned)f2bfbits(o[0]) | ((unsigned)f2bfbits(o[1]) << 16);
        pk.y = (unsigned)f2bfbits(o[2]) | ((unsigned)f2bfbits(o[3]) << 16);
        pk.z = (unsigned)f2bfbits(o[4]) | ((unsigned)f2bfbits(o[5]) << 16);
        pk.w = (unsigned)f2bfbits(o[6]) | ((unsigned)f2bfbits(o[7]) << 16);
        *(uint4*)&vdw[pix][ci0] = pk;
    }
    __syncthreads();

    const int lane = tid & 63, wv = tid >> 6;
    const int quad = lane >> 4, l16 = lane & 15;
    f32x4 acc[2] = {f32x4{0,0,0,0}, f32x4{0,0,0,0}};
    const bf16* fb = &vdw[l16][quad * 8];
    const bf16* wl0 = wPf + (size_t)wv * 4096 + lane * 8;
    #pragma unroll
    for (int kt = 0; kt < 4; kt++) {
        sh8 bf = *(const sh8*)(fb + kt * 32);
        #pragma unroll
        for (int mt = 0; mt < 2; mt++) {
            sh8 af = *(const sh8*)(wl0 + (kt * 2 + mt) * 512);
            acc[mt] = __builtin_amdgcn_mfma_f32_16x16x32_bf16(af, bf, acc[mt], 0, 0, 0);
        }
    }

    // global write of contour features
    bf16* ct = combined + ((size_t)b * HWP + pos0 + l16) * 384 + 256;
    #pragma unroll
    for (int mt = 0; mt < 2; mt++) {
        int co_b = wv * 32 + mt * 16 + quad * 4;
        uint2 pk;
        pk.x = (unsigned)f2bfbits(acc[mt][0] + pw_b[co_b])     | ((unsigned)f2bfbits(acc[mt][1] + pw_b[co_b + 1]) << 16);
        pk.y = (unsigned)f2bfbits(acc[mt][2] + pw_b[co_b + 2]) | ((unsigned)f2bfbits(acc[mt][3] + pw_b[co_b + 3]) << 16);
        *(uint2*)(ct + co_b) = pk;
    }

    // ---- Phase3: SA contribution for contour channels (global kt 8..11), reuse vdw as ct2[pix][co]
    __syncthreads();                       // all pw B-reads of vdw done
    bf16* ct2 = &vdw[0][0];                // [pix][co], stride 136
    #pragma unroll
    for (int mt = 0; mt < 2; mt++) {
        int co_b = wv * 32 + mt * 16 + quad * 4;
        uint2 pk;
        pk.x = (unsigned)f2bfbits(acc[mt][0] + pw_b[co_b])     | ((unsigned)f2bfbits(acc[mt][1] + pw_b[co_b + 1]) << 16);
        pk.y = (unsigned)f2bfbits(acc[mt][2] + pw_b[co_b + 2]) | ((unsigned)f2bfbits(acc[mt][3] + pw_b[co_b + 3]) << 16);
        *(uint2*)(ct2 + l16 * 136 + co_b) = pk;
    }
    __syncthreads();

    f32x4 sacc = {0, 0, 0, 0};
    const bf16* awl = wSAf + (size_t)wv * 6144 + lane * 8;
    #pragma unroll
    for (int kt2 = 0; kt2 < 4; kt2++) {
        sh8 af = *(const sh8*)(awl + (8 + kt2) * 512);
        sh8 bf2 = *(const sh8*)(ct2 + l16 * 136 + kt2 * 32 + quad * 8);
        sacc = __builtin_amdgcn_mfma_f32_16x16x32_bf16(af, bf2, sacc, 0, 0, 0);
    }
    #pragma unroll
    for (int r = 0; r < 4; r++) {
        int j = wv * 16 + quad * 4 + r;
        if (j < 49) part_b[(size_t)(j * BN + b) * HWP + pos0 + l16] = sacc[r];
    }
}

// ---------------------------------------------------------------- fused conv2 + deform + SA(main)
// grid 512, block 256 = 4 waves. LDS ~49 KB.
__global__ __launch_bounds__(256) void deform_kernel(
    const bf16* __restrict__ xt, const bf16* __restrict__ ht, const bf16* __restrict__ wDf,
    const float* __restrict__ oc2_b, const float* __restrict__ mc2_b,
    const bf16* __restrict__ wBf2, const float* __restrict__ bias,
    const bf16* __restrict__ wSAf, bf16* __restrict__ combined, float* __restrict__ part_a)
{
    __shared__ __align__(16) bf16 val[32][584];
    __shared__ int   ti[288][4];
    __shared__ float tw[288][4];
    __shared__ float loff[18][32];
    __shared__ float lmsk[9][32];

    const int bid = blockIdx.x;
    const int b = (bid & 7) >> 1;                    // XCD-affinity
    const int tile = ((bid >> 3) << 1) | (bid & 1);  // [0,128)
    const int pos0 = tile * 32;
    const int y = tile >> 1, x0 = (tile & 1) * 32;
    const int tid = threadIdx.x;
    const int lane = tid & 63, wv = tid >> 6;
    const int quad = lane >> 4, l16 = lane & 15;

    // ---- Phase A: conv2 (oc2+mc2) for this tile's 32 pixels
    {
        const int cig = tid & 7, pix = tid >> 3;
        const int xxp = x0 + pix;
        const bf16* hb = ht + (size_t)b * HWP * 64;
        #pragma unroll
        for (int k = 0; k < 9; k++) {
            int yy = y + k / 3 - 1, xx = xxp + k % 3 - 1;
            bool valid = (yy >= 0 && yy <= 63 && xx >= 0 && xx <= 63);
            uint4 c = {0, 0, 0, 0};
            if (valid) c = *(const uint4*)(hb + (size_t)(yy * 64 + xx) * 64 + cig * 8);
            *(uint4*)&val[pix][k * 64 + cig * 8] = c;
        }
    }
    __syncthreads();
    {
        const int ph = wv >> 1, mt = wv & 1;
        f32x4 acc2 = {0, 0, 0, 0};
        const bf16* wl0 = wDf + ((size_t)mt * 64 + lane) * 8;
        const bf16* vbase = &val[ph * 16 + l16][quad * 8];
        for (int kt = 0; kt < 18; kt++) {
            sh8 af = *(const sh8*)(wl0 + kt * 1024);
            sh8 bf = *(const sh8*)(vbase + kt * 32);
            acc2 = __builtin_amdgcn_mfma_f32_16x16x32_bf16(af, bf, acc2, 0, 0, 0);
        }
        const int pix2 = ph * 16 + l16;
        #pragma unroll
        for (int r = 0; r < 4; r++) {
            int co = mt * 16 + quad * 4 + r;
            if (co < 18) {
                loff[co][pix2] = acc2[r] + oc2_b[co];
            } else if (co < 27) {
                float s = acc2[r] + mc2_b[co - 18];
                lmsk[co - 18][pix2] = 1.f / (1.f + expf(-s));
            }
        }
    }
    __syncthreads();

    // ---- Phase B: bilinear corner tables
    for (int e = tid; e < 288; e += 256) {
        int k = e >> 5, pix = e & 31;
        int pos = pos0 + pix;
        int yp = pos >> 6, xc = pos & 63;
        float offy = loff[2 * k][pix];
        float offx = loff[2 * k + 1][pix];
        float m = lmsk[k][pix];
        float py = (float)(yp - 1 + k / 3) + offy;
        float px = (float)(xc - 1 + k % 3) + offx;
        float fy = floorf(py), fx = floorf(px);
        float wy1 = py - fy, wx1 = px - fx;
        int y0 = (int)fy, x0c = (int)fx;
        int y1 = y0 + 1, x1 = x0c + 1;
        bool vy0 = (y0 >= 0 && y0 <= 63), vy1 = (y1 >= 0 && y1 <= 63);
        bool vx0 = (x0c >= 0 && x0c <= 63), vx1 = (x1 >= 0 && x1 <= 63);
        int cy0 = min(max(y0, 0), 63), cy1 = min(max(y1, 0), 63);
        int cx0 = min(max(x0c, 0), 63), cx1 = min(max(x1, 0), 63);
        ti[e][0] = cy0 * 64 + cx0;  tw[e][0] = (vy0 && vx0) ? (1.f - wy1) * (1.f - wx1) * m : 0.f;
        ti[e][1] = cy0 * 64 + cx1;  tw[e][1] = (vy0 && vx1) ? (1.f - wy1) * wx1 * m : 0.f;
        ti[e][2] = cy1 * 64 + cx0;  tw[e][2] = (vy1 && vx0) ? wy1 * (1.f - wx1) * m : 0.f;
        ti[e][3] = cy1 * 64 + cx1;  tw[e][3] = (vy1 && vx1) ? wy1 * wx1 * m : 0.f;
    }
    __syncthreads();

    // ---- Phase C/D: K-split gather + MFMA
    f32x4 acc[4][2] = {{f32x4{0,0,0,0}, f32x4{0,0,0,0}}, {f32x4{0,0,0,0}, f32x4{0,0,0,0}},
                       {f32x4{0,0,0,0}, f32x4{0,0,0,0}}, {f32x4{0,0,0,0}, f32x4{0,0,0,0}}};
    const bf16* xtb = xt + (size_t)b * HWP * 128;

    #pragma unroll
    for (int h = 0; h < 2; h++) {
        if (h) __syncthreads();
        {
            const int cig = tid & 7, pix = tid >> 3;
            const int ci0 = h * 64 + cig * 8;
            for (int k = 0; k < 9; k++) {
                const int e = k * 32 + pix;
                const int i0 = ti[e][0], i1 = ti[e][1], i2 = ti[e][2], i3 = ti[e][3];
                const float w0 = tw[e][0], w1 = tw[e][1], w2 = tw[e][2], w3 = tw[e][3];
                uint4 c0 = *(const uint4*)(xtb + (size_t)i0 * 128 + ci0);
                uint4 c1 = *(const uint4*)(xtb + (size_t)i1 * 128 + ci0);
                uint4 c2 = *(const uint4*)(xtb + (size_t)i2 * 128 + ci0);
                uint4 c3 = *(const uint4*)(xtb + (size_t)i3 * 128 + ci0);
                float g[8];
                #pragma unroll
                for (int j = 0; j < 8; j++)
                    g[j] = w0 * bfj(c0, j) + w1 * bfj(c1, j) + w2 * bfj(c2, j) + w3 * bfj(c3, j);
                uint4 pk;
                pk.x = (unsigned)f2bfbits(g[0]) | ((unsigned)f2bfbits(g[1]) << 16);
                pk.y = (unsigned)f2bfbits(g[2]) | ((unsigned)f2bfbits(g[3]) << 16);
                pk.z = (unsigned)f2bfbits(g[4]) | ((unsigned)f2bfbits(g[5]) << 16);
                pk.w = (unsigned)f2bfbits(g[6]) | ((unsigned)f2bfbits(g[7]) << 16);
                *(uint4*)&val[pix][k * 64 + cig * 8] = pk;
            }
        }
        __syncthreads();

        const bf16* wl0 = wBf2 + ((size_t)(wv * 2 + h) * 72) * 512 + lane * 8;
        const bf16* vb0 = &val[l16][quad * 8];
        const bf16* vb1 = &val[16 + l16][quad * 8];
        sh8 af[4], afn[4];
        #pragma unroll
        for (int mt = 0; mt < 4; mt++) af[mt] = *(const sh8*)(wl0 + mt * 512);
        for (int kt = 0; kt < 18; kt++) {
            sh8 b0 = *(const sh8*)(vb0 + kt * 32);
            sh8 b1 = *(const sh8*)(vb1 + kt * 32);
            if (kt < 17) {
                #pragma unroll
                for (int mt = 0; mt < 4; mt++)
                    afn[mt] = *(const sh8*)(wl0 + ((kt + 1) * 4 + mt) * 512);
            }
            #pragma unroll
            for (int mt = 0; mt < 4; mt++) {
                acc[mt][0] = __builtin_amdgcn_mfma_f32_16x16x32_bf16(af[mt], b0, acc[mt][0], 0, 0, 0);
                acc[mt][1] = __builtin_amdgcn_mfma_f32_16x16x32_bf16(af[mt], b1, acc[mt][1], 0, 0, 0);
            }
            #pragma unroll
            for (int mt = 0; mt < 4; mt++) af[mt] = afn[mt];
        }
    }

    // ---- epilogue: global comb write + LDS transpose for SA
    uint2 pko[4][2];
    #pragma unroll
    for (int ph = 0; ph < 2; ph++) {
        bf16* ct = combined + ((size_t)b * HWP + pos0 + ph * 16 + l16) * 384;
        #pragma unroll
        for (int mt = 0; mt < 4; mt++) {
            int co_b = wv * 64 + mt * 16 + quad * 4;
            uint2 pk;
            pk.x = (unsigned)f2bfbits(acc[mt][ph][0] + bias[co_b])     | ((unsigned)f2bfbits(acc[mt][ph][1] + bias[co_b + 1]) << 16);
            pk.y = (unsigned)f2bfbits(acc[mt][ph][2] + bias[co_b + 2]) | ((unsigned)f2bfbits(acc[mt][ph][3] + bias[co_b + 3]) << 16);
            *(uint2*)(ct + co_b) = pk;
            pko[mt][ph] = pk;
        }
    }

    // ---- Phase E: SA for main channels (global kt 0..7); reuse val as ctile[pix][co] stride 264
    __syncthreads();                          // all MFMA B-reads of val done
    bf16* ctile = &val[0][0];
    #pragma unroll
    for (int ph = 0; ph < 2; ph++) {
        int pix = ph * 16 + l16;
        #pragma unroll
        for (int mt = 0; mt < 4; mt++) {
            int co_b = wv * 64 + mt * 16 + quad * 4;
            *(uint2*)(ctile + pix * 264 + co_b) = pko[mt][ph];
        }
    }
    __syncthreads();

    f32x4 sacc[2] = {f32x4{0,0,0,0}, f32x4{0,0,0,0}};
    const bf16* awl = wSAf + (size_t)wv * 6144 + lane * 8;
    for (int kt = 0; kt < 8; kt++) {
        sh8 af = *(const sh8*)(awl + kt * 512);
        sh8 b0 = *(const sh8*)(ctile + l16 * 264 + kt * 32 + quad * 8);
        sh8 b1 = *(const sh8*)(ctile + (16 + l16) * 264 + kt * 32 + quad * 8);
        sacc[0] = __builtin_amdgcn_mfma_f32_16x16x32_bf16(af, b0, sacc[0], 0, 0, 0);
        sacc[1] = __builtin_amdgcn_mfma_f32_16x16x32_bf16(af, b1, sacc[1], 0, 0, 0);
    }
    #pragma unroll
    for (int ph = 0; ph < 2; ph++) {
        #pragma unroll
        for (int r = 0; r < 4; r++) {
            int j = wv * 16 + quad * 4 + r;
            if (j < 49) part_a[(size_t)(j * BN + b) * HWP + pos0 + ph * 16 + l16] = sacc[ph][r];
        }
    }
}

// ---------------------------------------------------------------- fusion 1x1 MFMA + in-block attn finalize
__global__ __launch_bounds__(256) void fuse_kernel(
    const bf16* __restrict__ combined, const float* __restrict__ part_a, const float* __restrict__ part_b,
    const float* __restrict__ sa_b,
    const bf16* __restrict__ wFf, const float* __restrict__ fab, float* __restrict__ out)
{
    __shared__ float sattn[16][17];
    __shared__ float lattn[16];

    const int bid = blockIdx.x;
    const int b = bid >> 8, tile = bid & 255;
    const int pos0 = tile * 16;
    const int y = tile >> 2, x0 = (tile & 3) * 16;
    const int tid = threadIdx.x;

    {
        const int px = tid & 15, g = tid >> 4;
        const int xp = x0 + px;
        float s = 0.f;
        for (int j = g; j < 49; j += 16) {
            int yy = y + j / 7 - 3, xx = xp + j % 7 - 3;
            if (yy < 0 || yy > 63 || xx < 0 || xx > 63) continue;
            size_t idx = (size_t)(j * BN + b) * HWP + yy * 64 + xx;
            s += part_a[idx] + part_b[idx];
        }
        sattn[px][g] = s;
    }
    __syncthreads();
    if (tid < 16) {
        float t = sa_b[0];
        #pragma unroll
        for (int g = 0; g < 16; g++) t += sattn[tid][g];
        lattn[tid] = 1.f / (1.f + expf(-t));
    }
    __syncthreads();

    const int lane = tid & 63, wv = tid >> 6;
    const int quad = lane >> 4, l16 = lane & 15;

    f32x4 acc[4] = {f32x4{0,0,0,0}, f32x4{0,0,0,0}, f32x4{0,0,0,0}, f32x4{0,0,0,0}};
    const bf16* fb = combined + ((size_t)b * HWP + pos0 + l16) * 384 + quad * 8;
    const bf16* wl0 = wFf + (size_t)wv * 24576 + lane * 8;

    sh8 af[4], afn[4], bf, bfn;
    bf = *(const sh8*)(fb);
    #pragma unroll
    for (int mt = 0; mt < 4; mt++) af[mt] = *(const sh8*)(wl0 + mt * 512);
    for (int kt = 0; kt < 12; kt++) {
        if (kt < 11) {
            bfn = *(const sh8*)(fb + (kt + 1) * 32);
            #pragma unroll
            for (int mt = 0; mt < 4; mt++)
                afn[mt] = *(const sh8*)(wl0 + ((kt + 1) * 4 + mt) * 512);
        }
        #pragma unroll
        for (int mt = 0; mt < 4; mt++)
            acc[mt] = __builtin_amdgcn_mfma_f32_16x16x32_bf16(af[mt], bf, acc[mt], 0, 0, 0);
        bf = bfn;
        #pragma unroll
        for (int mt = 0; mt < 4; mt++) af[mt] = afn[mt];
    }

    float a = lattn[l16];
    float* op = out + (size_t)b * COUT * HWP + pos0 + l16;
    #pragma unroll
    for (int mt = 0; mt < 4; mt++) {
        int co_b = wv * 64 + mt * 16 + quad * 4;
        #pragma unroll
        for (int r = 0; r < 4; r++) {
            int co = co_b + r;
            float o = fmaxf(acc[mt][r] * a * fab[co] + fab[256 + co], 0.f);
            op[(size_t)co * HWP] = o;
        }
    }
}

// ================================================================ launch
extern "C" void kernel_launch(void* const* d_in, const int* in_sizes, int n_in,
                              void* d_out, int out_size, void* d_ws, size_t ws_size,
                              hipStream_t stream)
{
    const float* x      = (const float*)d_in[0];
    const float* oc1_w  = (const float*)d_in[1];
    const float* oc1_b  = (const float*)d_in[2];
    const float* obn_g  = (const float*)d_in[3];
    const float* obn_b  = (const float*)d_in[4];
    const float* obn_m  = (const float*)d_in[5];
    const float* obn_v  = (const float*)d_in[6];
    const float* oc2_w  = (const float*)d_in[7];
    const float* oc2_b  = (const float*)d_in[8];
    const float* mc1_w  = (const float*)d_in[9];
    const float* mc1_b  = (const float*)d_in[10];
    const float* mbn_g  = (const float*)d_in[11];
    const float* mbn_b  = (const float*)d_in[12];
    const float* mbn_m  = (const float*)d_in[13];
    const float* mbn_v  = (const float*)d_in[14];
    const float* mc2_w  = (const float*)d_in[15];
    const float* mc2_b  = (const float*)d_in[16];
    const float* dc_w   = (const float*)d_in[17];
    const float* dc_b   = (const float*)d_in[18];
    const float* cb_dw_w= (const float*)d_in[19];
    const float* cb_dw_b= (const float*)d_in[20];
    const float* cbn_g  = (const float*)d_in[21];
    const float* cbn_b  = (const float*)d_in[22];
    const float* cbn_m  = (const float*)d_in[23];
    const float* cbn_v  = (const float*)d_in[24];
    const float* cb_pw_w= (const float*)d_in[25];
    const float* cb_pw_b= (const float*)d_in[26];
    const float* sa_w   = (const float*)d_in[27];
    const float* sa_b   = (const float*)d_in[28];
    const float* fu_w   = (const float*)d_in[29];
    const float* fu_b   = (const float*)d_in[30];
    const float* fbn_g  = (const float*)d_in[31];
    const float* fbn_b  = (const float*)d_in[32];
    const float* fbn_m  = (const float*)d_in[33];
    const float* fbn_v  = (const float*)d_in[34];

    // workspace layout
    bf16*  ht     = (bf16*)d_ws;                 // 1,048,576 bf16
    bf16*  comb   = ht + 1048576;                // 6,291,456 bf16
    float* part_a = (float*)(comb + 6291456);    //   802,816 f32
    float* part_b = part_a + 802816;             //   802,816 f32
    bf16*  xt     = (bf16*)(part_b + 802816);    // 2,097,152 bf16
    bf16*  wBf2   = xt + 2097152;                //   294,912 bf16
    bf16*  wCf2   = wBf2 + 294912;               //    73,728 bf16
    float* ab     = (float*)(wCf2 + 73728);      //       128 f32
    bf16*  wFf    = (bf16*)(ab + 128);           //    98,304 bf16
    bf16*  wSAf   = wFf + 98304;                 //    24,576 bf16
    float* fab    = (float*)(wSAf + 24576);      //       512 f32
    bf16*  wDf    = (bf16*)(fab + 512);          //    18,432 bf16
    bf16*  wPf    = wDf + 18432;                 //    16,384 bf16
    float* dwab   = (float*)(wPf + 16384);       //       256 f32

    float* out = (float*)d_out;

    // 1. x transpose + all weight preps
    prep_all_kernel<<<256 + 2058, 256, 0, stream>>>(
        x, xt,
        dc_w, oc1_w, oc1_b, obn_g, obn_b, obn_m, obn_v,
        mc1_w, mc1_b, mbn_g, mbn_b, mbn_m, mbn_v,
        fu_w, fu_b, fbn_g, fbn_b, fbn_m, fbn_v, sa_w,
        oc2_w, mc2_w, cb_pw_w, cb_dw_b, cbn_g, cbn_b, cbn_m, cbn_v,
        wBf2, wCf2, ab, wFf, wSAf, fab, wDf, wPf, dwab);
    // 2. oc1 + mc1 fused MFMA conv (32px K-split) -> ht pixel-major
    conv1_mfma_kernel<<<512, 256, 0, stream>>>(xt, wCf2, ab, ht);
    // 3. fused contour dw + pw + SA(contour) -> comb[:,256:384], part_b
    dwpw_kernel<<<1024, 256, 0, stream>>>(xt, cb_dw_w, dwab, wPf, cb_pw_b, wSAf, comb, part_b);
    // 4. fused conv2 + deform + SA(main) -> comb[:,0:256], part_a
    deform_kernel<<<512, 256, 0, stream>>>(xt, ht, wDf, oc2_b, mc2_b, wBf2, dc_b, wSAf, comb, part_a);
    // 5. fusion 1x1 MFMA (+in-block attn from part_a+part_b, folded BN, ReLU) -> fp32 out
    fuse_kernel<<<1024, 256, 0, stream>>>(comb, part_a, part_b, sa_b, wFf, fab, out);
}